// Round 1
// 362.916 us; speedup vs baseline: 1.0070x; 1.0070x over previous
//
#include <hip/hip_runtime.h>

// Problem constants (fixed by the reference)
#define M 3
#define B 32
#define S 256
#define D 768
#define H 1024
#define MD (M * D)          // 2304
#define NP (M * (M - 1))    // 6 ordered (i,j) pairs
#define SCALE 0.03608439182435161f  // 1/sqrt(768)
#define LN_EPS 1e-5f

// Workspace layout (float offsets).
#define OFF_WMU   0         // [M][D]
#define OFF_WLV   2304      // [M][D]
#define OFF_WPGQ  4608      // [M][D]
#define OFF_WPK   6912      // [NP][D]
#define OFF_CMU   11520     // [M]
#define OFF_CLV   11523     // [M]
#define OFF_CPGQ  11526     // [M]
#define OFF_CPK   11529     // [NP]
#define OFF_MU    11552     // [M][B][S]
#define OFF_LV    36128     // [M][B][S]
#define OFF_PKPRE 60704     // [NP][B][S]
#define OFF_PQPRE 109856    // [M][B]
#define OFF_Q     109952    // [M][B][D]
#define OFF_QBK   183680    // [NP][B]
#define OFF_FSUM  331328    // [2(h)][NP][B][D] (h stride 147456)
#define OFF_MLH   626240    // [NP][B][2(h)][2(m,l)] = 768 floats
#define OFF_FUSED 699968    // [B][MD]
#define OFF_KL    773696    // [1]
#define OFF_WKT   773760    // [M][D][D] Wk transposed (1769472 floats)
#define OFF_ARENA 2543232   // Q partials (L1) -> agg partials (L4). 1769472 floats
#define OFF_ARENA2 4312704  // QK partials (L2) -> E/G partials (L5). 1769472 floats

__device__ __forceinline__ float wave_reduce(float v) {
    #pragma unroll
    for (int o = 32; o > 0; o >>= 1) v += __shfl_down(v, o, 64);
    return v;
}

__device__ __forceinline__ float sigmoidf(float x) {
    return 1.0f / (1.0f + __expf(-x));
}

__device__ __forceinline__ float dot4(float4 a, float4 b) {
    return a.x * b.x + a.y * b.y + a.z * b.z + a.w * b.w;
}

__device__ __forceinline__ void fma4(float4& a, float s, float4 w) {
    a.x += s * w.x; a.y += s * w.y; a.z += s * w.z; a.w += s * w.w;
}

// L1: fused prep + Q partials.
// blocks 0..71 vector-dots, 72..86 scalar consts, 87..518 Wk transpose,
// 519..806 Q GEMV partials (feats_s0 @ Wq, split-K 24).
__global__ __launch_bounds__(256) void k_prep2(const float* feats,
        const float* Wq, const float* Wk,
        const float* bq, const float* bk,
        const float* mu_w, const float* mu_b, const float* lv_w, const float* lv_b,
        const float* pgq_w, const float* pgq_b, const float* pgk_w, const float* pgk_b,
        float* ws) {
    int blk = blockIdx.x;
    if (blk < 72) {
        int mat = blk / 12, rg = blk % 12;
        const float* Wm; const float *va, *vb, *vc;
        float *oa, *ob, *oc; int nv;
        if (mat < 3) {
            int i = mat;
            Wm = Wq + i * D * D;
            va = mu_w + i * D; vb = lv_w + i * D; vc = pgq_w + i * D;
            oa = ws + OFF_WMU + i * D; ob = ws + OFF_WLV + i * D; oc = ws + OFF_WPGQ + i * D;
            nv = 3;
        } else {
            int j = mat - 3;
            int i1 = (j == 0) ? 1 : 0, i2 = (j == 2) ? 1 : 2;
            int p1 = 2 * i1 + ((j < i1) ? j : j - 1);
            int p2 = 2 * i2 + ((j < i2) ? j : j - 1);
            Wm = Wk + j * D * D;
            va = pgk_w + i1 * D; vb = pgk_w + i2 * D; vc = va;
            oa = ws + OFF_WPK + p1 * D; ob = ws + OFF_WPK + p2 * D; oc = oa;
            nv = 2;
        }
        int wave = threadIdx.x >> 6, lane = threadIdx.x & 63;
        const float4* va4 = (const float4*)va;
        const float4* vb4 = (const float4*)vb;
        const float4* vc4 = (const float4*)vc;
        float4 A0 = va4[lane], A1 = va4[lane + 64], A2 = va4[lane + 128];
        float4 B0 = vb4[lane], B1 = vb4[lane + 64], B2 = vb4[lane + 128];
        float4 C0 = vc4[lane], C1 = vc4[lane + 64], C2 = vc4[lane + 128];
        int base = rg * 64 + wave * 16;
        for (int r = 0; r < 16; r += 2) {
            const float4* rowP = (const float4*)(Wm + (base + r) * D);
            const float4* rowQ = (const float4*)(Wm + (base + r + 1) * D);
            float4 x0 = rowP[lane], x1 = rowP[lane + 64], x2 = rowP[lane + 128];
            float4 y0 = rowQ[lane], y1 = rowQ[lane + 64], y2 = rowQ[lane + 128];
            float daP = dot4(x0, A0) + dot4(x1, A1) + dot4(x2, A2);
            float dbP = dot4(x0, B0) + dot4(x1, B1) + dot4(x2, B2);
            float dcP = dot4(x0, C0) + dot4(x1, C1) + dot4(x2, C2);
            float daQ = dot4(y0, A0) + dot4(y1, A1) + dot4(y2, A2);
            float dbQ = dot4(y0, B0) + dot4(y1, B1) + dot4(y2, B2);
            float dcQ = dot4(y0, C0) + dot4(y1, C1) + dot4(y2, C2);
            daP = wave_reduce(daP); dbP = wave_reduce(dbP);
            daQ = wave_reduce(daQ); dbQ = wave_reduce(dbQ);
            if (nv == 3) { dcP = wave_reduce(dcP); dcQ = wave_reduce(dcQ); }
            if (lane == 0) {
                oa[base + r] = daP; ob[base + r] = dbP;
                oa[base + r + 1] = daQ; ob[base + r + 1] = dbQ;
                if (nv == 3) { oc[base + r] = dcP; oc[base + r + 1] = dcQ; }
            }
        }
    } else if (blk < 87) {
        int job = blk - 72;
        const float *a, *bvec; float bias; float* out;
        if (job < 3)      { int i = job;     a = bq + i * D; bvec = mu_w + i * D;  bias = mu_b[i];  out = ws + OFF_CMU + i; }
        else if (job < 6) { int i = job - 3; a = bq + i * D; bvec = lv_w + i * D;  bias = lv_b[i];  out = ws + OFF_CLV + i; }
        else if (job < 9) { int i = job - 6; a = bq + i * D; bvec = pgq_w + i * D; bias = pgq_b[i]; out = ws + OFF_CPGQ + i; }
        else {
            int p = job - 9, i = p / 2, c = p % 2, j = c + (c >= i ? 1 : 0);
            a = bk + j * D; bvec = pgk_w + i * D; bias = pgk_b[i]; out = ws + OFF_CPK + p;
        }
        int t = threadIdx.x;
        float part = 0.f;
        if (t < 192) part = dot4(((const float4*)a)[t], ((const float4*)bvec)[t]);
        part = wave_reduce(part);
        __shared__ float r[4];
        if ((t & 63) == 0) r[t >> 6] = part;
        __syncthreads();
        if (t == 0) *out = r[0] + r[1] + r[2] + r[3] + bias;
    } else if (blk < 519) {
        int r = blk - 87;
        int j = r / 144; r = r % 144;
        int d0 = (r / 12) * 64, e0 = (r % 12) * 64;
        __shared__ float tile[64][65];
        const float* src = Wk + j * D * D;
        for (int idx = threadIdx.x; idx < 4096; idx += 256) {
            int rr = idx / 64, cc = idx % 64;
            tile[rr][cc] = src[(d0 + rr) * D + e0 + cc];
        }
        __syncthreads();
        float* dst = ws + OFF_WKT + j * D * D;
        for (int idx = threadIdx.x; idx < 4096; idx += 256) {
            int rr = idx / 64, cc = idx % 64;
            dst[(e0 + rr) * D + d0 + cc] = tile[cc][rr];
        }
    } else {
        // Q partials: blocks (i 3, bg 4 (8 b), kc 24 (32 k))
        int qb = blk - 519;
        int i = qb / 96, r = qb % 96, bg = r / 24, kc = r % 24;
        int kbase = kc * 32;
        __shared__ __align__(16) float xs[32][8];
        for (int idx = threadIdx.x; idx < 256; idx += 256) {
            int d = idx / 8, bb = idx % 8;
            xs[d][bb] = feats[((size_t)(i * B + bg * 8 + bb) * S) * D + kbase + d];
        }
        __syncthreads();
        if (threadIdx.x < 192) {
            int e4 = threadIdx.x * 4;
            const float* Wm = Wq + i * D * D + kbase * D + e4;
            float4 acc[8];
            #pragma unroll
            for (int bb = 0; bb < 8; bb++) acc[bb] = make_float4(0.f, 0.f, 0.f, 0.f);
            for (int k = 0; k < 32; k++) {
                float4 w = *(const float4*)(Wm + k * D);
                float4 x0 = *(const float4*)&xs[k][0];
                float4 x1 = *(const float4*)&xs[k][4];
                fma4(acc[0], x0.x, w); fma4(acc[1], x0.y, w);
                fma4(acc[2], x0.z, w); fma4(acc[3], x0.w, w);
                fma4(acc[4], x1.x, w); fma4(acc[5], x1.y, w);
                fma4(acc[6], x1.z, w); fma4(acc[7], x1.w, w);
            }
            #pragma unroll
            for (int bb = 0; bb < 8; bb++)
                *(float4*)&ws[OFF_ARENA + kc * 73728 + (i * 32 + bg * 8 + bb) * 768 + e4] = acc[bb];
        }
    }
}

// L2: merged stats (blocks 0..1535) + red_q (1536..1631) + qk w/ inline Q-reduce (1632..1919).
__global__ __launch_bounds__(256) void k_stats2(const float* feats,
        const float* bq, const float* bk, float* ws) {
    int blk = blockIdx.x;
    if (blk < 1536) {
        __shared__ float klred[4];
        int wave = threadIdx.x >> 6, lane = threadIdx.x & 63;
        int m = blk / 512;
        int row0 = blk * 16 + wave * 4;
        int i1 = (m == 0) ? 1 : 0, i2 = (m == 2) ? 1 : 2;
        int p0 = 2 * i1 + ((m < i1) ? m : m - 1);
        int p1 = 2 * i2 + ((m < i2) ? m : m - 1);
        const float4* wmu  = (const float4*)(ws + OFF_WMU + m * D);
        const float4* wlv  = (const float4*)(ws + OFF_WLV + m * D);
        const float4* wpgq = (const float4*)(ws + OFF_WPGQ + m * D);
        const float4* wpk0 = (const float4*)(ws + OFF_WPK + p0 * D);
        const float4* wpk1 = (const float4*)(ws + OFF_WPK + p1 * D);
        float4 U0 = wmu[lane],  U1 = wmu[lane + 64],  U2 = wmu[lane + 128];
        float4 L0 = wlv[lane],  L1 = wlv[lane + 64],  L2 = wlv[lane + 128];
        float4 Q0 = wpgq[lane], Q1 = wpgq[lane + 64], Q2 = wpgq[lane + 128];
        float4 P0 = wpk0[lane], P1 = wpk0[lane + 64], P2 = wpk0[lane + 128];
        float4 R0 = wpk1[lane], R1 = wpk1[lane + 64], R2 = wpk1[lane + 128];
        float4 x[4][3];
        #pragma unroll
        for (int rr = 0; rr < 4; rr++) {
            const float4* f = (const float4*)(feats + (size_t)(row0 + rr) * D);
            x[rr][0] = f[lane]; x[rr][1] = f[lane + 64]; x[rr][2] = f[lane + 128];
        }
        float amu[4], alv[4], apgq[4], apk0[4], apk1[4];
        #pragma unroll
        for (int rr = 0; rr < 4; rr++) {
            amu[rr]  = dot4(x[rr][0], U0) + dot4(x[rr][1], U1) + dot4(x[rr][2], U2);
            alv[rr]  = dot4(x[rr][0], L0) + dot4(x[rr][1], L1) + dot4(x[rr][2], L2);
            apgq[rr] = dot4(x[rr][0], Q0) + dot4(x[rr][1], Q1) + dot4(x[rr][2], Q2);
            apk0[rr] = dot4(x[rr][0], P0) + dot4(x[rr][1], P1) + dot4(x[rr][2], P2);
            apk1[rr] = dot4(x[rr][0], R0) + dot4(x[rr][1], R1) + dot4(x[rr][2], R2);
        }
        #pragma unroll
        for (int rr = 0; rr < 4; rr++) {
            amu[rr] = wave_reduce(amu[rr]);  alv[rr] = wave_reduce(alv[rr]);
            apgq[rr] = wave_reduce(apgq[rr]);
            apk0[rr] = wave_reduce(apk0[rr]); apk1[rr] = wave_reduce(apk1[rr]);
        }
        if (lane == 0) {
            float cmu = ws[OFF_CMU + m], clv = ws[OFF_CLV + m];
            float cpgq = ws[OFF_CPGQ + m];
            float cpk0 = ws[OFF_CPK + p0], cpk1 = ws[OFF_CPK + p1];
            float klsum = 0.f;
            #pragma unroll
            for (int rr = 0; rr < 4; rr++) {
                int row = row0 + rr;
                int rem = row % (B * S);
                int b = rem / S, s = rem % S;
                float muv = amu[rr] + cmu;
                float lvv = alv[rr] + clv;
                ws[OFF_MU + row] = muv;
                ws[OFF_LV + row] = lvv;
                ws[OFF_PKPRE + (p0 * B + b) * S + s] = apk0[rr] + cpk0;
                ws[OFF_PKPRE + (p1 * B + b) * S + s] = apk1[rr] + cpk1;
                if (s == 0) ws[OFF_PQPRE + m * B + b] = apgq[rr] + cpgq;
                klsum += 1.0f + lvv - muv * muv - __expf(lvv);
            }
            klred[wave] = klsum;
        }
        __syncthreads();
        if (threadIdx.x == 0)
            atomicAdd(ws + OFF_KL, -(klred[0] + klred[1] + klred[2] + klred[3]));
    } else if (blk < 1632) {
        // red_q: reduce Q partials + bias; also qbk for both pairs. (i,b)
        int rb = blk - 1536;
        int i = rb / B, b = rb % B;
        int fbase = (i * B + b) * D;
        int t = threadIdx.x;
        __shared__ float4 qsh[192];
        __shared__ float redsh[8];
        if (t < 192) {
            float4 a = *(const float4*)&bq[i * D + t * 4];
            #pragma unroll
            for (int kc = 0; kc < 24; kc++) {
                float4 v = *(const float4*)&ws[OFF_ARENA + kc * 73728 + fbase + t * 4];
                a.x += v.x; a.y += v.y; a.z += v.z; a.w += v.w;
            }
            *(float4*)&ws[OFF_Q + fbase + t * 4] = a;
            qsh[t] = a;
        }
        __syncthreads();
        int jA = (i == 0) ? 1 : 0, jB = (i == 2) ? 1 : 2;
        float pA_ = 0.f, pB_ = 0.f;
        if (t < 192) {
            float4 q = qsh[t];
            pA_ = dot4(q, *(const float4*)&bk[jA * D + t * 4]);
            pB_ = dot4(q, *(const float4*)&bk[jB * D + t * 4]);
        }
        pA_ = wave_reduce(pA_); pB_ = wave_reduce(pB_);
        int wave = t >> 6, lane = t & 63;
        if (lane == 0) { redsh[wave] = pA_; redsh[4 + wave] = pB_; }
        __syncthreads();
        if (t == 0) {
            ws[OFF_QBK + (2 * i) * B + b]     = redsh[0] + redsh[1] + redsh[2] + redsh[3];
            ws[OFF_QBK + (2 * i + 1) * B + b] = redsh[4] + redsh[5] + redsh[6] + redsh[7];
        }
    } else {
        // qk partials with WkT, reducing Q partials inline. (j 3, vg 8, kc 12 (64 k))
        int qb = blk - 1632;
        int j = qb / 96, r = qb % 96, vg = r / 12, kc = r % 12;
        int kbase = kc * 64;
        int i1 = (j == 0) ? 1 : 0, i2 = (j == 2) ? 1 : 2;
        __shared__ __align__(16) float xs[64][8];
        for (int idx = threadIdx.x; idx < 512; idx += 256) {
            int d = idx / 8, v = idx % 8;
            int v64 = vg * 8 + v;
            int i_ = (v64 < 32) ? i1 : i2, b = v64 & 31;
            int row = (i_ * 32 + b) * 768 + kbase + d;
            float a = bq[i_ * 768 + kbase + d];
            #pragma unroll
            for (int kc2 = 0; kc2 < 24; kc2++) a += ws[OFF_ARENA + kc2 * 73728 + row];
            xs[d][v] = a;
        }
        __syncthreads();
        if (threadIdx.x < 192) {
            int e4 = threadIdx.x * 4;
            const float* Wm = ws + OFF_WKT + j * D * D + kbase * D + e4;
            float4 acc[8];
            #pragma unroll
            for (int bb = 0; bb < 8; bb++) acc[bb] = make_float4(0.f, 0.f, 0.f, 0.f);
            for (int k = 0; k < 64; k++) {
                float4 w = *(const float4*)(Wm + k * D);
                float4 x0 = *(const float4*)&xs[k][0];
                float4 x1 = *(const float4*)&xs[k][4];
                fma4(acc[0], x0.x, w); fma4(acc[1], x0.y, w);
                fma4(acc[2], x0.z, w); fma4(acc[3], x0.w, w);
                fma4(acc[4], x1.x, w); fma4(acc[5], x1.y, w);
                fma4(acc[6], x1.z, w); fma4(acc[7], x1.w, w);
            }
            #pragma unroll
            for (int v = 0; v < 8; v++)
                *(float4*)&ws[OFF_ARENA2 + kc * 147456 + (j * 64 + vg * 8 + v) * 768 + e4] = acc[v];
        }
    }
}

// L3: fused QK-reduce + raw scores + gates + online softmax + weighted feats sum.
// 192 blocks (j 3, b 32, half 2 of S) x 1024 threads. Unnormalized partial sums +
// per-half (m,l) are combined analytically in k_agg2.
__global__ __launch_bounds__(1024) void k_attn(const float* feats, const float* eps,
                                               const float* dyn, float* ws) {
    int blk = blockIdx.x;
    int j = blk / 64, r = blk % 64, b = r / 2, h = r & 1;
    int i1 = (j == 0) ? 1 : 0, i2 = (j == 2) ? 1 : 2;
    int pA = 2 * i1 + ((j < i1) ? j : j - 1);
    int pB = 2 * i2 + ((j < i2) ? j : j - 1);
    __shared__ __align__(16) float q[2][768];
    __shared__ float pk[2][128];
    __shared__ float sch[2][32], wch[2][32];
    __shared__ float scal[2], pqs[2];
    int t = threadIdx.x;
    float dynv = dyn[0];
    if (t < 384) {
        int slot = t / 192;
        int d4 = (t % 192) * 4;
        int vg = slot * 32 + b;
        const float* base = ws + OFF_ARENA2 + (j * 64 + vg) * 768 + d4;
        float4 a = make_float4(0.f, 0.f, 0.f, 0.f);
        #pragma unroll
        for (int kc = 0; kc < 12; kc++) {
            float4 p = *(const float4*)(base + kc * 147456);
            a.x += p.x; a.y += p.y; a.z += p.z; a.w += p.w;
        }
        *(float4*)&q[slot][d4] = a;
    } else if (t < 640) {
        int t2 = t - 384, slot = t2 >> 7, tt = t2 & 127;
        int k = h * 128 + tt;
        int iq = slot ? i2 : i1, p = slot ? pB : pA;
        float mu = ws[OFF_MU + (iq * B + b) * S + k];
        float lv = ws[OFF_LV + (iq * B + b) * S + k];
        float e  = eps[(p * B + b) * S + k];
        float g  = sigmoidf(mu + dynv * __expf(0.5f * lv) * e);
        pk[slot][tt] = sigmoidf(ws[OFF_PKPRE + (p * B + b) * S + k]) * g;
    } else if (t < 642) {
        int slot = t - 640;
        int iq = slot ? i2 : i1, p = slot ? pB : pA;
        float mu0 = ws[OFF_MU + (iq * B + b) * S];
        float lv0 = ws[OFF_LV + (iq * B + b) * S];
        float e0  = eps[(p * B + b) * S];
        float g0  = sigmoidf(mu0 + dynv * __expf(0.5f * lv0) * e0);
        pqs[slot] = sigmoidf(ws[OFF_PQPRE + iq * B + b]) * g0;
    }
    __syncthreads();
    float qbkA = ws[OFF_QBK + pA * B + b];
    float qbkB = ws[OFF_QBK + pB * B + b];
    const float* fb = feats + (size_t)((j * B + b) * S + h * 128) * D;
    float accA = 0.f, accB = 0.f;
    float mloc = -1e30f, lloc = 0.f;
    int w = t >> 6, lane = t & 63;
    for (int c = 0; c < 4; c++) {
        // dot phase: 16 waves x 2 rows = 32 rows
        #pragma unroll
        for (int e = 0; e < 2; e++) {
            int rloc = c * 32 + (w << 1) + e;
            const float4* f4 = (const float4*)(fb + (size_t)rloc * D);
            float4 x0 = f4[lane], x1 = f4[lane + 64], x2 = f4[lane + 128];
            const float4* qa4 = (const float4*)&q[0][0];
            const float4* qb4 = (const float4*)&q[1][0];
            float dA = dot4(x0, qa4[lane]) + dot4(x1, qa4[lane + 64]) + dot4(x2, qa4[lane + 128]);
            float dB = dot4(x0, qb4[lane]) + dot4(x1, qb4[lane + 64]) + dot4(x2, qb4[lane + 128]);
            dA = wave_reduce(dA); dB = wave_reduce(dB);
            if (lane == 0) {
                int kk = (w << 1) + e;
                sch[0][kk] = (dA + qbkA) * SCALE * pqs[0] * pk[0][rloc];
                sch[1][kk] = (dB + qbkB) * SCALE * pqs[1] * pk[1][rloc];
            }
        }
        __syncthreads();
        if (t < 2) {
            float mc = -1e30f;
            #pragma unroll
            for (int k = 0; k < 32; k++) mc = fmaxf(mc, sch[t][k]);
            float mn = fmaxf(mloc, mc);
            float f = __expf(mloc - mn);
            float ssum = 0.f;
            #pragma unroll
            for (int k = 0; k < 32; k++) {
                float wv = __expf(sch[t][k] - mn);
                wch[t][k] = wv; ssum += wv;
            }
            lloc = lloc * f + ssum;
            mloc = mn;
            scal[t] = f;
        }
        __syncthreads();
        if (t < 768) {
            accA *= scal[0]; accB *= scal[1];
            const float* fcol = fb + (size_t)(c * 32) * D + t;
            #pragma unroll 8
            for (int k = 0; k < 32; k++) {
                float fv = fcol[(size_t)k * D];
                accA += wch[0][k] * fv;
                accB += wch[1][k] * fv;
            }
        }
        __syncthreads();
    }
    if (t < 768) {
        ws[OFF_FSUM + h * 147456 + (pA * B + b) * D + t] = accA;
        ws[OFF_FSUM + h * 147456 + (pB * B + b) * D + t] = accB;
    }
    if (t < 2) {
        int p = t ? pB : pA;
        float* mh = ws + OFF_MLH + (p * B + b) * 4 + h * 2;
        mh[0] = mloc; mh[1] = lloc;
    }
}

// L4: agg partials (2 Wv fused), combining the two S-halves via (m,l).
// 288 blocks (i 3, bg 4, kc 24 (32 k)).
__global__ __launch_bounds__(192) void k_agg2(const float* Wv, float* ws) {
    int blk = blockIdx.x;
    int i = blk / 96, r = blk % 96, bg = r / 24, kc = r % 24;
    int kbase = kc * 32;
    int j0 = (i == 0) ? 1 : 0, j1 = (i == 2) ? 1 : 2;
    int p0 = 2 * i, p1 = 2 * i + 1;
    __shared__ __align__(16) float xs0[32][8], xs1[32][8];
    __shared__ float comb[2][2][8];
    if (threadIdx.x < 16) {
        int slot = threadIdx.x >> 3, bb = threadIdx.x & 7;
        int p = slot ? p1 : p0;
        int b = bg * 8 + bb;
        const float* mh = ws + OFF_MLH + (p * B + b) * 4;
        float m0 = mh[0], l0 = mh[1], m1 = mh[2], l1 = mh[3];
        float Mx = fmaxf(m0, m1);
        float e0 = __expf(m0 - Mx), e1 = __expf(m1 - Mx);
        float L = e0 * l0 + e1 * l1;
        comb[slot][0][bb] = e0 / L;
        comb[slot][1][bb] = e1 / L;
    }
    __syncthreads();
    for (int idx = threadIdx.x; idx < 256; idx += 192) {
        int d = idx / 8, bb = idx % 8;
        int row0 = (p0 * B + bg * 8 + bb) * D + kbase + d;
        int row1 = (p1 * B + bg * 8 + bb) * D + kbase + d;
        xs0[d][bb] = comb[0][0][bb] * ws[OFF_FSUM + row0] + comb[0][1][bb] * ws[OFF_FSUM + 147456 + row0];
        xs1[d][bb] = comb[1][0][bb] * ws[OFF_FSUM + row1] + comb[1][1][bb] * ws[OFF_FSUM + 147456 + row1];
    }
    __syncthreads();
    int e4 = threadIdx.x * 4;
    const float* W0 = Wv + j0 * D * D + kbase * D + e4;
    const float* W1 = Wv + j1 * D * D + kbase * D + e4;
    float4 acc[8];
    #pragma unroll
    for (int bb = 0; bb < 8; bb++) acc[bb] = make_float4(0.f, 0.f, 0.f, 0.f);
    for (int k = 0; k < 32; k++) {
        float4 w0 = *(const float4*)(W0 + k * D);
        float4 w1 = *(const float4*)(W1 + k * D);
        float4 a0 = *(const float4*)&xs0[k][0];
        float4 a1 = *(const float4*)&xs0[k][4];
        float4 b0 = *(const float4*)&xs1[k][0];
        float4 b1 = *(const float4*)&xs1[k][4];
        fma4(acc[0], a0.x, w0); fma4(acc[1], a0.y, w0);
        fma4(acc[2], a0.z, w0); fma4(acc[3], a0.w, w0);
        fma4(acc[4], a1.x, w0); fma4(acc[5], a1.y, w0);
        fma4(acc[6], a1.z, w0); fma4(acc[7], a1.w, w0);
        fma4(acc[0], b0.x, w1); fma4(acc[1], b0.y, w1);
        fma4(acc[2], b0.z, w1); fma4(acc[3], b0.w, w1);
        fma4(acc[4], b1.x, w1); fma4(acc[5], b1.y, w1);
        fma4(acc[6], b1.z, w1); fma4(acc[7], b1.w, w1);
    }
    #pragma unroll
    for (int bb = 0; bb < 8; bb++)
        *(float4*)&ws[OFF_ARENA + kc * 73728 + (i * 32 + bg * 8 + bb) * 768 + e4] = acc[bb];
}

// L5: E/G partials, reducing agg partials (+bv) inline. 288 blocks (kind 2, i 3, bg 4, kc 12).
__global__ __launch_bounds__(192) void k_eg2(const float* WE_w, const float* Wh_w,
                                             const float* Wqc_w, const float* bv, float* ws) {
    int blk = blockIdx.x;
    int kind = blk / 144, r = blk % 144;
    int i = r / 48, r2 = r % 48, bg = r2 / 12, kc = r2 % 12;
    int kbase = kc * 64;
    int j0 = (i == 0) ? 1 : 0, j1 = (i == 2) ? 1 : 2;
    __shared__ __align__(16) float xa[64][8], xq[64][8];
    for (int idx = threadIdx.x; idx < 512; idx += 192) {
        int d = idx / 8, bb = idx % 8;
        int row = (i * 32 + bg * 8 + bb) * 768 + kbase + d;
        float a = bv[j0 * 768 + kbase + d] + bv[j1 * 768 + kbase + d];
        #pragma unroll
        for (int kc2 = 0; kc2 < 24; kc2++) a += ws[OFF_ARENA + kc2 * 73728 + row];
        xa[d][bb] = a;
        if (kind) xq[d][bb] = ws[OFF_Q + row];
    }
    __syncthreads();
    int e4 = threadIdx.x * 4;
    float4 acc[8];
    #pragma unroll
    for (int bb = 0; bb < 8; bb++) acc[bb] = make_float4(0.f, 0.f, 0.f, 0.f);
    if (kind == 0) {
        const float* Wm = WE_w + i * D * D + kbase * D + e4;
        for (int k = 0; k < 64; k++) {
            float4 w = *(const float4*)(Wm + k * D);
            float4 a0 = *(const float4*)&xa[k][0];
            float4 a1 = *(const float4*)&xa[k][4];
            fma4(acc[0], a0.x, w); fma4(acc[1], a0.y, w);
            fma4(acc[2], a0.z, w); fma4(acc[3], a0.w, w);
            fma4(acc[4], a1.x, w); fma4(acc[5], a1.y, w);
            fma4(acc[6], a1.z, w); fma4(acc[7], a1.w, w);
        }
    } else {
        const float* Wh = Wh_w + i * D * D + kbase * D + e4;
        const float* Wc = Wqc_w + i * D * D + kbase * D + e4;
        for (int k = 0; k < 64; k++) {
            float4 wh = *(const float4*)(Wh + k * D);
            float4 wc = *(const float4*)(Wc + k * D);
            float4 a0 = *(const float4*)&xa[k][0];
            float4 a1 = *(const float4*)&xa[k][4];
            float4 q0 = *(const float4*)&xq[k][0];
            float4 q1 = *(const float4*)&xq[k][4];
            fma4(acc[0], a0.x, wh); fma4(acc[1], a0.y, wh);
            fma4(acc[2], a0.z, wh); fma4(acc[3], a0.w, wh);
            fma4(acc[4], a1.x, wh); fma4(acc[5], a1.y, wh);
            fma4(acc[6], a1.z, wh); fma4(acc[7], a1.w, wh);
            fma4(acc[0], q0.x, wc); fma4(acc[1], q0.y, wc);
            fma4(acc[2], q0.z, wc); fma4(acc[3], q0.w, wc);
            fma4(acc[4], q1.x, wc); fma4(acc[5], q1.y, wc);
            fma4(acc[6], q1.z, wc); fma4(acc[7], q1.w, wc);
        }
    }
    int base = OFF_ARENA2 + (kind ? 884736 : 0) + kc * 73728;
    #pragma unroll
    for (int bb = 0; bb < 8; bb++)
        *(float4*)&ws[base + (i * 32 + bg * 8 + bb) * 768 + e4] = acc[bb];
}

// L6: reduce E/G partials (+bias+relu) inline, then LayerNorm(E)*LayerNorm(G) -> fused.
// 96 blocks (i,b).
__global__ __launch_bounds__(256) void k_ln2(const float* WE_b, const float* Wh_b,
        const float* Wqc_b,
        const float* lnE_g, const float* lnE_b,
        const float* lnG_g, const float* lnG_b, float* ws) {
    int blk = blockIdx.x;
    int i = blk / B, b = blk % B;
    int row = (i * B + b) * D;
    int t = threadIdx.x;
    float e[3], g[3];
    #pragma unroll
    for (int u = 0; u < 3; u++) {
        int dd = t + u * 256;
        float ev = WE_b[i * D + dd];
        float gv = Wh_b[i * D + dd] + Wqc_b[i * D + dd];
        #pragma unroll
        for (int kc = 0; kc < 12; kc++) {
            ev += ws[OFF_ARENA2 + kc * 73728 + row + dd];
            gv += ws[OFF_ARENA2 + 884736 + kc * 73728 + row + dd];
        }
        e[u] = fmaxf(ev, 0.f);
        g[u] = fmaxf(gv, 0.f);
    }
    __shared__ float r1[256], r2[256], r3[256], r4[256];
    r1[t] = e[0] + e[1] + e[2];
    r2[t] = e[0] * e[0] + e[1] * e[1] + e[2] * e[2];
    r3[t] = g[0] + g[1] + g[2];
    r4[t] = g[0] * g[0] + g[1] * g[1] + g[2] * g[2];
    __syncthreads();
    for (int st = 128; st > 0; st >>= 1) {
        if (t < st) { r1[t] += r1[t + st]; r2[t] += r2[t + st]; r3[t] += r3[t + st]; r4[t] += r4[t + st]; }
        __syncthreads();
    }
    float mE = r1[0] * (1.0f / D), vE = r2[0] * (1.0f / D) - mE * mE;
    float mG = r3[0] * (1.0f / D), vG = r4[0] * (1.0f / D) - mG * mG;
    float sE = rsqrtf(vE + LN_EPS), sG = rsqrtf(vG + LN_EPS);
    float* o = ws + OFF_FUSED + b * MD + i * D;
    const float* eg = lnE_g + i * D; const float* ebv = lnE_b + i * D;
    const float* gg = lnG_g + i * D; const float* gbv = lnG_b + i * D;
    #pragma unroll
    for (int u = 0; u < 3; u++) {
        int dd = t + u * 256;
        o[dd] = ((e[u] - mE) * sE * eg[dd] + ebv[dd]) * ((g[u] - mG) * sG * gg[dd] + gbv[dd]);
    }
}

// L7: out GEMM partials accumulated atomically into d_out (pre-zeroed). 144 blocks (bg 4, kc 36).
__global__ __launch_bounds__(256) void k_out2(const float* out_w, const float* out_b,
                                              float* ws, float* out) {
    int blk = blockIdx.x;
    int bg = blk / 36, kc = blk % 36;
    int kbase = kc * 64;
    __shared__ __align__(16) float xs[64][8];
    for (int idx = threadIdx.x; idx < 512; idx += 256) {
        int d = idx / 8, bb = idx % 8;
        xs[d][bb] = ws[OFF_FUSED + (bg * 8 + bb) * MD + kbase + d];
    }
    __syncthreads();
    int e4 = threadIdx.x * 4;
    const float* Wm = out_w + kbase * H + e4;
    float4 acc[8];
    #pragma unroll
    for (int bb = 0; bb < 8; bb++) acc[bb] = make_float4(0.f, 0.f, 0.f, 0.f);
    for (int k = 0; k < 64; k++) {
        float4 w = *(const float4*)(Wm + k * H);
        float4 x0 = *(const float4*)&xs[k][0];
        float4 x1 = *(const float4*)&xs[k][4];
        fma4(acc[0], x0.x, w); fma4(acc[1], x0.y, w);
        fma4(acc[2], x0.z, w); fma4(acc[3], x0.w, w);
        fma4(acc[4], x1.x, w); fma4(acc[5], x1.y, w);
        fma4(acc[6], x1.z, w); fma4(acc[7], x1.w, w);
    }
    float4 bias = make_float4(0.f, 0.f, 0.f, 0.f);
    if (kc == 0) bias = *(const float4*)&out_b[e4];
    #pragma unroll
    for (int bb = 0; bb < 8; bb++) {
        float* dst = out + (bg * 8 + bb) * H + e4;
        atomicAdd(dst + 0, acc[bb].x + bias.x);
        atomicAdd(dst + 1, acc[bb].y + bias.y);
        atomicAdd(dst + 2, acc[bb].z + bias.z);
        atomicAdd(dst + 3, acc[bb].w + bias.w);
    }
    if (blk == 0 && threadIdx.x == 0) out[B * H] = ws[OFF_KL];
}

extern "C" void kernel_launch(void* const* d_in, const int* in_sizes, int n_in,
                              void* d_out, int out_size, void* d_ws, size_t ws_size,
                              hipStream_t stream) {
    const float* feats = (const float*)d_in[0];
    const float* Wq    = (const float*)d_in[1];
    const float* bq    = (const float*)d_in[2];
    const float* Wk    = (const float*)d_in[3];
    const float* bk    = (const float*)d_in[4];
    const float* Wv    = (const float*)d_in[5];
    const float* bv    = (const float*)d_in[6];
    const float* pgq_w = (const float*)d_in[7];
    const float* pgq_b = (const float*)d_in[8];
    const float* pgk_w = (const float*)d_in[9];
    const float* pgk_b = (const float*)d_in[10];
    const float* mu_w  = (const float*)d_in[11];
    const float* mu_b  = (const float*)d_in[12];
    const float* lv_w  = (const float*)d_in[13];
    const float* lv_b  = (const float*)d_in[14];
    const float* dyn   = (const float*)d_in[15];
    const float* WE_w  = (const float*)d_in[16];
    const float* WE_b  = (const float*)d_in[17];
    const float* Wh_w  = (const float*)d_in[18];
    const float* Wh_b  = (const float*)d_in[19];
    const float* Wqc_w = (const float*)d_in[20];
    const float* Wqc_b = (const float*)d_in[21];
    const float* lnE_g = (const float*)d_in[22];
    const float* lnE_b = (const float*)d_in[23];
    const float* lnG_g = (const float*)d_in[24];
    const float* lnG_b = (const float*)d_in[25];
    const float* out_w = (const float*)d_in[26];
    const float* out_b = (const float*)d_in[27];
    const float* eps   = (const float*)d_in[28];
    float* ws  = (float*)d_ws;
    float* out = (float*)d_out;

    hipMemsetAsync((char*)d_ws + OFF_KL * sizeof(float), 0, sizeof(float), stream);
    hipMemsetAsync(d_out, 0, (size_t)out_size, stream);

    k_prep2<<<807, 256, 0, stream>>>(feats, Wq, Wk, bq, bk, mu_w, mu_b, lv_w, lv_b,
                                     pgq_w, pgq_b, pgk_w, pgk_b, ws);
    k_stats2<<<1920, 256, 0, stream>>>(feats, bq, bk, ws);
    k_attn<<<192, 1024, 0, stream>>>(feats, eps, dyn, ws);
    k_agg2<<<288, 192, 0, stream>>>(Wv, ws);
    k_eg2<<<288, 192, 0, stream>>>(WE_w, Wh_w, Wqc_w, bv, ws);
    k_ln2<<<96, 256, 0, stream>>>(WE_b, Wh_b, Wqc_b, lnE_g, lnE_b, lnG_g, lnG_b, ws);
    k_out2<<<144, 256, 0, stream>>>(out_w, out_b, ws, out);
}

// Round 2
// 348.083 us; speedup vs baseline: 1.0499x; 1.0426x over previous
//
#include <hip/hip_runtime.h>

// Problem constants (fixed by the reference)
#define M 3
#define B 32
#define S 256
#define D 768
#define H 1024
#define MD (M * D)          // 2304
#define NP (M * (M - 1))    // 6 ordered (i,j) pairs
#define SCALE 0.03608439182435161f  // 1/sqrt(768)
#define LN_EPS 1e-5f

// Workspace layout (float offsets).
#define OFF_WMU   0         // [M][D]
#define OFF_WLV   2304      // [M][D]
#define OFF_WPGQ  4608      // [M][D]
#define OFF_WPK   6912      // [NP][D]
#define OFF_CMU   11520     // [M]
#define OFF_CLV   11523     // [M]
#define OFF_CPGQ  11526     // [M]
#define OFF_CPK   11529     // [NP]
#define OFF_MU    11552     // [M][B][S]
#define OFF_LV    36128     // [M][B][S]
#define OFF_PKPRE 60704     // [NP][B][S]
#define OFF_PQPRE 109856    // [M][B]
#define OFF_Q     109952    // [M][B][D]
#define OFF_QBK   183680    // [NP][B]
#define OFF_QK    183872    // [NP][B][D] reduced qk (147456)
#define OFF_MLH   331328    // [NP][B][4(h)][2(m,l)] = 1536
#define OFF_AGG   332864    // [M][B][D]
#define OFF_E     406592    // [M][B][D]
#define OFF_G     480320    // [M][B][D]
#define OFF_FUSED 554048    // [B][MD]
#define OFF_KL    627776    // [1]
#define OFF_FSUM  627840    // [4(h)][NP][B][D] (h stride 147456) = 589824
#define OFF_WKT   1217664   // [M][D][D] Wk transposed (1769472)
#define OFF_ARENA 2987136   // Q partials (24 slots) then agg partials (48 slots), stride 73728
#define OFF_ARENA2 6526080  // qk partials (24 slots, stride 147456) then E/G partials (72 slots, stride 73728)

__device__ __forceinline__ float wave_reduce(float v) {
    #pragma unroll
    for (int o = 32; o > 0; o >>= 1) v += __shfl_down(v, o, 64);
    return v;
}

__device__ __forceinline__ float sigmoidf(float x) {
    return 1.0f / (1.0f + __expf(-x));
}

__device__ __forceinline__ float dot4(float4 a, float4 b) {
    return a.x * b.x + a.y * b.y + a.z * b.z + a.w * b.w;
}

__device__ __forceinline__ void fma4(float4& a, float s, float4 w) {
    a.x += s * w.x; a.y += s * w.y; a.z += s * w.z; a.w += s * w.w;
}

// L1: fused prep + Q partials.
// blocks 0..71 vector-dots, 72..86 scalar consts, 87..518 Wk transpose,
// 519..806 Q GEMV partials (feats_s0 @ Wq, split-K 24).
__global__ __launch_bounds__(256) void k_prep2(const float* feats,
        const float* Wq, const float* Wk,
        const float* bq, const float* bk,
        const float* mu_w, const float* mu_b, const float* lv_w, const float* lv_b,
        const float* pgq_w, const float* pgq_b, const float* pgk_w, const float* pgk_b,
        float* ws) {
    int blk = blockIdx.x;
    if (blk < 72) {
        int mat = blk / 12, rg = blk % 12;
        const float* Wm; const float *va, *vb, *vc;
        float *oa, *ob, *oc; int nv;
        if (mat < 3) {
            int i = mat;
            Wm = Wq + i * D * D;
            va = mu_w + i * D; vb = lv_w + i * D; vc = pgq_w + i * D;
            oa = ws + OFF_WMU + i * D; ob = ws + OFF_WLV + i * D; oc = ws + OFF_WPGQ + i * D;
            nv = 3;
        } else {
            int j = mat - 3;
            int i1 = (j == 0) ? 1 : 0, i2 = (j == 2) ? 1 : 2;
            int p1 = 2 * i1 + ((j < i1) ? j : j - 1);
            int p2 = 2 * i2 + ((j < i2) ? j : j - 1);
            Wm = Wk + j * D * D;
            va = pgk_w + i1 * D; vb = pgk_w + i2 * D; vc = va;
            oa = ws + OFF_WPK + p1 * D; ob = ws + OFF_WPK + p2 * D; oc = oa;
            nv = 2;
        }
        int wave = threadIdx.x >> 6, lane = threadIdx.x & 63;
        const float4* va4 = (const float4*)va;
        const float4* vb4 = (const float4*)vb;
        const float4* vc4 = (const float4*)vc;
        float4 A0 = va4[lane], A1 = va4[lane + 64], A2 = va4[lane + 128];
        float4 B0 = vb4[lane], B1 = vb4[lane + 64], B2 = vb4[lane + 128];
        float4 C0 = vc4[lane], C1 = vc4[lane + 64], C2 = vc4[lane + 128];
        int base = rg * 64 + wave * 16;
        for (int r = 0; r < 16; r += 2) {
            const float4* rowP = (const float4*)(Wm + (base + r) * D);
            const float4* rowQ = (const float4*)(Wm + (base + r + 1) * D);
            float4 x0 = rowP[lane], x1 = rowP[lane + 64], x2 = rowP[lane + 128];
            float4 y0 = rowQ[lane], y1 = rowQ[lane + 64], y2 = rowQ[lane + 128];
            float daP = dot4(x0, A0) + dot4(x1, A1) + dot4(x2, A2);
            float dbP = dot4(x0, B0) + dot4(x1, B1) + dot4(x2, B2);
            float dcP = dot4(x0, C0) + dot4(x1, C1) + dot4(x2, C2);
            float daQ = dot4(y0, A0) + dot4(y1, A1) + dot4(y2, A2);
            float dbQ = dot4(y0, B0) + dot4(y1, B1) + dot4(y2, B2);
            float dcQ = dot4(y0, C0) + dot4(y1, C1) + dot4(y2, C2);
            daP = wave_reduce(daP); dbP = wave_reduce(dbP);
            daQ = wave_reduce(daQ); dbQ = wave_reduce(dbQ);
            if (nv == 3) { dcP = wave_reduce(dcP); dcQ = wave_reduce(dcQ); }
            if (lane == 0) {
                oa[base + r] = daP; ob[base + r] = dbP;
                oa[base + r + 1] = daQ; ob[base + r + 1] = dbQ;
                if (nv == 3) { oc[base + r] = dcP; oc[base + r + 1] = dcQ; }
            }
        }
    } else if (blk < 87) {
        int job = blk - 72;
        const float *a, *bvec; float bias; float* out;
        if (job < 3)      { int i = job;     a = bq + i * D; bvec = mu_w + i * D;  bias = mu_b[i];  out = ws + OFF_CMU + i; }
        else if (job < 6) { int i = job - 3; a = bq + i * D; bvec = lv_w + i * D;  bias = lv_b[i];  out = ws + OFF_CLV + i; }
        else if (job < 9) { int i = job - 6; a = bq + i * D; bvec = pgq_w + i * D; bias = pgq_b[i]; out = ws + OFF_CPGQ + i; }
        else {
            int p = job - 9, i = p / 2, c = p % 2, j = c + (c >= i ? 1 : 0);
            a = bk + j * D; bvec = pgk_w + i * D; bias = pgk_b[i]; out = ws + OFF_CPK + p;
        }
        int t = threadIdx.x;
        float part = 0.f;
        if (t < 192) part = dot4(((const float4*)a)[t], ((const float4*)bvec)[t]);
        part = wave_reduce(part);
        __shared__ float r[4];
        if ((t & 63) == 0) r[t >> 6] = part;
        __syncthreads();
        if (t == 0) *out = r[0] + r[1] + r[2] + r[3] + bias;
    } else if (blk < 519) {
        int r = blk - 87;
        int j = r / 144; r = r % 144;
        int d0 = (r / 12) * 64, e0 = (r % 12) * 64;
        __shared__ float tile[64][65];
        const float* src = Wk + j * D * D;
        for (int idx = threadIdx.x; idx < 4096; idx += 256) {
            int rr = idx / 64, cc = idx % 64;
            tile[rr][cc] = src[(d0 + rr) * D + e0 + cc];
        }
        __syncthreads();
        float* dst = ws + OFF_WKT + j * D * D;
        for (int idx = threadIdx.x; idx < 4096; idx += 256) {
            int rr = idx / 64, cc = idx % 64;
            dst[(e0 + rr) * D + d0 + cc] = tile[cc][rr];
        }
    } else {
        // Q partials: blocks (i 3, bg 4 (8 b), kc 24 (32 k))
        int qb = blk - 519;
        int i = qb / 96, r = qb % 96, bg = r / 24, kc = r % 24;
        int kbase = kc * 32;
        __shared__ __align__(16) float xs[32][8];
        for (int idx = threadIdx.x; idx < 256; idx += 256) {
            int d = idx & 31, bb = idx >> 5;
            xs[d][bb] = feats[((size_t)(i * B + bg * 8 + bb) * S) * D + kbase + d];
        }
        __syncthreads();
        if (threadIdx.x < 192) {
            int e4 = threadIdx.x * 4;
            const float* Wm = Wq + i * D * D + kbase * D + e4;
            float4 acc[8];
            #pragma unroll
            for (int bb = 0; bb < 8; bb++) acc[bb] = make_float4(0.f, 0.f, 0.f, 0.f);
            for (int k = 0; k < 32; k++) {
                float4 w = *(const float4*)(Wm + k * D);
                float4 x0 = *(const float4*)&xs[k][0];
                float4 x1 = *(const float4*)&xs[k][4];
                fma4(acc[0], x0.x, w); fma4(acc[1], x0.y, w);
                fma4(acc[2], x0.z, w); fma4(acc[3], x0.w, w);
                fma4(acc[4], x1.x, w); fma4(acc[5], x1.y, w);
                fma4(acc[6], x1.z, w); fma4(acc[7], x1.w, w);
            }
            #pragma unroll
            for (int bb = 0; bb < 8; bb++)
                *(float4*)&ws[OFF_ARENA + kc * 73728 + (i * 32 + bg * 8 + bb) * 768 + e4] = acc[bb];
        }
    }
}

// L2: qk GEMV first (long blocks, 576), then stats (1536), then red_q (96). Total 2208.
__global__ __launch_bounds__(256) void k_stats2(const float* feats,
        const float* bq, const float* bk, float* ws) {
    int blk = blockIdx.x;
    if (blk < 576) {
        // qk partials with WkT, reducing Q partials inline. (j 3, vg 8, kc 24 (32 k))
        int j = blk / 192, r = blk % 192, vg = r / 24, kc = r % 24;
        int kbase = kc * 32;
        int i1 = (j == 0) ? 1 : 0, i2 = (j == 2) ? 1 : 2;
        __shared__ __align__(16) float xs[32][8];
        for (int idx = threadIdx.x; idx < 256; idx += 256) {
            int d = idx & 31, v = idx >> 5;
            int v64 = vg * 8 + v;
            int i_ = (v64 < 32) ? i1 : i2, b = v64 & 31;
            int row = (i_ * 32 + b) * 768 + kbase + d;
            float a = bq[i_ * 768 + kbase + d];
            #pragma unroll
            for (int kc2 = 0; kc2 < 24; kc2++) a += ws[OFF_ARENA + kc2 * 73728 + row];
            xs[d][v] = a;
        }
        __syncthreads();
        if (threadIdx.x < 192) {
            int e4 = threadIdx.x * 4;
            const float* Wm = ws + OFF_WKT + j * D * D + kbase * D + e4;
            float4 acc[8];
            #pragma unroll
            for (int bb = 0; bb < 8; bb++) acc[bb] = make_float4(0.f, 0.f, 0.f, 0.f);
            for (int k = 0; k < 32; k++) {
                float4 w = *(const float4*)(Wm + k * D);
                float4 x0 = *(const float4*)&xs[k][0];
                float4 x1 = *(const float4*)&xs[k][4];
                fma4(acc[0], x0.x, w); fma4(acc[1], x0.y, w);
                fma4(acc[2], x0.z, w); fma4(acc[3], x0.w, w);
                fma4(acc[4], x1.x, w); fma4(acc[5], x1.y, w);
                fma4(acc[6], x1.z, w); fma4(acc[7], x1.w, w);
            }
            #pragma unroll
            for (int v = 0; v < 8; v++)
                *(float4*)&ws[OFF_ARENA2 + kc * 147456 + (j * 64 + vg * 8 + v) * 768 + e4] = acc[v];
        }
    } else if (blk < 2112) {
        int blk2 = blk - 576;
        __shared__ float klred[4];
        int wave = threadIdx.x >> 6, lane = threadIdx.x & 63;
        int m = blk2 / 512;
        int row0 = blk2 * 16 + wave * 4;
        int i1 = (m == 0) ? 1 : 0, i2 = (m == 2) ? 1 : 2;
        int p0 = 2 * i1 + ((m < i1) ? m : m - 1);
        int p1 = 2 * i2 + ((m < i2) ? m : m - 1);
        const float4* wmu  = (const float4*)(ws + OFF_WMU + m * D);
        const float4* wlv  = (const float4*)(ws + OFF_WLV + m * D);
        const float4* wpgq = (const float4*)(ws + OFF_WPGQ + m * D);
        const float4* wpk0 = (const float4*)(ws + OFF_WPK + p0 * D);
        const float4* wpk1 = (const float4*)(ws + OFF_WPK + p1 * D);
        float4 U0 = wmu[lane],  U1 = wmu[lane + 64],  U2 = wmu[lane + 128];
        float4 L0 = wlv[lane],  L1 = wlv[lane + 64],  L2 = wlv[lane + 128];
        float4 Q0 = wpgq[lane], Q1 = wpgq[lane + 64], Q2 = wpgq[lane + 128];
        float4 P0 = wpk0[lane], P1 = wpk0[lane + 64], P2 = wpk0[lane + 128];
        float4 R0 = wpk1[lane], R1 = wpk1[lane + 64], R2 = wpk1[lane + 128];
        float4 x[4][3];
        #pragma unroll
        for (int rr = 0; rr < 4; rr++) {
            const float4* f = (const float4*)(feats + (size_t)(row0 + rr) * D);
            x[rr][0] = f[lane]; x[rr][1] = f[lane + 64]; x[rr][2] = f[lane + 128];
        }
        float amu[4], alv[4], apgq[4], apk0[4], apk1[4];
        #pragma unroll
        for (int rr = 0; rr < 4; rr++) {
            amu[rr]  = dot4(x[rr][0], U0) + dot4(x[rr][1], U1) + dot4(x[rr][2], U2);
            alv[rr]  = dot4(x[rr][0], L0) + dot4(x[rr][1], L1) + dot4(x[rr][2], L2);
            apgq[rr] = dot4(x[rr][0], Q0) + dot4(x[rr][1], Q1) + dot4(x[rr][2], Q2);
            apk0[rr] = dot4(x[rr][0], P0) + dot4(x[rr][1], P1) + dot4(x[rr][2], P2);
            apk1[rr] = dot4(x[rr][0], R0) + dot4(x[rr][1], R1) + dot4(x[rr][2], R2);
        }
        #pragma unroll
        for (int rr = 0; rr < 4; rr++) {
            amu[rr] = wave_reduce(amu[rr]);  alv[rr] = wave_reduce(alv[rr]);
            apgq[rr] = wave_reduce(apgq[rr]);
            apk0[rr] = wave_reduce(apk0[rr]); apk1[rr] = wave_reduce(apk1[rr]);
        }
        if (lane == 0) {
            float cmu = ws[OFF_CMU + m], clv = ws[OFF_CLV + m];
            float cpgq = ws[OFF_CPGQ + m];
            float cpk0 = ws[OFF_CPK + p0], cpk1 = ws[OFF_CPK + p1];
            float klsum = 0.f;
            #pragma unroll
            for (int rr = 0; rr < 4; rr++) {
                int row = row0 + rr;
                int rem = row % (B * S);
                int b = rem / S, s = rem % S;
                float muv = amu[rr] + cmu;
                float lvv = alv[rr] + clv;
                ws[OFF_MU + row] = muv;
                ws[OFF_LV + row] = lvv;
                ws[OFF_PKPRE + (p0 * B + b) * S + s] = apk0[rr] + cpk0;
                ws[OFF_PKPRE + (p1 * B + b) * S + s] = apk1[rr] + cpk1;
                if (s == 0) ws[OFF_PQPRE + m * B + b] = apgq[rr] + cpgq;
                klsum += 1.0f + lvv - muv * muv - __expf(lvv);
            }
            klred[wave] = klsum;
        }
        __syncthreads();
        if (threadIdx.x == 0)
            atomicAdd(ws + OFF_KL, -(klred[0] + klred[1] + klred[2] + klred[3]));
    } else {
        // red_q: reduce Q partials + bias; also qbk for both pairs. (i,b)
        int rb = blk - 2112;
        int i = rb / B, b = rb % B;
        int fbase = (i * B + b) * D;
        int t = threadIdx.x;
        __shared__ float4 qsh[192];
        __shared__ float redsh[8];
        if (t < 192) {
            float4 a = *(const float4*)&bq[i * D + t * 4];
            #pragma unroll
            for (int kc = 0; kc < 24; kc++) {
                float4 v = *(const float4*)&ws[OFF_ARENA + kc * 73728 + fbase + t * 4];
                a.x += v.x; a.y += v.y; a.z += v.z; a.w += v.w;
            }
            *(float4*)&ws[OFF_Q + fbase + t * 4] = a;
            qsh[t] = a;
        }
        __syncthreads();
        int jA = (i == 0) ? 1 : 0, jB = (i == 2) ? 1 : 2;
        float pA_ = 0.f, pB_ = 0.f;
        if (t < 192) {
            float4 q = qsh[t];
            pA_ = dot4(q, *(const float4*)&bk[jA * D + t * 4]);
            pB_ = dot4(q, *(const float4*)&bk[jB * D + t * 4]);
        }
        pA_ = wave_reduce(pA_); pB_ = wave_reduce(pB_);
        int wave = t >> 6, lane = t & 63;
        if (lane == 0) { redsh[wave] = pA_; redsh[4 + wave] = pB_; }
        __syncthreads();
        if (t == 0) {
            ws[OFF_QBK + (2 * i) * B + b]     = redsh[0] + redsh[1] + redsh[2] + redsh[3];
            ws[OFF_QBK + (2 * i + 1) * B + b] = redsh[4] + redsh[5] + redsh[6] + redsh[7];
        }
    }
}

// L2b: coalesced reduce of qk partials (24 slots) -> QK[p][b][d]. 144 blocks x 256.
__global__ __launch_bounds__(256) void k_redqk(float* ws) {
    int idx = blockIdx.x * 256 + threadIdx.x;
    int fidx = idx * 4;
    int row = fidx / 768, d = fidx % 768;
    int j = row / 64, v64 = row % 64;
    int b = v64 & 31, islot = v64 >> 5;
    int i_ = islot ? ((j == 2) ? 1 : 2) : ((j == 0) ? 1 : 0);
    int p = 2 * i_ + ((j < i_) ? j : j - 1);
    float4 a = make_float4(0.f, 0.f, 0.f, 0.f);
    #pragma unroll
    for (int kc = 0; kc < 24; kc++) {
        float4 v = *(const float4*)&ws[OFF_ARENA2 + kc * 147456 + fidx];
        a.x += v.x; a.y += v.y; a.z += v.z; a.w += v.w;
    }
    *(float4*)&ws[OFF_QK + (p * B + b) * D + d] = a;
}

// L3: fused scores + gates + online softmax + weighted feats sum, S split in QUARTERS.
// 384 blocks (j 3, b 32, h 4) x 1024 threads. Unnormalized partial sums + per-quarter
// (m,l) combined analytically in k_agg2.
__global__ __launch_bounds__(1024) void k_attn(const float* feats, const float* eps,
                                               const float* dyn, float* ws) {
    int blk = blockIdx.x;
    int j = blk / 128, r = blk % 128, b = r >> 2, h = r & 3;
    int i1 = (j == 0) ? 1 : 0, i2 = (j == 2) ? 1 : 2;
    int pA = 2 * i1 + ((j < i1) ? j : j - 1);
    int pB = 2 * i2 + ((j < i2) ? j : j - 1);
    __shared__ __align__(16) float q[2][768];
    __shared__ float pk[2][64];
    __shared__ float sch[2][32], wch[2][32];
    __shared__ float scal[2], pqs[2];
    int t = threadIdx.x;
    float dynv = dyn[0];
    if (t < 384) {
        int slot = t / 192;
        int d4 = (t % 192) * 4;
        int p = slot ? pB : pA;
        *(float4*)&q[slot][d4] = *(const float4*)&ws[OFF_QK + (p * B + b) * D + d4];
    } else if (t < 512) {
        int t2 = t - 384, slot = t2 >> 6, tt = t2 & 63;
        int k = h * 64 + tt;
        int iq = slot ? i2 : i1, p = slot ? pB : pA;
        float mu = ws[OFF_MU + (iq * B + b) * S + k];
        float lv = ws[OFF_LV + (iq * B + b) * S + k];
        float e  = eps[(p * B + b) * S + k];
        float g  = sigmoidf(mu + dynv * __expf(0.5f * lv) * e);
        pk[slot][tt] = sigmoidf(ws[OFF_PKPRE + (p * B + b) * S + k]) * g;
    } else if (t < 514) {
        int slot = t - 512;
        int iq = slot ? i2 : i1, p = slot ? pB : pA;
        float mu0 = ws[OFF_MU + (iq * B + b) * S];
        float lv0 = ws[OFF_LV + (iq * B + b) * S];
        float e0  = eps[(p * B + b) * S];
        float g0  = sigmoidf(mu0 + dynv * __expf(0.5f * lv0) * e0);
        pqs[slot] = sigmoidf(ws[OFF_PQPRE + iq * B + b]) * g0;
    }
    __syncthreads();
    float qbkA = ws[OFF_QBK + pA * B + b];
    float qbkB = ws[OFF_QBK + pB * B + b];
    const float* fb = feats + (size_t)((j * B + b) * S + h * 64) * D;
    float accA = 0.f, accB = 0.f;
    float mloc = -1e30f, lloc = 0.f;
    int w = t >> 6, lane = t & 63;
    for (int c = 0; c < 2; c++) {
        // dot phase: 16 waves x 2 rows = 32 rows
        #pragma unroll
        for (int e = 0; e < 2; e++) {
            int rloc = c * 32 + (w << 1) + e;
            const float4* f4 = (const float4*)(fb + (size_t)rloc * D);
            float4 x0 = f4[lane], x1 = f4[lane + 64], x2 = f4[lane + 128];
            const float4* qa4 = (const float4*)&q[0][0];
            const float4* qb4 = (const float4*)&q[1][0];
            float dA = dot4(x0, qa4[lane]) + dot4(x1, qa4[lane + 64]) + dot4(x2, qa4[lane + 128]);
            float dB = dot4(x0, qb4[lane]) + dot4(x1, qb4[lane + 64]) + dot4(x2, qb4[lane + 128]);
            dA = wave_reduce(dA); dB = wave_reduce(dB);
            if (lane == 0) {
                int kk = (w << 1) + e;
                sch[0][kk] = (dA + qbkA) * SCALE * pqs[0] * pk[0][rloc];
                sch[1][kk] = (dB + qbkB) * SCALE * pqs[1] * pk[1][rloc];
            }
        }
        __syncthreads();
        if (t < 2) {
            float mc = -1e30f;
            #pragma unroll
            for (int k = 0; k < 32; k++) mc = fmaxf(mc, sch[t][k]);
            float mn = fmaxf(mloc, mc);
            float f = __expf(mloc - mn);
            float ssum = 0.f;
            #pragma unroll
            for (int k = 0; k < 32; k++) {
                float wv = __expf(sch[t][k] - mn);
                wch[t][k] = wv; ssum += wv;
            }
            lloc = lloc * f + ssum;
            mloc = mn;
            scal[t] = f;
        }
        __syncthreads();
        if (t < 768) {
            accA *= scal[0]; accB *= scal[1];
            const float* fcol = fb + (size_t)(c * 32) * D + t;
            #pragma unroll 8
            for (int k = 0; k < 32; k++) {
                float fv = fcol[(size_t)k * D];
                accA += wch[0][k] * fv;
                accB += wch[1][k] * fv;
            }
        }
        __syncthreads();
    }
    if (t < 768) {
        ws[OFF_FSUM + h * 147456 + (pA * B + b) * D + t] = accA;
        ws[OFF_FSUM + h * 147456 + (pB * B + b) * D + t] = accB;
    }
    if (t < 2) {
        int p = t ? pB : pA;
        float* mh = ws + OFF_MLH + (p * B + b) * 8 + h * 2;
        mh[0] = mloc; mh[1] = lloc;
    }
}

// L4: agg partials, one Wv stream per block, combining the 4 S-quarters via (m,l).
// 576 blocks (i 3, js 2, bg 4, kc 24 (32 k)) x 192.
__global__ __launch_bounds__(192) void k_agg2(const float* Wv, float* ws) {
    int blk = blockIdx.x;
    int i = blk / 192, r = blk % 192, js = r / 96, r2 = r % 96, bg = r2 / 24, kc = r2 % 24;
    int kbase = kc * 32;
    int j0 = (i == 0) ? 1 : 0, j1 = (i == 2) ? 1 : 2;
    int jv = js ? j1 : j0;
    int p = 2 * i + js;
    __shared__ __align__(16) float xs[32][8];
    __shared__ float comb[4][8];
    if (threadIdx.x < 8) {
        int bb = threadIdx.x;
        const float* mh = ws + OFF_MLH + (p * B + bg * 8 + bb) * 8;
        float m0 = mh[0], l0 = mh[1], m1 = mh[2], l1 = mh[3];
        float m2 = mh[4], l2 = mh[5], m3 = mh[6], l3 = mh[7];
        float Mx = fmaxf(fmaxf(m0, m1), fmaxf(m2, m3));
        float e0 = __expf(m0 - Mx), e1 = __expf(m1 - Mx);
        float e2 = __expf(m2 - Mx), e3 = __expf(m3 - Mx);
        float L = e0 * l0 + e1 * l1 + e2 * l2 + e3 * l3;
        comb[0][bb] = e0 / L; comb[1][bb] = e1 / L;
        comb[2][bb] = e2 / L; comb[3][bb] = e3 / L;
    }
    __syncthreads();
    for (int idx = threadIdx.x; idx < 256; idx += 192) {
        int d = idx & 31, bb = idx >> 5;
        int base = OFF_FSUM + (p * B + bg * 8 + bb) * D + kbase + d;
        xs[d][bb] = comb[0][bb] * ws[base]
                  + comb[1][bb] * ws[base + 147456]
                  + comb[2][bb] * ws[base + 2 * 147456]
                  + comb[3][bb] * ws[base + 3 * 147456];
    }
    __syncthreads();
    int e4 = threadIdx.x * 4;
    const float* W0 = Wv + jv * D * D + kbase * D + e4;
    float4 acc[8];
    #pragma unroll
    for (int bb = 0; bb < 8; bb++) acc[bb] = make_float4(0.f, 0.f, 0.f, 0.f);
    for (int k = 0; k < 32; k++) {
        float4 w0 = *(const float4*)(W0 + k * D);
        float4 a0 = *(const float4*)&xs[k][0];
        float4 a1 = *(const float4*)&xs[k][4];
        fma4(acc[0], a0.x, w0); fma4(acc[1], a0.y, w0);
        fma4(acc[2], a0.z, w0); fma4(acc[3], a0.w, w0);
        fma4(acc[4], a1.x, w0); fma4(acc[5], a1.y, w0);
        fma4(acc[6], a1.z, w0); fma4(acc[7], a1.w, w0);
    }
    #pragma unroll
    for (int bb = 0; bb < 8; bb++)
        *(float4*)&ws[OFF_ARENA + (js * 24 + kc) * 73728 + (i * 32 + bg * 8 + bb) * 768 + e4] = acc[bb];
}

// L4b: coalesced reduce agg partials (48 slots) + bv biases -> AGG. 72 blocks x 256.
__global__ __launch_bounds__(256) void k_redA(const float* bv, float* ws) {
    int idx = blockIdx.x * 256 + threadIdx.x;
    int fidx = idx * 4;
    int i = fidx / 24576, e = fidx % 768;
    int j0 = (i == 0) ? 1 : 0, j1 = (i == 2) ? 1 : 2;
    float4 b0 = *(const float4*)&bv[j0 * 768 + e];
    float4 b1 = *(const float4*)&bv[j1 * 768 + e];
    float4 a = make_float4(b0.x + b1.x, b0.y + b1.y, b0.z + b1.z, b0.w + b1.w);
    #pragma unroll
    for (int s = 0; s < 48; s++) {
        float4 p = *(const float4*)&ws[OFF_ARENA + s * 73728 + fidx];
        a.x += p.x; a.y += p.y; a.z += p.z; a.w += p.w;
    }
    *(float4*)&ws[OFF_AGG + fidx] = a;
}

// L5: E/G partials, one stream per block. 864 blocks (kind 3, i 3, bg 4, kc 24 (32 k)).
// kind0: E partial = AGG@WE; kind1: G partial = AGG@Wh; kind2: G partial = Q@Wqc.
__global__ __launch_bounds__(192) void k_eg2(const float* WE_w, const float* Wh_w,
                                             const float* Wqc_w, float* ws) {
    int blk = blockIdx.x;
    int kind = blk / 288, r = blk % 288;
    int i = r / 96, r2 = r % 96, bg = r2 / 24, kc = r2 % 24;
    int kbase = kc * 32;
    int src = (kind == 2) ? OFF_Q : OFF_AGG;
    __shared__ __align__(16) float xs[32][8];
    for (int idx = threadIdx.x; idx < 256; idx += 192) {
        int d = idx & 31, bb = idx >> 5;
        xs[d][bb] = ws[src + (i * 32 + bg * 8 + bb) * 768 + kbase + d];
    }
    __syncthreads();
    int e4 = threadIdx.x * 4;
    const float* Wm = ((kind == 0) ? WE_w : (kind == 1) ? Wh_w : Wqc_w) + i * D * D + kbase * D + e4;
    float4 acc[8];
    #pragma unroll
    for (int bb = 0; bb < 8; bb++) acc[bb] = make_float4(0.f, 0.f, 0.f, 0.f);
    for (int k = 0; k < 32; k++) {
        float4 w = *(const float4*)(Wm + k * D);
        float4 a0 = *(const float4*)&xs[k][0];
        float4 a1 = *(const float4*)&xs[k][4];
        fma4(acc[0], a0.x, w); fma4(acc[1], a0.y, w);
        fma4(acc[2], a0.z, w); fma4(acc[3], a0.w, w);
        fma4(acc[4], a1.x, w); fma4(acc[5], a1.y, w);
        fma4(acc[6], a1.z, w); fma4(acc[7], a1.w, w);
    }
    #pragma unroll
    for (int bb = 0; bb < 8; bb++)
        *(float4*)&ws[OFF_ARENA2 + (kind * 24 + kc) * 73728 + (i * 32 + bg * 8 + bb) * 768 + e4] = acc[bb];
}

// L5b: coalesced reduce E/G partials + bias + relu. 144 blocks x 256 (first half E, rest G).
__global__ __launch_bounds__(256) void k_redEG(const float* WE_b, const float* Wh_b,
                                               const float* Wqc_b, float* ws) {
    int idx = blockIdx.x * 256 + threadIdx.x;
    int fidx = idx * 4;
    int kind = fidx / 73728;        // 0 = E, 1 = G
    int rr = fidx % 73728;
    int i = rr / 24576, e = rr % 768;
    float4 a;
    if (kind == 0) {
        a = *(const float4*)&WE_b[i * 768 + e];
        #pragma unroll
        for (int s = 0; s < 24; s++) {
            float4 p = *(const float4*)&ws[OFF_ARENA2 + s * 73728 + rr];
            a.x += p.x; a.y += p.y; a.z += p.z; a.w += p.w;
        }
    } else {
        float4 b0 = *(const float4*)&Wh_b[i * 768 + e];
        float4 b1 = *(const float4*)&Wqc_b[i * 768 + e];
        a = make_float4(b0.x + b1.x, b0.y + b1.y, b0.z + b1.z, b0.w + b1.w);
        #pragma unroll
        for (int s = 24; s < 72; s++) {
            float4 p = *(const float4*)&ws[OFF_ARENA2 + s * 73728 + rr];
            a.x += p.x; a.y += p.y; a.z += p.z; a.w += p.w;
        }
    }
    a.x = fmaxf(a.x, 0.f); a.y = fmaxf(a.y, 0.f); a.z = fmaxf(a.z, 0.f); a.w = fmaxf(a.w, 0.f);
    *(float4*)&ws[(kind ? OFF_G : OFF_E) + rr] = a;
}

// L6: LayerNorm(E)*LayerNorm(G) -> fused. 96 blocks (i,b).
__global__ __launch_bounds__(256) void k_ln2(const float* lnE_g, const float* lnE_b,
        const float* lnG_g, const float* lnG_b, float* ws) {
    int blk = blockIdx.x;
    int i = blk / B, b = blk % B;
    const float* E = ws + OFF_E + (i * B + b) * D;
    const float* G = ws + OFF_G + (i * B + b) * D;
    int t = threadIdx.x;
    float e0 = E[t], e1 = E[t + 256], e2 = E[t + 512];
    float g0 = G[t], g1 = G[t + 256], g2 = G[t + 512];
    __shared__ float r1[256], r2[256], r3[256], r4[256];
    r1[t] = e0 + e1 + e2;
    r2[t] = e0 * e0 + e1 * e1 + e2 * e2;
    r3[t] = g0 + g1 + g2;
    r4[t] = g0 * g0 + g1 * g1 + g2 * g2;
    __syncthreads();
    for (int st = 128; st > 0; st >>= 1) {
        if (t < st) { r1[t] += r1[t + st]; r2[t] += r2[t + st]; r3[t] += r3[t + st]; r4[t] += r4[t + st]; }
        __syncthreads();
    }
    float mE = r1[0] * (1.0f / D), vE = r2[0] * (1.0f / D) - mE * mE;
    float mG = r3[0] * (1.0f / D), vG = r4[0] * (1.0f / D) - mG * mG;
    float sE = rsqrtf(vE + LN_EPS), sG = rsqrtf(vG + LN_EPS);
    float* o = ws + OFF_FUSED + b * MD + i * D;
    const float* eg = lnE_g + i * D; const float* ebv = lnE_b + i * D;
    const float* gg = lnG_g + i * D; const float* gbv = lnG_b + i * D;
    o[t]       = ((e0 - mE) * sE * eg[t]       + ebv[t])       * ((g0 - mG) * sG * gg[t]       + gbv[t]);
    o[t + 256] = ((e1 - mE) * sE * eg[t + 256] + ebv[t + 256]) * ((g1 - mG) * sG * gg[t + 256] + gbv[t + 256]);
    o[t + 512] = ((e2 - mE) * sE * eg[t + 512] + ebv[t + 512]) * ((g2 - mG) * sG * gg[t + 512] + gbv[t + 512]);
}

// L7: out GEMM partials accumulated atomically into d_out (pre-zeroed).
// 288 blocks (bg 4, kc 72 (32 k)) x 256.
__global__ __launch_bounds__(256) void k_out2(const float* out_w, const float* out_b,
                                              float* ws, float* out) {
    int blk = blockIdx.x;
    int bg = blk / 72, kc = blk % 72;
    int kbase = kc * 32;
    __shared__ __align__(16) float xs[32][8];
    for (int idx = threadIdx.x; idx < 256; idx += 256) {
        int d = idx & 31, bb = idx >> 5;
        xs[d][bb] = ws[OFF_FUSED + (bg * 8 + bb) * MD + kbase + d];
    }
    __syncthreads();
    int e4 = threadIdx.x * 4;
    const float* Wm = out_w + kbase * H + e4;
    float4 acc[8];
    #pragma unroll
    for (int bb = 0; bb < 8; bb++) acc[bb] = make_float4(0.f, 0.f, 0.f, 0.f);
    for (int k = 0; k < 32; k++) {
        float4 w = *(const float4*)(Wm + k * H);
        float4 x0 = *(const float4*)&xs[k][0];
        float4 x1 = *(const float4*)&xs[k][4];
        fma4(acc[0], x0.x, w); fma4(acc[1], x0.y, w);
        fma4(acc[2], x0.z, w); fma4(acc[3], x0.w, w);
        fma4(acc[4], x1.x, w); fma4(acc[5], x1.y, w);
        fma4(acc[6], x1.z, w); fma4(acc[7], x1.w, w);
    }
    float4 bias = make_float4(0.f, 0.f, 0.f, 0.f);
    if (kc == 0) bias = *(const float4*)&out_b[e4];
    #pragma unroll
    for (int bb = 0; bb < 8; bb++) {
        float* dst = out + (bg * 8 + bb) * H + e4;
        atomicAdd(dst + 0, acc[bb].x + bias.x);
        atomicAdd(dst + 1, acc[bb].y + bias.y);
        atomicAdd(dst + 2, acc[bb].z + bias.z);
        atomicAdd(dst + 3, acc[bb].w + bias.w);
    }
    if (blk == 0 && threadIdx.x == 0) out[B * H] = ws[OFF_KL];
}

extern "C" void kernel_launch(void* const* d_in, const int* in_sizes, int n_in,
                              void* d_out, int out_size, void* d_ws, size_t ws_size,
                              hipStream_t stream) {
    const float* feats = (const float*)d_in[0];
    const float* Wq    = (const float*)d_in[1];
    const float* bq    = (const float*)d_in[2];
    const float* Wk    = (const float*)d_in[3];
    const float* bk    = (const float*)d_in[4];
    const float* Wv    = (const float*)d_in[5];
    const float* bv    = (const float*)d_in[6];
    const float* pgq_w = (const float*)d_in[7];
    const float* pgq_b = (const float*)d_in[8];
    const float* pgk_w = (const float*)d_in[9];
    const float* pgk_b = (const float*)d_in[10];
    const float* mu_w  = (const float*)d_in[11];
    const float* mu_b  = (const float*)d_in[12];
    const float* lv_w  = (const float*)d_in[13];
    const float* lv_b  = (const float*)d_in[14];
    const float* dyn   = (const float*)d_in[15];
    const float* WE_w  = (const float*)d_in[16];
    const float* WE_b  = (const float*)d_in[17];
    const float* Wh_w  = (const float*)d_in[18];
    const float* Wh_b  = (const float*)d_in[19];
    const float* Wqc_w = (const float*)d_in[20];
    const float* Wqc_b = (const float*)d_in[21];
    const float* lnE_g = (const float*)d_in[22];
    const float* lnE_b = (const float*)d_in[23];
    const float* lnG_g = (const float*)d_in[24];
    const float* lnG_b = (const float*)d_in[25];
    const float* out_w = (const float*)d_in[26];
    const float* out_b = (const float*)d_in[27];
    const float* eps   = (const float*)d_in[28];
    float* ws  = (float*)d_ws;
    float* out = (float*)d_out;

    hipMemsetAsync((char*)d_ws + OFF_KL * sizeof(float), 0, sizeof(float), stream);
    hipMemsetAsync(d_out, 0, (size_t)out_size, stream);

    k_prep2<<<807, 256, 0, stream>>>(feats, Wq, Wk, bq, bk, mu_w, mu_b, lv_w, lv_b,
                                     pgq_w, pgq_b, pgk_w, pgk_b, ws);
    k_stats2<<<2208, 256, 0, stream>>>(feats, bq, bk, ws);
    k_redqk<<<144, 256, 0, stream>>>(ws);
    k_attn<<<384, 1024, 0, stream>>>(feats, eps, dyn, ws);
    k_agg2<<<576, 192, 0, stream>>>(Wv, ws);
    k_redA<<<72, 256, 0, stream>>>(bv, ws);
    k_eg2<<<864, 192, 0, stream>>>(WE_w, Wh_w, Wqc_w, ws);
    k_redEG<<<144, 256, 0, stream>>>(WE_b, Wh_b, Wqc_b, ws);
    k_ln2<<<96, 256, 0, stream>>>(lnE_g, lnE_b, lnG_g, lnG_b, ws);
    k_out2<<<288, 256, 0, stream>>>(out_w, out_b, ws, out);
}

// Round 3
// 307.977 us; speedup vs baseline: 1.1866x; 1.1302x over previous
//
#include <hip/hip_runtime.h>

// Problem constants (fixed by the reference)
#define M 3
#define B 32
#define S 256
#define D 768
#define H 1024
#define MD (M * D)          // 2304
#define NP (M * (M - 1))    // 6 ordered (i,j) pairs
#define SCALE 0.03608439182435161f  // 1/sqrt(768)
#define LN_EPS 1e-5f

// Workspace layout (float offsets).
#define OFF_WMU   0         // [M][D]
#define OFF_WLV   2304      // [M][D]
#define OFF_WPGQ  4608      // [M][D]
#define OFF_WPK   6912      // [NP][D]
#define OFF_CMU   11520     // [M]
#define OFF_CLV   11523     // [M]
#define OFF_CPGQ  11526     // [M]
#define OFF_CPK   11529     // [NP]
#define OFF_MU    11552     // [M][B][S]
#define OFF_LV    36128     // [M][B][S]
#define OFF_PKPRE 60704     // [NP][B][S]
#define OFF_PQPRE 109856    // [M][B]
#define OFF_Q     109952    // [M][B][D]
#define OFF_QBK   183680    // [NP][B]
#define OFF_QK    183872    // [NP][B][D] reduced qk (147456)
#define OFF_MLH   331328    // [NP][B][4(h)][2(m,l)] = 1536
#define OFF_AGG   332864    // [M][B][D]
#define OFF_E     406592    // [M][B][D]
#define OFF_G     480320    // [M][B][D]
#define OFF_FUSED 554048    // [B][MD]
#define OFF_KL    627776    // [1]
#define OFF_FSUM  627840    // [4(h)][NP][B][D] (h stride 147456) = 589824
#define OFF_WKT   1217664   // [M][D][D] Wk transposed (1769472)
#define OFF_ARENA 2987136   // Q partials (24 slots, 73728) -> agg partials (48) -> out partials (72 x 32768)
#define OFF_ARENA2 6526080  // qk partials (24 slots, stride 147456) then E/G partials (72 slots, stride 73728)

__device__ __forceinline__ float wave_reduce(float v) {
    #pragma unroll
    for (int o = 32; o > 0; o >>= 1) v += __shfl_down(v, o, 64);
    return v;
}

__device__ __forceinline__ float sigmoidf(float x) {
    return 1.0f / (1.0f + __expf(-x));
}

__device__ __forceinline__ float dot4(float4 a, float4 b) {
    return a.x * b.x + a.y * b.y + a.z * b.z + a.w * b.w;
}

__device__ __forceinline__ void fma4(float4& a, float s, float4 w) {
    a.x += s * w.x; a.y += s * w.y; a.z += s * w.z; a.w += s * w.w;
}

// L1: fused prep + Q partials.
// blocks 0..71 vector-dots, 72..86 scalar consts, 87..518 Wk transpose,
// 519..806 Q GEMV partials (feats_s0 @ Wq, split-K 24).
__global__ __launch_bounds__(256) void k_prep2(const float* feats,
        const float* Wq, const float* Wk,
        const float* bq, const float* bk,
        const float* mu_w, const float* mu_b, const float* lv_w, const float* lv_b,
        const float* pgq_w, const float* pgq_b, const float* pgk_w, const float* pgk_b,
        float* ws) {
    int blk = blockIdx.x;
    if (blk < 72) {
        int mat = blk / 12, rg = blk % 12;
        const float* Wm; const float *va, *vb, *vc;
        float *oa, *ob, *oc; int nv;
        if (mat < 3) {
            int i = mat;
            Wm = Wq + i * D * D;
            va = mu_w + i * D; vb = lv_w + i * D; vc = pgq_w + i * D;
            oa = ws + OFF_WMU + i * D; ob = ws + OFF_WLV + i * D; oc = ws + OFF_WPGQ + i * D;
            nv = 3;
        } else {
            int j = mat - 3;
            int i1 = (j == 0) ? 1 : 0, i2 = (j == 2) ? 1 : 2;
            int p1 = 2 * i1 + ((j < i1) ? j : j - 1);
            int p2 = 2 * i2 + ((j < i2) ? j : j - 1);
            Wm = Wk + j * D * D;
            va = pgk_w + i1 * D; vb = pgk_w + i2 * D; vc = va;
            oa = ws + OFF_WPK + p1 * D; ob = ws + OFF_WPK + p2 * D; oc = oa;
            nv = 2;
        }
        int wave = threadIdx.x >> 6, lane = threadIdx.x & 63;
        const float4* va4 = (const float4*)va;
        const float4* vb4 = (const float4*)vb;
        const float4* vc4 = (const float4*)vc;
        float4 A0 = va4[lane], A1 = va4[lane + 64], A2 = va4[lane + 128];
        float4 B0 = vb4[lane], B1 = vb4[lane + 64], B2 = vb4[lane + 128];
        float4 C0 = vc4[lane], C1 = vc4[lane + 64], C2 = vc4[lane + 128];
        int base = rg * 64 + wave * 16;
        for (int r = 0; r < 16; r += 2) {
            const float4* rowP = (const float4*)(Wm + (base + r) * D);
            const float4* rowQ = (const float4*)(Wm + (base + r + 1) * D);
            float4 x0 = rowP[lane], x1 = rowP[lane + 64], x2 = rowP[lane + 128];
            float4 y0 = rowQ[lane], y1 = rowQ[lane + 64], y2 = rowQ[lane + 128];
            float daP = dot4(x0, A0) + dot4(x1, A1) + dot4(x2, A2);
            float dbP = dot4(x0, B0) + dot4(x1, B1) + dot4(x2, B2);
            float dcP = dot4(x0, C0) + dot4(x1, C1) + dot4(x2, C2);
            float daQ = dot4(y0, A0) + dot4(y1, A1) + dot4(y2, A2);
            float dbQ = dot4(y0, B0) + dot4(y1, B1) + dot4(y2, B2);
            float dcQ = dot4(y0, C0) + dot4(y1, C1) + dot4(y2, C2);
            daP = wave_reduce(daP); dbP = wave_reduce(dbP);
            daQ = wave_reduce(daQ); dbQ = wave_reduce(dbQ);
            if (nv == 3) { dcP = wave_reduce(dcP); dcQ = wave_reduce(dcQ); }
            if (lane == 0) {
                oa[base + r] = daP; ob[base + r] = dbP;
                oa[base + r + 1] = daQ; ob[base + r + 1] = dbQ;
                if (nv == 3) { oc[base + r] = dcP; oc[base + r + 1] = dcQ; }
            }
        }
    } else if (blk < 87) {
        int job = blk - 72;
        const float *a, *bvec; float bias; float* out;
        if (job < 3)      { int i = job;     a = bq + i * D; bvec = mu_w + i * D;  bias = mu_b[i];  out = ws + OFF_CMU + i; }
        else if (job < 6) { int i = job - 3; a = bq + i * D; bvec = lv_w + i * D;  bias = lv_b[i];  out = ws + OFF_CLV + i; }
        else if (job < 9) { int i = job - 6; a = bq + i * D; bvec = pgq_w + i * D; bias = pgq_b[i]; out = ws + OFF_CPGQ + i; }
        else {
            int p = job - 9, i = p / 2, c = p % 2, j = c + (c >= i ? 1 : 0);
            a = bk + j * D; bvec = pgk_w + i * D; bias = pgk_b[i]; out = ws + OFF_CPK + p;
        }
        int t = threadIdx.x;
        float part = 0.f;
        if (t < 192) part = dot4(((const float4*)a)[t], ((const float4*)bvec)[t]);
        part = wave_reduce(part);
        __shared__ float r[4];
        if ((t & 63) == 0) r[t >> 6] = part;
        __syncthreads();
        if (t == 0) *out = r[0] + r[1] + r[2] + r[3] + bias;
    } else if (blk < 519) {
        int r = blk - 87;
        int j = r / 144; r = r % 144;
        int d0 = (r / 12) * 64, e0 = (r % 12) * 64;
        __shared__ float tile[64][65];
        const float* src = Wk + j * D * D;
        for (int idx = threadIdx.x; idx < 4096; idx += 256) {
            int rr = idx / 64, cc = idx % 64;
            tile[rr][cc] = src[(d0 + rr) * D + e0 + cc];
        }
        __syncthreads();
        float* dst = ws + OFF_WKT + j * D * D;
        for (int idx = threadIdx.x; idx < 4096; idx += 256) {
            int rr = idx / 64, cc = idx % 64;
            dst[(e0 + rr) * D + d0 + cc] = tile[cc][rr];
        }
    } else {
        // Q partials: blocks (i 3, bg 4 (8 b), kc 24 (32 k))
        int qb = blk - 519;
        int i = qb / 96, r = qb % 96, bg = r / 24, kc = r % 24;
        int kbase = kc * 32;
        __shared__ __align__(16) float xs[32][8];
        for (int idx = threadIdx.x; idx < 256; idx += 256) {
            int d = idx & 31, bb = idx >> 5;
            xs[d][bb] = feats[((size_t)(i * B + bg * 8 + bb) * S) * D + kbase + d];
        }
        __syncthreads();
        if (threadIdx.x < 192) {
            int e4 = threadIdx.x * 4;
            const float* Wm = Wq + i * D * D + kbase * D + e4;
            float4 acc[8];
            #pragma unroll
            for (int bb = 0; bb < 8; bb++) acc[bb] = make_float4(0.f, 0.f, 0.f, 0.f);
            for (int k = 0; k < 32; k++) {
                float4 w = *(const float4*)(Wm + k * D);
                float4 x0 = *(const float4*)&xs[k][0];
                float4 x1 = *(const float4*)&xs[k][4];
                fma4(acc[0], x0.x, w); fma4(acc[1], x0.y, w);
                fma4(acc[2], x0.z, w); fma4(acc[3], x0.w, w);
                fma4(acc[4], x1.x, w); fma4(acc[5], x1.y, w);
                fma4(acc[6], x1.z, w); fma4(acc[7], x1.w, w);
            }
            #pragma unroll
            for (int bb = 0; bb < 8; bb++)
                *(float4*)&ws[OFF_ARENA + kc * 73728 + (i * 32 + bg * 8 + bb) * 768 + e4] = acc[bb];
        }
    }
}

// L1b: reduce Q partials (+bq) -> OFF_Q, and qbk = (Q+bq).bk for both pairs. 96 blocks (i,b).
__global__ __launch_bounds__(256) void k_redQ(const float* bq, const float* bk, float* ws) {
    int blk = blockIdx.x;
    int i = blk / B, b = blk % B;
    int fbase = (i * B + b) * D;
    int t = threadIdx.x;
    __shared__ float4 qsh[192];
    __shared__ float redsh[8];
    if (t < 192) {
        float4 a = *(const float4*)&bq[i * D + t * 4];
        #pragma unroll
        for (int kc = 0; kc < 24; kc++) {
            float4 v = *(const float4*)&ws[OFF_ARENA + kc * 73728 + fbase + t * 4];
            a.x += v.x; a.y += v.y; a.z += v.z; a.w += v.w;
        }
        *(float4*)&ws[OFF_Q + fbase + t * 4] = a;
        qsh[t] = a;
    }
    __syncthreads();
    int jA = (i == 0) ? 1 : 0, jB = (i == 2) ? 1 : 2;
    float pA_ = 0.f, pB_ = 0.f;
    if (t < 192) {
        float4 q = qsh[t];
        pA_ = dot4(q, *(const float4*)&bk[jA * D + t * 4]);
        pB_ = dot4(q, *(const float4*)&bk[jB * D + t * 4]);
    }
    pA_ = wave_reduce(pA_); pB_ = wave_reduce(pB_);
    int wave = t >> 6, lane = t & 63;
    if (lane == 0) { redsh[wave] = pA_; redsh[4 + wave] = pB_; }
    __syncthreads();
    if (t == 0) {
        ws[OFF_QBK + (2 * i) * B + b]     = redsh[0] + redsh[1] + redsh[2] + redsh[3];
        ws[OFF_QBK + (2 * i + 1) * B + b] = redsh[4] + redsh[5] + redsh[6] + redsh[7];
    }
}

// L2: qk GEMV first (long blocks, 576, reads reduced Q), then stats (1536). Total 2112.
__global__ __launch_bounds__(256) void k_stats2(const float* feats,
        const float* bq, const float* bk, float* ws) {
    int blk = blockIdx.x;
    if (blk < 576) {
        // qk partials with WkT. (j 3, vg 8, kc 24 (32 k))
        int j = blk / 192, r = blk % 192, vg = r / 24, kc = r % 24;
        int kbase = kc * 32;
        int i1 = (j == 0) ? 1 : 0, i2 = (j == 2) ? 1 : 2;
        __shared__ __align__(16) float xs[32][8];
        for (int idx = threadIdx.x; idx < 256; idx += 256) {
            int d = idx & 31, v = idx >> 5;
            int v64 = vg * 8 + v;
            int i_ = (v64 < 32) ? i1 : i2, b = v64 & 31;
            xs[d][v] = ws[OFF_Q + (i_ * 32 + b) * 768 + kbase + d];
        }
        __syncthreads();
        if (threadIdx.x < 192) {
            int e4 = threadIdx.x * 4;
            const float* Wm = ws + OFF_WKT + j * D * D + kbase * D + e4;
            float4 acc[8];
            #pragma unroll
            for (int bb = 0; bb < 8; bb++) acc[bb] = make_float4(0.f, 0.f, 0.f, 0.f);
            for (int k = 0; k < 32; k++) {
                float4 w = *(const float4*)(Wm + k * D);
                float4 x0 = *(const float4*)&xs[k][0];
                float4 x1 = *(const float4*)&xs[k][4];
                fma4(acc[0], x0.x, w); fma4(acc[1], x0.y, w);
                fma4(acc[2], x0.z, w); fma4(acc[3], x0.w, w);
                fma4(acc[4], x1.x, w); fma4(acc[5], x1.y, w);
                fma4(acc[6], x1.z, w); fma4(acc[7], x1.w, w);
            }
            #pragma unroll
            for (int v = 0; v < 8; v++)
                *(float4*)&ws[OFF_ARENA2 + kc * 147456 + (j * 64 + vg * 8 + v) * 768 + e4] = acc[v];
        }
    } else {
        int blk2 = blk - 576;
        __shared__ float klred[4];
        int wave = threadIdx.x >> 6, lane = threadIdx.x & 63;
        int m = blk2 / 512;
        int row0 = blk2 * 16 + wave * 4;
        int i1 = (m == 0) ? 1 : 0, i2 = (m == 2) ? 1 : 2;
        int p0 = 2 * i1 + ((m < i1) ? m : m - 1);
        int p1 = 2 * i2 + ((m < i2) ? m : m - 1);
        const float4* wmu  = (const float4*)(ws + OFF_WMU + m * D);
        const float4* wlv  = (const float4*)(ws + OFF_WLV + m * D);
        const float4* wpgq = (const float4*)(ws + OFF_WPGQ + m * D);
        const float4* wpk0 = (const float4*)(ws + OFF_WPK + p0 * D);
        const float4* wpk1 = (const float4*)(ws + OFF_WPK + p1 * D);
        float4 U0 = wmu[lane],  U1 = wmu[lane + 64],  U2 = wmu[lane + 128];
        float4 L0 = wlv[lane],  L1 = wlv[lane + 64],  L2 = wlv[lane + 128];
        float4 Q0 = wpgq[lane], Q1 = wpgq[lane + 64], Q2 = wpgq[lane + 128];
        float4 P0 = wpk0[lane], P1 = wpk0[lane + 64], P2 = wpk0[lane + 128];
        float4 R0 = wpk1[lane], R1 = wpk1[lane + 64], R2 = wpk1[lane + 128];
        float4 x[4][3];
        #pragma unroll
        for (int rr = 0; rr < 4; rr++) {
            const float4* f = (const float4*)(feats + (size_t)(row0 + rr) * D);
            x[rr][0] = f[lane]; x[rr][1] = f[lane + 64]; x[rr][2] = f[lane + 128];
        }
        float amu[4], alv[4], apgq[4], apk0[4], apk1[4];
        #pragma unroll
        for (int rr = 0; rr < 4; rr++) {
            amu[rr]  = dot4(x[rr][0], U0) + dot4(x[rr][1], U1) + dot4(x[rr][2], U2);
            alv[rr]  = dot4(x[rr][0], L0) + dot4(x[rr][1], L1) + dot4(x[rr][2], L2);
            apgq[rr] = dot4(x[rr][0], Q0) + dot4(x[rr][1], Q1) + dot4(x[rr][2], Q2);
            apk0[rr] = dot4(x[rr][0], P0) + dot4(x[rr][1], P1) + dot4(x[rr][2], P2);
            apk1[rr] = dot4(x[rr][0], R0) + dot4(x[rr][1], R1) + dot4(x[rr][2], R2);
        }
        #pragma unroll
        for (int rr = 0; rr < 4; rr++) {
            amu[rr] = wave_reduce(amu[rr]);  alv[rr] = wave_reduce(alv[rr]);
            apgq[rr] = wave_reduce(apgq[rr]);
            apk0[rr] = wave_reduce(apk0[rr]); apk1[rr] = wave_reduce(apk1[rr]);
        }
        if (lane == 0) {
            float cmu = ws[OFF_CMU + m], clv = ws[OFF_CLV + m];
            float cpgq = ws[OFF_CPGQ + m];
            float cpk0 = ws[OFF_CPK + p0], cpk1 = ws[OFF_CPK + p1];
            float klsum = 0.f;
            #pragma unroll
            for (int rr = 0; rr < 4; rr++) {
                int row = row0 + rr;
                int rem = row % (B * S);
                int b = rem / S, s = rem % S;
                float muv = amu[rr] + cmu;
                float lvv = alv[rr] + clv;
                ws[OFF_MU + row] = muv;
                ws[OFF_LV + row] = lvv;
                ws[OFF_PKPRE + (p0 * B + b) * S + s] = apk0[rr] + cpk0;
                ws[OFF_PKPRE + (p1 * B + b) * S + s] = apk1[rr] + cpk1;
                if (s == 0) ws[OFF_PQPRE + m * B + b] = apgq[rr] + cpgq;
                klsum += 1.0f + lvv - muv * muv - __expf(lvv);
            }
            klred[wave] = klsum;
        }
        __syncthreads();
        if (threadIdx.x == 0)
            atomicAdd(ws + OFF_KL, -(klred[0] + klred[1] + klred[2] + klred[3]));
    }
}

// L2b: coalesced reduce of qk partials (24 slots) -> QK[p][b][d]. 144 blocks x 256.
__global__ __launch_bounds__(256) void k_redqk(float* ws) {
    int idx = blockIdx.x * 256 + threadIdx.x;
    int fidx = idx * 4;
    int row = fidx / 768, d = fidx % 768;
    int j = row / 64, v64 = row % 64;
    int b = v64 & 31, islot = v64 >> 5;
    int i_ = islot ? ((j == 2) ? 1 : 2) : ((j == 0) ? 1 : 0);
    int p = 2 * i_ + ((j < i_) ? j : j - 1);
    float4 a = make_float4(0.f, 0.f, 0.f, 0.f);
    #pragma unroll
    for (int kc = 0; kc < 24; kc++) {
        float4 v = *(const float4*)&ws[OFF_ARENA2 + kc * 147456 + fidx];
        a.x += v.x; a.y += v.y; a.z += v.z; a.w += v.w;
    }
    *(float4*)&ws[OFF_QK + (p * B + b) * D + d] = a;
}

// L3: fused scores + gates + online softmax + weighted feats sum, S split in QUARTERS.
// 384 blocks (j 3, b 32, h 4) x 1024 threads. Unnormalized partial sums + per-quarter
// (m,l) combined analytically in k_agg2.
__global__ __launch_bounds__(1024) void k_attn(const float* feats, const float* eps,
                                               const float* dyn, float* ws) {
    int blk = blockIdx.x;
    int j = blk / 128, r = blk % 128, b = r >> 2, h = r & 3;
    int i1 = (j == 0) ? 1 : 0, i2 = (j == 2) ? 1 : 2;
    int pA = 2 * i1 + ((j < i1) ? j : j - 1);
    int pB = 2 * i2 + ((j < i2) ? j : j - 1);
    __shared__ __align__(16) float q[2][768];
    __shared__ float pk[2][64];
    __shared__ float sch[2][32], wch[2][32];
    __shared__ float scal[2], pqs[2];
    int t = threadIdx.x;
    float dynv = dyn[0];
    if (t < 384) {
        int slot = t / 192;
        int d4 = (t % 192) * 4;
        int p = slot ? pB : pA;
        *(float4*)&q[slot][d4] = *(const float4*)&ws[OFF_QK + (p * B + b) * D + d4];
    } else if (t < 512) {
        int t2 = t - 384, slot = t2 >> 6, tt = t2 & 63;
        int k = h * 64 + tt;
        int iq = slot ? i2 : i1, p = slot ? pB : pA;
        float mu = ws[OFF_MU + (iq * B + b) * S + k];
        float lv = ws[OFF_LV + (iq * B + b) * S + k];
        float e  = eps[(p * B + b) * S + k];
        float g  = sigmoidf(mu + dynv * __expf(0.5f * lv) * e);
        pk[slot][tt] = sigmoidf(ws[OFF_PKPRE + (p * B + b) * S + k]) * g;
    } else if (t < 514) {
        int slot = t - 512;
        int iq = slot ? i2 : i1, p = slot ? pB : pA;
        float mu0 = ws[OFF_MU + (iq * B + b) * S];
        float lv0 = ws[OFF_LV + (iq * B + b) * S];
        float e0  = eps[(p * B + b) * S];
        float g0  = sigmoidf(mu0 + dynv * __expf(0.5f * lv0) * e0);
        pqs[slot] = sigmoidf(ws[OFF_PQPRE + iq * B + b]) * g0;
    }
    __syncthreads();
    float qbkA = ws[OFF_QBK + pA * B + b];
    float qbkB = ws[OFF_QBK + pB * B + b];
    const float* fb = feats + (size_t)((j * B + b) * S + h * 64) * D;
    float accA = 0.f, accB = 0.f;
    float mloc = -1e30f, lloc = 0.f;
    int w = t >> 6, lane = t & 63;
    for (int c = 0; c < 2; c++) {
        // dot phase: 16 waves x 2 rows = 32 rows
        #pragma unroll
        for (int e = 0; e < 2; e++) {
            int rloc = c * 32 + (w << 1) + e;
            const float4* f4 = (const float4*)(fb + (size_t)rloc * D);
            float4 x0 = f4[lane], x1 = f4[lane + 64], x2 = f4[lane + 128];
            const float4* qa4 = (const float4*)&q[0][0];
            const float4* qb4 = (const float4*)&q[1][0];
            float dA = dot4(x0, qa4[lane]) + dot4(x1, qa4[lane + 64]) + dot4(x2, qa4[lane + 128]);
            float dB = dot4(x0, qb4[lane]) + dot4(x1, qb4[lane + 64]) + dot4(x2, qb4[lane + 128]);
            dA = wave_reduce(dA); dB = wave_reduce(dB);
            if (lane == 0) {
                int kk = (w << 1) + e;
                sch[0][kk] = (dA + qbkA) * SCALE * pqs[0] * pk[0][rloc];
                sch[1][kk] = (dB + qbkB) * SCALE * pqs[1] * pk[1][rloc];
            }
        }
        __syncthreads();
        if (t < 2) {
            float mc = -1e30f;
            #pragma unroll
            for (int k = 0; k < 32; k++) mc = fmaxf(mc, sch[t][k]);
            float mn = fmaxf(mloc, mc);
            float f = __expf(mloc - mn);
            float ssum = 0.f;
            #pragma unroll
            for (int k = 0; k < 32; k++) {
                float wv = __expf(sch[t][k] - mn);
                wch[t][k] = wv; ssum += wv;
            }
            lloc = lloc * f + ssum;
            mloc = mn;
            scal[t] = f;
        }
        __syncthreads();
        if (t < 768) {
            accA *= scal[0]; accB *= scal[1];
            const float* fcol = fb + (size_t)(c * 32) * D + t;
            #pragma unroll 8
            for (int k = 0; k < 32; k++) {
                float fv = fcol[(size_t)k * D];
                accA += wch[0][k] * fv;
                accB += wch[1][k] * fv;
            }
        }
        __syncthreads();
    }
    if (t < 768) {
        ws[OFF_FSUM + h * 147456 + (pA * B + b) * D + t] = accA;
        ws[OFF_FSUM + h * 147456 + (pB * B + b) * D + t] = accB;
    }
    if (t < 2) {
        int p = t ? pB : pA;
        float* mh = ws + OFF_MLH + (p * B + b) * 8 + h * 2;
        mh[0] = mloc; mh[1] = lloc;
    }
}

// L4: agg partials, one Wv stream per block, combining the 4 S-quarters via (m,l).
// 576 blocks (i 3, js 2, bg 4, kc 24 (32 k)) x 192.
__global__ __launch_bounds__(192) void k_agg2(const float* Wv, float* ws) {
    int blk = blockIdx.x;
    int i = blk / 192, r = blk % 192, js = r / 96, r2 = r % 96, bg = r2 / 24, kc = r2 % 24;
    int kbase = kc * 32;
    int j0 = (i == 0) ? 1 : 0, j1 = (i == 2) ? 1 : 2;
    int jv = js ? j1 : j0;
    int p = 2 * i + js;
    __shared__ __align__(16) float xs[32][8];
    __shared__ float comb[4][8];
    if (threadIdx.x < 8) {
        int bb = threadIdx.x;
        const float* mh = ws + OFF_MLH + (p * B + bg * 8 + bb) * 8;
        float m0 = mh[0], l0 = mh[1], m1 = mh[2], l1 = mh[3];
        float m2 = mh[4], l2 = mh[5], m3 = mh[6], l3 = mh[7];
        float Mx = fmaxf(fmaxf(m0, m1), fmaxf(m2, m3));
        float e0 = __expf(m0 - Mx), e1 = __expf(m1 - Mx);
        float e2 = __expf(m2 - Mx), e3 = __expf(m3 - Mx);
        float L = e0 * l0 + e1 * l1 + e2 * l2 + e3 * l3;
        comb[0][bb] = e0 / L; comb[1][bb] = e1 / L;
        comb[2][bb] = e2 / L; comb[3][bb] = e3 / L;
    }
    __syncthreads();
    for (int idx = threadIdx.x; idx < 256; idx += 192) {
        int d = idx & 31, bb = idx >> 5;
        int base = OFF_FSUM + (p * B + bg * 8 + bb) * D + kbase + d;
        xs[d][bb] = comb[0][bb] * ws[base]
                  + comb[1][bb] * ws[base + 147456]
                  + comb[2][bb] * ws[base + 2 * 147456]
                  + comb[3][bb] * ws[base + 3 * 147456];
    }
    __syncthreads();
    int e4 = threadIdx.x * 4;
    const float* W0 = Wv + jv * D * D + kbase * D + e4;
    float4 acc[8];
    #pragma unroll
    for (int bb = 0; bb < 8; bb++) acc[bb] = make_float4(0.f, 0.f, 0.f, 0.f);
    for (int k = 0; k < 32; k++) {
        float4 w0 = *(const float4*)(W0 + k * D);
        float4 a0 = *(const float4*)&xs[k][0];
        float4 a1 = *(const float4*)&xs[k][4];
        fma4(acc[0], a0.x, w0); fma4(acc[1], a0.y, w0);
        fma4(acc[2], a0.z, w0); fma4(acc[3], a0.w, w0);
        fma4(acc[4], a1.x, w0); fma4(acc[5], a1.y, w0);
        fma4(acc[6], a1.z, w0); fma4(acc[7], a1.w, w0);
    }
    #pragma unroll
    for (int bb = 0; bb < 8; bb++)
        *(float4*)&ws[OFF_ARENA + (js * 24 + kc) * 73728 + (i * 32 + bg * 8 + bb) * 768 + e4] = acc[bb];
}

// L4b: coalesced reduce agg partials (48 slots) + bv biases -> AGG. 72 blocks x 256.
__global__ __launch_bounds__(256) void k_redA(const float* bv, float* ws) {
    int idx = blockIdx.x * 256 + threadIdx.x;
    int fidx = idx * 4;
    int i = fidx / 24576, e = fidx % 768;
    int j0 = (i == 0) ? 1 : 0, j1 = (i == 2) ? 1 : 2;
    float4 b0 = *(const float4*)&bv[j0 * 768 + e];
    float4 b1 = *(const float4*)&bv[j1 * 768 + e];
    float4 a = make_float4(b0.x + b1.x, b0.y + b1.y, b0.z + b1.z, b0.w + b1.w);
    #pragma unroll
    for (int s = 0; s < 48; s++) {
        float4 p = *(const float4*)&ws[OFF_ARENA + s * 73728 + fidx];
        a.x += p.x; a.y += p.y; a.z += p.z; a.w += p.w;
    }
    *(float4*)&ws[OFF_AGG + fidx] = a;
}

// L5: E/G partials, one stream per block. 864 blocks (kind 3, i 3, bg 4, kc 24 (32 k)).
// kind0: E partial = AGG@WE; kind1: G partial = AGG@Wh; kind2: G partial = Q@Wqc.
__global__ __launch_bounds__(192) void k_eg2(const float* WE_w, const float* Wh_w,
                                             const float* Wqc_w, float* ws) {
    int blk = blockIdx.x;
    int kind = blk / 288, r = blk % 288;
    int i = r / 96, r2 = r % 96, bg = r2 / 24, kc = r2 % 24;
    int kbase = kc * 32;
    int src = (kind == 2) ? OFF_Q : OFF_AGG;
    __shared__ __align__(16) float xs[32][8];
    for (int idx = threadIdx.x; idx < 256; idx += 192) {
        int d = idx & 31, bb = idx >> 5;
        xs[d][bb] = ws[src + (i * 32 + bg * 8 + bb) * 768 + kbase + d];
    }
    __syncthreads();
    int e4 = threadIdx.x * 4;
    const float* Wm = ((kind == 0) ? WE_w : (kind == 1) ? Wh_w : Wqc_w) + i * D * D + kbase * D + e4;
    float4 acc[8];
    #pragma unroll
    for (int bb = 0; bb < 8; bb++) acc[bb] = make_float4(0.f, 0.f, 0.f, 0.f);
    for (int k = 0; k < 32; k++) {
        float4 w = *(const float4*)(Wm + k * D);
        float4 a0 = *(const float4*)&xs[k][0];
        float4 a1 = *(const float4*)&xs[k][4];
        fma4(acc[0], a0.x, w); fma4(acc[1], a0.y, w);
        fma4(acc[2], a0.z, w); fma4(acc[3], a0.w, w);
        fma4(acc[4], a1.x, w); fma4(acc[5], a1.y, w);
        fma4(acc[6], a1.z, w); fma4(acc[7], a1.w, w);
    }
    #pragma unroll
    for (int bb = 0; bb < 8; bb++)
        *(float4*)&ws[OFF_ARENA2 + (kind * 24 + kc) * 73728 + (i * 32 + bg * 8 + bb) * 768 + e4] = acc[bb];
}

// L5b: coalesced reduce E/G partials + bias + relu. 144 blocks x 256 (first half E, rest G).
__global__ __launch_bounds__(256) void k_redEG(const float* WE_b, const float* Wh_b,
                                               const float* Wqc_b, float* ws) {
    int idx = blockIdx.x * 256 + threadIdx.x;
    int fidx = idx * 4;
    int kind = fidx / 73728;        // 0 = E, 1 = G
    int rr = fidx % 73728;
    int i = rr / 24576, e = rr % 768;
    float4 a;
    if (kind == 0) {
        a = *(const float4*)&WE_b[i * 768 + e];
        #pragma unroll
        for (int s = 0; s < 24; s++) {
            float4 p = *(const float4*)&ws[OFF_ARENA2 + s * 73728 + rr];
            a.x += p.x; a.y += p.y; a.z += p.z; a.w += p.w;
        }
    } else {
        float4 b0 = *(const float4*)&Wh_b[i * 768 + e];
        float4 b1 = *(const float4*)&Wqc_b[i * 768 + e];
        a = make_float4(b0.x + b1.x, b0.y + b1.y, b0.z + b1.z, b0.w + b1.w);
        #pragma unroll
        for (int s = 24; s < 72; s++) {
            float4 p = *(const float4*)&ws[OFF_ARENA2 + s * 73728 + rr];
            a.x += p.x; a.y += p.y; a.z += p.z; a.w += p.w;
        }
    }
    a.x = fmaxf(a.x, 0.f); a.y = fmaxf(a.y, 0.f); a.z = fmaxf(a.z, 0.f); a.w = fmaxf(a.w, 0.f);
    *(float4*)&ws[(kind ? OFF_G : OFF_E) + rr] = a;
}

// L6: LayerNorm(E)*LayerNorm(G) -> fused. 96 blocks (i,b).
__global__ __launch_bounds__(256) void k_ln2(const float* lnE_g, const float* lnE_b,
        const float* lnG_g, const float* lnG_b, float* ws) {
    int blk = blockIdx.x;
    int i = blk / B, b = blk % B;
    const float* E = ws + OFF_E + (i * B + b) * D;
    const float* G = ws + OFF_G + (i * B + b) * D;
    int t = threadIdx.x;
    float e0 = E[t], e1 = E[t + 256], e2 = E[t + 512];
    float g0 = G[t], g1 = G[t + 256], g2 = G[t + 512];
    __shared__ float r1[256], r2[256], r3[256], r4[256];
    r1[t] = e0 + e1 + e2;
    r2[t] = e0 * e0 + e1 * e1 + e2 * e2;
    r3[t] = g0 + g1 + g2;
    r4[t] = g0 * g0 + g1 * g1 + g2 * g2;
    __syncthreads();
    for (int st = 128; st > 0; st >>= 1) {
        if (t < st) { r1[t] += r1[t + st]; r2[t] += r2[t + st]; r3[t] += r3[t + st]; r4[t] += r4[t + st]; }
        __syncthreads();
    }
    float mE = r1[0] * (1.0f / D), vE = r2[0] * (1.0f / D) - mE * mE;
    float mG = r3[0] * (1.0f / D), vG = r4[0] * (1.0f / D) - mG * mG;
    float sE = rsqrtf(vE + LN_EPS), sG = rsqrtf(vG + LN_EPS);
    float* o = ws + OFF_FUSED + b * MD + i * D;
    const float* eg = lnE_g + i * D; const float* ebv = lnE_b + i * D;
    const float* gg = lnG_g + i * D; const float* gbv = lnG_b + i * D;
    o[t]       = ((e0 - mE) * sE * eg[t]       + ebv[t])       * ((g0 - mG) * sG * gg[t]       + gbv[t]);
    o[t + 256] = ((e1 - mE) * sE * eg[t + 256] + ebv[t + 256]) * ((g1 - mG) * sG * gg[t + 256] + gbv[t + 256]);
    o[t + 512] = ((e2 - mE) * sE * eg[t + 512] + ebv[t + 512]) * ((g2 - mG) * sG * gg[t + 512] + gbv[t + 512]);
}

// L7: out GEMM partials -> arena (no atomics). 288 blocks (bg 4, kc 72 (32 k)) x 256.
__global__ __launch_bounds__(256) void k_out2(const float* out_w, float* ws) {
    int blk = blockIdx.x;
    int bg = blk / 72, kc = blk % 72;
    int kbase = kc * 32;
    __shared__ __align__(16) float xs[32][8];
    for (int idx = threadIdx.x; idx < 256; idx += 256) {
        int d = idx & 31, bb = idx >> 5;
        xs[d][bb] = ws[OFF_FUSED + (bg * 8 + bb) * MD + kbase + d];
    }
    __syncthreads();
    int e4 = threadIdx.x * 4;
    const float* Wm = out_w + kbase * H + e4;
    float4 acc[8];
    #pragma unroll
    for (int bb = 0; bb < 8; bb++) acc[bb] = make_float4(0.f, 0.f, 0.f, 0.f);
    for (int k = 0; k < 32; k++) {
        float4 w = *(const float4*)(Wm + k * H);
        float4 x0 = *(const float4*)&xs[k][0];
        float4 x1 = *(const float4*)&xs[k][4];
        fma4(acc[0], x0.x, w); fma4(acc[1], x0.y, w);
        fma4(acc[2], x0.z, w); fma4(acc[3], x0.w, w);
        fma4(acc[4], x1.x, w); fma4(acc[5], x1.y, w);
        fma4(acc[6], x1.z, w); fma4(acc[7], x1.w, w);
    }
    #pragma unroll
    for (int bb = 0; bb < 8; bb++)
        *(float4*)&ws[OFF_ARENA + kc * 32768 + (bg * 8 + bb) * 1024 + e4] = acc[bb];
}

// L7b: sum out partials (72 kc) + bias, write kl. 32 blocks (b) x 256.
__global__ __launch_bounds__(256) void k_fin(const float* out_b, float* ws, float* out) {
    int b = blockIdx.x;
    int h4 = threadIdx.x * 4;
    float4 a = *(const float4*)&out_b[h4];
    #pragma unroll
    for (int kc = 0; kc < 72; kc++) {
        float4 p = *(const float4*)&ws[OFF_ARENA + kc * 32768 + b * 1024 + h4];
        a.x += p.x; a.y += p.y; a.z += p.z; a.w += p.w;
    }
    *(float4*)&out[b * H + h4] = a;
    if (b == 0 && threadIdx.x == 0) out[B * H] = ws[OFF_KL];
}

extern "C" void kernel_launch(void* const* d_in, const int* in_sizes, int n_in,
                              void* d_out, int out_size, void* d_ws, size_t ws_size,
                              hipStream_t stream) {
    const float* feats = (const float*)d_in[0];
    const float* Wq    = (const float*)d_in[1];
    const float* bq    = (const float*)d_in[2];
    const float* Wk    = (const float*)d_in[3];
    const float* bk    = (const float*)d_in[4];
    const float* Wv    = (const float*)d_in[5];
    const float* bv    = (const float*)d_in[6];
    const float* pgq_w = (const float*)d_in[7];
    const float* pgq_b = (const float*)d_in[8];
    const float* pgk_w = (const float*)d_in[9];
    const float* pgk_b = (const float*)d_in[10];
    const float* mu_w  = (const float*)d_in[11];
    const float* mu_b  = (const float*)d_in[12];
    const float* lv_w  = (const float*)d_in[13];
    const float* lv_b  = (const float*)d_in[14];
    const float* dyn   = (const float*)d_in[15];
    const float* WE_w  = (const float*)d_in[16];
    const float* WE_b  = (const float*)d_in[17];
    const float* Wh_w  = (const float*)d_in[18];
    const float* Wh_b  = (const float*)d_in[19];
    const float* Wqc_w = (const float*)d_in[20];
    const float* Wqc_b = (const float*)d_in[21];
    const float* lnE_g = (const float*)d_in[22];
    const float* lnE_b = (const float*)d_in[23];
    const float* lnG_g = (const float*)d_in[24];
    const float* lnG_b = (const float*)d_in[25];
    const float* out_w = (const float*)d_in[26];
    const float* out_b = (const float*)d_in[27];
    const float* eps   = (const float*)d_in[28];
    float* ws  = (float*)d_ws;
    float* out = (float*)d_out;

    hipMemsetAsync((char*)d_ws + OFF_KL * sizeof(float), 0, sizeof(float), stream);

    k_prep2<<<807, 256, 0, stream>>>(feats, Wq, Wk, bq, bk, mu_w, mu_b, lv_w, lv_b,
                                     pgq_w, pgq_b, pgk_w, pgk_b, ws);
    k_redQ<<<96, 256, 0, stream>>>(bq, bk, ws);
    k_stats2<<<2112, 256, 0, stream>>>(feats, bq, bk, ws);
    k_redqk<<<144, 256, 0, stream>>>(ws);
    k_attn<<<384, 1024, 0, stream>>>(feats, eps, dyn, ws);
    k_agg2<<<576, 192, 0, stream>>>(Wv, ws);
    k_redA<<<72, 256, 0, stream>>>(bv, ws);
    k_eg2<<<864, 192, 0, stream>>>(WE_w, Wh_w, Wqc_w, ws);
    k_redEG<<<144, 256, 0, stream>>>(WE_b, Wh_b, Wqc_b, ws);
    k_ln2<<<96, 256, 0, stream>>>(lnE_g, lnE_b, lnG_g, lnG_b, ws);
    k_out2<<<288, 256, 0, stream>>>(out_w, ws);
    k_fin<<<32, 256, 0, stream>>>(out_b, ws, out);
}

// Round 5
// 299.602 us; speedup vs baseline: 1.2198x; 1.0280x over previous
//
#include <hip/hip_runtime.h>

// Problem constants (fixed by the reference)
#define M 3
#define B 32
#define S 256
#define D 768
#define H 1024
#define MD (M * D)          // 2304
#define NP (M * (M - 1))    // 6 ordered (i,j) pairs
#define SCALE 0.03608439182435161f  // 1/sqrt(768)
#define LN_EPS 1e-5f

// Workspace layout (float offsets).
#define OFF_WMU   0         // [M][D]
#define OFF_WLV   2304      // [M][D]
#define OFF_WPGQ  4608      // [M][D]
#define OFF_WPK   6912      // [NP][D]
#define OFF_CMU   11520     // [M]
#define OFF_CLV   11523     // [M]
#define OFF_CPGQ  11526     // [M]
#define OFF_CPK   11529     // [NP]
#define OFF_MU    11552     // [M][B][S]
#define OFF_LV    36128     // [M][B][S]
#define OFF_PKPRE 60704     // [NP][B][S]
#define OFF_PQPRE 109856    // [M][B]
#define OFF_Q     109952    // [M][B][D]
#define OFF_QBK   183680    // [NP][B]
#define OFF_QK    183872    // [NP][B][D] reduced qk (147456)
#define OFF_MLH   331328    // [NP][B][4(h)][2(m,l)] = 1536
#define OFF_AGG   332864    // [M][B][D]
#define OFF_E     406592    // [M][B][D]
#define OFF_G     480320    // [M][B][D]
#define OFF_FUSED 554048    // [B][MD]
#define OFF_KL    627776    // [1] (unused now)
#define OFF_FSUM  627840    // [4(h)][NP][B][D] (h stride 147456) = 589824
#define OFF_WKT   1217664   // [M][D][D] Wk transposed (1769472)
#define OFF_ARENA 2987136   // Q partials (24 slots, 73728) -> agg partials (48) -> out partials (72 x 32768)
#define OFF_ARENA2 6526080  // qk partials (24 slots, stride 147456) then E/G partials (72 slots, stride 73728)
#define OFF_KLP   11834496  // [1536] per-block KL partials (after ARENA2's E/G region)

__device__ __forceinline__ float wave_reduce(float v) {
    #pragma unroll
    for (int o = 32; o > 0; o >>= 1) v += __shfl_down(v, o, 64);
    return v;
}

__device__ __forceinline__ float sigmoidf(float x) {
    return 1.0f / (1.0f + __expf(-x));
}

__device__ __forceinline__ float dot4(float4 a, float4 b) {
    return a.x * b.x + a.y * b.y + a.z * b.z + a.w * b.w;
}

__device__ __forceinline__ void fma4(float4& a, float s, float4 w) {
    a.x += s * w.x; a.y += s * w.y; a.z += s * w.z; a.w += s * w.w;
}

// L1: fused prep + Q partials.
// blocks 0..71 vector-dots, 72..86 scalar consts, 87..518 Wk transpose,
// 519..806 Q GEMV partials (feats_s0 @ Wq, split-K 24).
__global__ __launch_bounds__(256) void k_prep2(const float* feats,
        const float* Wq, const float* Wk,
        const float* bq, const float* bk,
        const float* mu_w, const float* mu_b, const float* lv_w, const float* lv_b,
        const float* pgq_w, const float* pgq_b, const float* pgk_w, const float* pgk_b,
        float* ws) {
    int blk = blockIdx.x;
    if (blk < 72) {
        int mat = blk / 12, rg = blk % 12;
        const float* Wm; const float *va, *vb, *vc;
        float *oa, *ob, *oc; int nv;
        if (mat < 3) {
            int i = mat;
            Wm = Wq + i * D * D;
            va = mu_w + i * D; vb = lv_w + i * D; vc = pgq_w + i * D;
            oa = ws + OFF_WMU + i * D; ob = ws + OFF_WLV + i * D; oc = ws + OFF_WPGQ + i * D;
            nv = 3;
        } else {
            int j = mat - 3;
            int i1 = (j == 0) ? 1 : 0, i2 = (j == 2) ? 1 : 2;
            int p1 = 2 * i1 + ((j < i1) ? j : j - 1);
            int p2 = 2 * i2 + ((j < i2) ? j : j - 1);
            Wm = Wk + j * D * D;
            va = pgk_w + i1 * D; vb = pgk_w + i2 * D; vc = va;
            oa = ws + OFF_WPK + p1 * D; ob = ws + OFF_WPK + p2 * D; oc = oa;
            nv = 2;
        }
        int wave = threadIdx.x >> 6, lane = threadIdx.x & 63;
        const float4* va4 = (const float4*)va;
        const float4* vb4 = (const float4*)vb;
        const float4* vc4 = (const float4*)vc;
        float4 A0 = va4[lane], A1 = va4[lane + 64], A2 = va4[lane + 128];
        float4 B0 = vb4[lane], B1 = vb4[lane + 64], B2 = vb4[lane + 128];
        float4 C0 = vc4[lane], C1 = vc4[lane + 64], C2 = vc4[lane + 128];
        int base = rg * 64 + wave * 16;
        for (int r = 0; r < 16; r += 2) {
            const float4* rowP = (const float4*)(Wm + (base + r) * D);
            const float4* rowQ = (const float4*)(Wm + (base + r + 1) * D);
            float4 x0 = rowP[lane], x1 = rowP[lane + 64], x2 = rowP[lane + 128];
            float4 y0 = rowQ[lane], y1 = rowQ[lane + 64], y2 = rowQ[lane + 128];
            float daP = dot4(x0, A0) + dot4(x1, A1) + dot4(x2, A2);
            float dbP = dot4(x0, B0) + dot4(x1, B1) + dot4(x2, B2);
            float dcP = dot4(x0, C0) + dot4(x1, C1) + dot4(x2, C2);
            float daQ = dot4(y0, A0) + dot4(y1, A1) + dot4(y2, A2);
            float dbQ = dot4(y0, B0) + dot4(y1, B1) + dot4(y2, B2);
            float dcQ = dot4(y0, C0) + dot4(y1, C1) + dot4(y2, C2);
            daP = wave_reduce(daP); dbP = wave_reduce(dbP);
            daQ = wave_reduce(daQ); dbQ = wave_reduce(dbQ);
            if (nv == 3) { dcP = wave_reduce(dcP); dcQ = wave_reduce(dcQ); }
            if (lane == 0) {
                oa[base + r] = daP; ob[base + r] = dbP;
                oa[base + r + 1] = daQ; ob[base + r + 1] = dbQ;
                if (nv == 3) { oc[base + r] = dcP; oc[base + r + 1] = dcQ; }
            }
        }
    } else if (blk < 87) {
        int job = blk - 72;
        const float *a, *bvec; float bias; float* out;
        if (job < 3)      { int i = job;     a = bq + i * D; bvec = mu_w + i * D;  bias = mu_b[i];  out = ws + OFF_CMU + i; }
        else if (job < 6) { int i = job - 3; a = bq + i * D; bvec = lv_w + i * D;  bias = lv_b[i];  out = ws + OFF_CLV + i; }
        else if (job < 9) { int i = job - 6; a = bq + i * D; bvec = pgq_w + i * D; bias = pgq_b[i]; out = ws + OFF_CPGQ + i; }
        else {
            int p = job - 9, i = p / 2, c = p % 2, j = c + (c >= i ? 1 : 0);
            a = bk + j * D; bvec = pgk_w + i * D; bias = pgk_b[i]; out = ws + OFF_CPK + p;
        }
        int t = threadIdx.x;
        float part = 0.f;
        if (t < 192) part = dot4(((const float4*)a)[t], ((const float4*)bvec)[t]);
        part = wave_reduce(part);
        __shared__ float r[4];
        if ((t & 63) == 0) r[t >> 6] = part;
        __syncthreads();
        if (t == 0) *out = r[0] + r[1] + r[2] + r[3] + bias;
    } else if (blk < 519) {
        int r = blk - 87;
        int j = r / 144; r = r % 144;
        int d0 = (r / 12) * 64, e0 = (r % 12) * 64;
        __shared__ float tile[64][65];
        const float* src = Wk + j * D * D;
        for (int idx = threadIdx.x; idx < 4096; idx += 256) {
            int rr = idx / 64, cc = idx % 64;
            tile[rr][cc] = src[(d0 + rr) * D + e0 + cc];
        }
        __syncthreads();
        float* dst = ws + OFF_WKT + j * D * D;
        for (int idx = threadIdx.x; idx < 4096; idx += 256) {
            int rr = idx / 64, cc = idx % 64;
            dst[(e0 + rr) * D + d0 + cc] = tile[cc][rr];
        }
    } else {
        // Q partials: blocks (i 3, bg 4 (8 b), kc 24 (32 k))
        int qb = blk - 519;
        int i = qb / 96, r = qb % 96, bg = r / 24, kc = r % 24;
        int kbase = kc * 32;
        __shared__ __align__(16) float xs[32][8];
        for (int idx = threadIdx.x; idx < 256; idx += 256) {
            int d = idx & 31, bb = idx >> 5;
            xs[d][bb] = feats[((size_t)(i * B + bg * 8 + bb) * S) * D + kbase + d];
        }
        __syncthreads();
        if (threadIdx.x < 192) {
            int e4 = threadIdx.x * 4;
            const float* Wm = Wq + i * D * D + kbase * D + e4;
            float4 acc[8];
            #pragma unroll
            for (int bb = 0; bb < 8; bb++) acc[bb] = make_float4(0.f, 0.f, 0.f, 0.f);
            for (int k = 0; k < 32; k++) {
                float4 w = *(const float4*)(Wm + k * D);
                float4 x0 = *(const float4*)&xs[k][0];
                float4 x1 = *(const float4*)&xs[k][4];
                fma4(acc[0], x0.x, w); fma4(acc[1], x0.y, w);
                fma4(acc[2], x0.z, w); fma4(acc[3], x0.w, w);
                fma4(acc[4], x1.x, w); fma4(acc[5], x1.y, w);
                fma4(acc[6], x1.z, w); fma4(acc[7], x1.w, w);
            }
            #pragma unroll
            for (int bb = 0; bb < 8; bb++)
                *(float4*)&ws[OFF_ARENA + kc * 73728 + (i * 32 + bg * 8 + bb) * 768 + e4] = acc[bb];
        }
    }
}

// L1b: reduce Q partials (+bq) -> OFF_Q, and qbk = (Q+bq).bk for both pairs. 96 blocks (i,b).
__global__ __launch_bounds__(256) void k_redQ(const float* bq, const float* bk, float* ws) {
    int blk = blockIdx.x;
    int i = blk / B, b = blk % B;
    int fbase = (i * B + b) * D;
    int t = threadIdx.x;
    __shared__ float4 qsh[192];
    __shared__ float redsh[8];
    if (t < 192) {
        float4 a = *(const float4*)&bq[i * D + t * 4];
        #pragma unroll
        for (int kc = 0; kc < 24; kc++) {
            float4 v = *(const float4*)&ws[OFF_ARENA + kc * 73728 + fbase + t * 4];
            a.x += v.x; a.y += v.y; a.z += v.z; a.w += v.w;
        }
        *(float4*)&ws[OFF_Q + fbase + t * 4] = a;
        qsh[t] = a;
    }
    __syncthreads();
    int jA = (i == 0) ? 1 : 0, jB = (i == 2) ? 1 : 2;
    float pA_ = 0.f, pB_ = 0.f;
    if (t < 192) {
        float4 q = qsh[t];
        pA_ = dot4(q, *(const float4*)&bk[jA * D + t * 4]);
        pB_ = dot4(q, *(const float4*)&bk[jB * D + t * 4]);
    }
    pA_ = wave_reduce(pA_); pB_ = wave_reduce(pB_);
    int wave = t >> 6, lane = t & 63;
    if (lane == 0) { redsh[wave] = pA_; redsh[4 + wave] = pB_; }
    __syncthreads();
    if (t == 0) {
        ws[OFF_QBK + (2 * i) * B + b]     = redsh[0] + redsh[1] + redsh[2] + redsh[3];
        ws[OFF_QBK + (2 * i + 1) * B + b] = redsh[4] + redsh[5] + redsh[6] + redsh[7];
    }
}

// L2: qk GEMV first (long blocks, 576, reads reduced Q), then stats (1536). Total 2112.
__global__ __launch_bounds__(256) void k_stats2(const float* feats,
        const float* bq, const float* bk, float* ws) {
    int blk = blockIdx.x;
    if (blk < 576) {
        // qk partials with WkT. (j 3, vg 8, kc 24 (32 k))
        int j = blk / 192, r = blk % 192, vg = r / 24, kc = r % 24;
        int kbase = kc * 32;
        int i1 = (j == 0) ? 1 : 0, i2 = (j == 2) ? 1 : 2;
        __shared__ __align__(16) float xs[32][8];
        for (int idx = threadIdx.x; idx < 256; idx += 256) {
            int d = idx & 31, v = idx >> 5;
            int v64 = vg * 8 + v;
            int i_ = (v64 < 32) ? i1 : i2, b = v64 & 31;
            xs[d][v] = ws[OFF_Q + (i_ * 32 + b) * 768 + kbase + d];
        }
        __syncthreads();
        if (threadIdx.x < 192) {
            int e4 = threadIdx.x * 4;
            const float* Wm = ws + OFF_WKT + j * D * D + kbase * D + e4;
            float4 acc[8];
            #pragma unroll
            for (int bb = 0; bb < 8; bb++) acc[bb] = make_float4(0.f, 0.f, 0.f, 0.f);
            for (int k = 0; k < 32; k++) {
                float4 w = *(const float4*)(Wm + k * D);
                float4 x0 = *(const float4*)&xs[k][0];
                float4 x1 = *(const float4*)&xs[k][4];
                fma4(acc[0], x0.x, w); fma4(acc[1], x0.y, w);
                fma4(acc[2], x0.z, w); fma4(acc[3], x0.w, w);
                fma4(acc[4], x1.x, w); fma4(acc[5], x1.y, w);
                fma4(acc[6], x1.z, w); fma4(acc[7], x1.w, w);
            }
            #pragma unroll
            for (int v = 0; v < 8; v++)
                *(float4*)&ws[OFF_ARENA2 + kc * 147456 + (j * 64 + vg * 8 + v) * 768 + e4] = acc[v];
        }
    } else {
        int blk2 = blk - 576;
        __shared__ float klred[4];
        int wave = threadIdx.x >> 6, lane = threadIdx.x & 63;
        int m = blk2 / 512;
        int row0 = blk2 * 16 + wave * 4;
        int i1 = (m == 0) ? 1 : 0, i2 = (m == 2) ? 1 : 2;
        int p0 = 2 * i1 + ((m < i1) ? m : m - 1);
        int p1 = 2 * i2 + ((m < i2) ? m : m - 1);
        const float4* wmu  = (const float4*)(ws + OFF_WMU + m * D);
        const float4* wlv  = (const float4*)(ws + OFF_WLV + m * D);
        const float4* wpgq = (const float4*)(ws + OFF_WPGQ + m * D);
        const float4* wpk0 = (const float4*)(ws + OFF_WPK + p0 * D);
        const float4* wpk1 = (const float4*)(ws + OFF_WPK + p1 * D);
        float4 U0 = wmu[lane],  U1 = wmu[lane + 64],  U2 = wmu[lane + 128];
        float4 L0 = wlv[lane],  L1 = wlv[lane + 64],  L2 = wlv[lane + 128];
        float4 Q0 = wpgq[lane], Q1 = wpgq[lane + 64], Q2 = wpgq[lane + 128];
        float4 P0 = wpk0[lane], P1 = wpk0[lane + 64], P2 = wpk0[lane + 128];
        float4 R0 = wpk1[lane], R1 = wpk1[lane + 64], R2 = wpk1[lane + 128];
        float4 x[4][3];
        #pragma unroll
        for (int rr = 0; rr < 4; rr++) {
            const float4* f = (const float4*)(feats + (size_t)(row0 + rr) * D);
            x[rr][0] = f[lane]; x[rr][1] = f[lane + 64]; x[rr][2] = f[lane + 128];
        }
        float amu[4], alv[4], apgq[4], apk0[4], apk1[4];
        #pragma unroll
        for (int rr = 0; rr < 4; rr++) {
            amu[rr]  = dot4(x[rr][0], U0) + dot4(x[rr][1], U1) + dot4(x[rr][2], U2);
            alv[rr]  = dot4(x[rr][0], L0) + dot4(x[rr][1], L1) + dot4(x[rr][2], L2);
            apgq[rr] = dot4(x[rr][0], Q0) + dot4(x[rr][1], Q1) + dot4(x[rr][2], Q2);
            apk0[rr] = dot4(x[rr][0], P0) + dot4(x[rr][1], P1) + dot4(x[rr][2], P2);
            apk1[rr] = dot4(x[rr][0], R0) + dot4(x[rr][1], R1) + dot4(x[rr][2], R2);
        }
        #pragma unroll
        for (int rr = 0; rr < 4; rr++) {
            amu[rr] = wave_reduce(amu[rr]);  alv[rr] = wave_reduce(alv[rr]);
            apgq[rr] = wave_reduce(apgq[rr]);
            apk0[rr] = wave_reduce(apk0[rr]); apk1[rr] = wave_reduce(apk1[rr]);
        }
        if (lane == 0) {
            float cmu = ws[OFF_CMU + m], clv = ws[OFF_CLV + m];
            float cpgq = ws[OFF_CPGQ + m];
            float cpk0 = ws[OFF_CPK + p0], cpk1 = ws[OFF_CPK + p1];
            float klsum = 0.f;
            #pragma unroll
            for (int rr = 0; rr < 4; rr++) {
                int row = row0 + rr;
                int rem = row % (B * S);
                int b = rem / S, s = rem % S;
                float muv = amu[rr] + cmu;
                float lvv = alv[rr] + clv;
                ws[OFF_MU + row] = muv;
                ws[OFF_LV + row] = lvv;
                ws[OFF_PKPRE + (p0 * B + b) * S + s] = apk0[rr] + cpk0;
                ws[OFF_PKPRE + (p1 * B + b) * S + s] = apk1[rr] + cpk1;
                if (s == 0) ws[OFF_PQPRE + m * B + b] = apgq[rr] + cpgq;
                klsum += 1.0f + lvv - muv * muv - __expf(lvv);
            }
            klred[wave] = klsum;
        }
        __syncthreads();
        // per-block partial instead of device-wide atomic funnel (KL = -sum of these)
        if (threadIdx.x == 0)
            ws[OFF_KLP + blk2] = klred[0] + klred[1] + klred[2] + klred[3];
    }
}

// L2b: coalesced reduce of qk partials (24 slots) -> QK[p][b][d]. 144 blocks x 256.
__global__ __launch_bounds__(256) void k_redqk(float* ws) {
    int idx = blockIdx.x * 256 + threadIdx.x;
    int fidx = idx * 4;
    int row = fidx / 768, d = fidx % 768;
    int j = row / 64, v64 = row % 64;
    int b = v64 & 31, islot = v64 >> 5;
    int i_ = islot ? ((j == 2) ? 1 : 2) : ((j == 0) ? 1 : 0);
    int p = 2 * i_ + ((j < i_) ? j : j - 1);
    float4 a = make_float4(0.f, 0.f, 0.f, 0.f);
    #pragma unroll
    for (int kc = 0; kc < 24; kc++) {
        float4 v = *(const float4*)&ws[OFF_ARENA2 + kc * 147456 + fidx];
        a.x += v.x; a.y += v.y; a.z += v.z; a.w += v.w;
    }
    *(float4*)&ws[OFF_QK + (p * B + b) * D + d] = a;
}

// L3: fused scores + gates + online softmax + weighted feats sum, S split in QUARTERS.
// 384 blocks (j 3, b 32, h 4) x 1024 threads. Wave-parallel softmax (64 lanes, 2 slots).
__global__ __launch_bounds__(1024) void k_attn(const float* feats, const float* eps,
                                               const float* dyn, float* ws) {
    int blk = blockIdx.x;
    int j = blk / 128, r = blk % 128, b = r >> 2, h = r & 3;
    int i1 = (j == 0) ? 1 : 0, i2 = (j == 2) ? 1 : 2;
    int pA = 2 * i1 + ((j < i1) ? j : j - 1);
    int pB = 2 * i2 + ((j < i2) ? j : j - 1);
    __shared__ __align__(16) float q[2][768];
    __shared__ float pk[2][64];
    __shared__ float sch[2][32], wch[2][32];
    __shared__ float scal[2], pqs[2];
    int t = threadIdx.x;
    float dynv = dyn[0];
    if (t < 384) {
        int slot = t / 192;
        int d4 = (t % 192) * 4;
        int p = slot ? pB : pA;
        *(float4*)&q[slot][d4] = *(const float4*)&ws[OFF_QK + (p * B + b) * D + d4];
    } else if (t < 512) {
        int t2 = t - 384, slot = t2 >> 6, tt = t2 & 63;
        int k = h * 64 + tt;
        int iq = slot ? i2 : i1, p = slot ? pB : pA;
        float mu = ws[OFF_MU + (iq * B + b) * S + k];
        float lv = ws[OFF_LV + (iq * B + b) * S + k];
        float e  = eps[(p * B + b) * S + k];
        float g  = sigmoidf(mu + dynv * __expf(0.5f * lv) * e);
        pk[slot][tt] = sigmoidf(ws[OFF_PKPRE + (p * B + b) * S + k]) * g;
    } else if (t < 514) {
        int slot = t - 512;
        int iq = slot ? i2 : i1, p = slot ? pB : pA;
        float mu0 = ws[OFF_MU + (iq * B + b) * S];
        float lv0 = ws[OFF_LV + (iq * B + b) * S];
        float e0  = eps[(p * B + b) * S];
        float g0  = sigmoidf(mu0 + dynv * __expf(0.5f * lv0) * e0);
        pqs[slot] = sigmoidf(ws[OFF_PQPRE + iq * B + b]) * g0;
    }
    __syncthreads();
    float qbkA = ws[OFF_QBK + pA * B + b];
    float qbkB = ws[OFF_QBK + pB * B + b];
    const float* fb = feats + (size_t)((j * B + b) * S + h * 64) * D;
    float accA = 0.f, accB = 0.f;
    float mloc = -1e30f, lloc = 0.f;
    int w = t >> 6, lane = t & 63;
    for (int c = 0; c < 2; c++) {
        // dot phase: 16 waves x 2 rows = 32 rows
        #pragma unroll
        for (int e = 0; e < 2; e++) {
            int rloc = c * 32 + (w << 1) + e;
            const float4* f4 = (const float4*)(fb + (size_t)rloc * D);
            float4 x0 = f4[lane], x1 = f4[lane + 64], x2 = f4[lane + 128];
            const float4* qa4 = (const float4*)&q[0][0];
            const float4* qb4 = (const float4*)&q[1][0];
            float dA = dot4(x0, qa4[lane]) + dot4(x1, qa4[lane + 64]) + dot4(x2, qa4[lane + 128]);
            float dB = dot4(x0, qb4[lane]) + dot4(x1, qb4[lane + 64]) + dot4(x2, qb4[lane + 128]);
            dA = wave_reduce(dA); dB = wave_reduce(dB);
            if (lane == 0) {
                int kk = (w << 1) + e;
                sch[0][kk] = (dA + qbkA) * SCALE * pqs[0] * pk[0][rloc];
                sch[1][kk] = (dB + qbkB) * SCALE * pqs[1] * pk[1][rloc];
            }
        }
        __syncthreads();
        // wave-parallel online softmax: lanes 0..31 = slot A elems, 32..63 = slot B
        if (t < 64) {
            int slot = t >> 5, kk = t & 31;
            float s = sch[slot][kk];
            float mc = s;
            #pragma unroll
            for (int o = 16; o > 0; o >>= 1) mc = fmaxf(mc, __shfl_xor(mc, o, 64));
            float mn = fmaxf(mloc, mc);
            float f = __expf(mloc - mn);
            float wv = __expf(s - mn);
            float ssum = wv;
            #pragma unroll
            for (int o = 16; o > 0; o >>= 1) ssum += __shfl_xor(ssum, o, 64);
            wch[slot][kk] = wv;
            lloc = lloc * f + ssum;
            mloc = mn;
            if (kk == 0) scal[slot] = f;
        }
        __syncthreads();
        if (t < 768) {
            accA *= scal[0]; accB *= scal[1];
            const float* fcol = fb + (size_t)(c * 32) * D + t;
            #pragma unroll 8
            for (int k = 0; k < 32; k++) {
                float fv = fcol[(size_t)k * D];
                accA += wch[0][k] * fv;
                accB += wch[1][k] * fv;
            }
        }
        __syncthreads();
    }
    if (t < 768) {
        ws[OFF_FSUM + h * 147456 + (pA * B + b) * D + t] = accA;
        ws[OFF_FSUM + h * 147456 + (pB * B + b) * D + t] = accB;
    }
    if (t < 64 && (t & 31) == 0) {
        int slot = t >> 5;
        int p = slot ? pB : pA;
        float* mh = ws + OFF_MLH + (p * B + b) * 8 + h * 2;
        mh[0] = mloc; mh[1] = lloc;
    }
}

// L4: agg partials, one Wv stream per block, combining the 4 S-quarters via (m,l).
// 576 blocks (i 3, js 2, bg 4, kc 24 (32 k)) x 192.
__global__ __launch_bounds__(192) void k_agg2(const float* Wv, float* ws) {
    int blk = blockIdx.x;
    int i = blk / 192, r = blk % 192, js = r / 96, r2 = r % 96, bg = r2 / 24, kc = r2 % 24;
    int kbase = kc * 32;
    int j0 = (i == 0) ? 1 : 0, j1 = (i == 2) ? 1 : 2;
    int jv = js ? j1 : j0;
    int p = 2 * i + js;
    __shared__ __align__(16) float xs[32][8];
    __shared__ float comb[4][8];
    if (threadIdx.x < 8) {
        int bb = threadIdx.x;
        const float* mh = ws + OFF_MLH + (p * B + bg * 8 + bb) * 8;
        float m0 = mh[0], l0 = mh[1], m1 = mh[2], l1 = mh[3];
        float m2 = mh[4], l2 = mh[5], m3 = mh[6], l3 = mh[7];
        float Mx = fmaxf(fmaxf(m0, m1), fmaxf(m2, m3));
        float e0 = __expf(m0 - Mx), e1 = __expf(m1 - Mx);
        float e2 = __expf(m2 - Mx), e3 = __expf(m3 - Mx);
        float L = e0 * l0 + e1 * l1 + e2 * l2 + e3 * l3;
        comb[0][bb] = e0 / L; comb[1][bb] = e1 / L;
        comb[2][bb] = e2 / L; comb[3][bb] = e3 / L;
    }
    __syncthreads();
    for (int idx = threadIdx.x; idx < 256; idx += 192) {
        int d = idx & 31, bb = idx >> 5;
        int base = OFF_FSUM + (p * B + bg * 8 + bb) * D + kbase + d;
        xs[d][bb] = comb[0][bb] * ws[base]
                  + comb[1][bb] * ws[base + 147456]
                  + comb[2][bb] * ws[base + 2 * 147456]
                  + comb[3][bb] * ws[base + 3 * 147456];
    }
    __syncthreads();
    int e4 = threadIdx.x * 4;
    const float* W0 = Wv + jv * D * D + kbase * D + e4;
    float4 acc[8];
    #pragma unroll
    for (int bb = 0; bb < 8; bb++) acc[bb] = make_float4(0.f, 0.f, 0.f, 0.f);
    for (int k = 0; k < 32; k++) {
        float4 w0 = *(const float4*)(W0 + k * D);
        float4 a0 = *(const float4*)&xs[k][0];
        float4 a1 = *(const float4*)&xs[k][4];
        fma4(acc[0], a0.x, w0); fma4(acc[1], a0.y, w0);
        fma4(acc[2], a0.z, w0); fma4(acc[3], a0.w, w0);
        fma4(acc[4], a1.x, w0); fma4(acc[5], a1.y, w0);
        fma4(acc[6], a1.z, w0); fma4(acc[7], a1.w, w0);
    }
    #pragma unroll
    for (int bb = 0; bb < 8; bb++)
        *(float4*)&ws[OFF_ARENA + (js * 24 + kc) * 73728 + (i * 32 + bg * 8 + bb) * 768 + e4] = acc[bb];
}

// L4b: coalesced reduce agg partials (48 slots) + bv biases -> AGG. 72 blocks x 256.
__global__ __launch_bounds__(256) void k_redA(const float* bv, float* ws) {
    int idx = blockIdx.x * 256 + threadIdx.x;
    int fidx = idx * 4;
    int i = fidx / 24576, e = fidx % 768;
    int j0 = (i == 0) ? 1 : 0, j1 = (i == 2) ? 1 : 2;
    float4 b0 = *(const float4*)&bv[j0 * 768 + e];
    float4 b1 = *(const float4*)&bv[j1 * 768 + e];
    float4 a = make_float4(b0.x + b1.x, b0.y + b1.y, b0.z + b1.z, b0.w + b1.w);
    #pragma unroll
    for (int s = 0; s < 48; s++) {
        float4 p = *(const float4*)&ws[OFF_ARENA + s * 73728 + fidx];
        a.x += p.x; a.y += p.y; a.z += p.z; a.w += p.w;
    }
    *(float4*)&ws[OFF_AGG + fidx] = a;
}

// L5: E/G partials, one stream per block. 864 blocks (kind 3, i 3, bg 4, kc 24 (32 k)).
// kind0: E partial = AGG@WE; kind1: G partial = AGG@Wh; kind2: G partial = Q@Wqc.
__global__ __launch_bounds__(192) void k_eg2(const float* WE_w, const float* Wh_w,
                                             const float* Wqc_w, float* ws) {
    int blk = blockIdx.x;
    int kind = blk / 288, r = blk % 288;
    int i = r / 96, r2 = r % 96, bg = r2 / 24, kc = r2 % 24;
    int kbase = kc * 32;
    int src = (kind == 2) ? OFF_Q : OFF_AGG;
    __shared__ __align__(16) float xs[32][8];
    for (int idx = threadIdx.x; idx < 256; idx += 192) {
        int d = idx & 31, bb = idx >> 5;
        xs[d][bb] = ws[src + (i * 32 + bg * 8 + bb) * 768 + kbase + d];
    }
    __syncthreads();
    int e4 = threadIdx.x * 4;
    const float* Wm = ((kind == 0) ? WE_w : (kind == 1) ? Wh_w : Wqc_w) + i * D * D + kbase * D + e4;
    float4 acc[8];
    #pragma unroll
    for (int bb = 0; bb < 8; bb++) acc[bb] = make_float4(0.f, 0.f, 0.f, 0.f);
    for (int k = 0; k < 32; k++) {
        float4 w = *(const float4*)(Wm + k * D);
        float4 a0 = *(const float4*)&xs[k][0];
        float4 a1 = *(const float4*)&xs[k][4];
        fma4(acc[0], a0.x, w); fma4(acc[1], a0.y, w);
        fma4(acc[2], a0.z, w); fma4(acc[3], a0.w, w);
        fma4(acc[4], a1.x, w); fma4(acc[5], a1.y, w);
        fma4(acc[6], a1.z, w); fma4(acc[7], a1.w, w);
    }
    #pragma unroll
    for (int bb = 0; bb < 8; bb++)
        *(float4*)&ws[OFF_ARENA2 + (kind * 24 + kc) * 73728 + (i * 32 + bg * 8 + bb) * 768 + e4] = acc[bb];
}

// L5b: coalesced reduce E/G partials + bias + relu. 144 blocks x 256 (first half E, rest G).
__global__ __launch_bounds__(256) void k_redEG(const float* WE_b, const float* Wh_b,
                                               const float* Wqc_b, float* ws) {
    int idx = blockIdx.x * 256 + threadIdx.x;
    int fidx = idx * 4;
    int kind = fidx / 73728;        // 0 = E, 1 = G
    int rr = fidx % 73728;
    int i = rr / 24576, e = rr % 768;
    float4 a;
    if (kind == 0) {
        a = *(const float4*)&WE_b[i * 768 + e];
        #pragma unroll
        for (int s = 0; s < 24; s++) {
            float4 p = *(const float4*)&ws[OFF_ARENA2 + s * 73728 + rr];
            a.x += p.x; a.y += p.y; a.z += p.z; a.w += p.w;
        }
    } else {
        float4 b0 = *(const float4*)&Wh_b[i * 768 + e];
        float4 b1 = *(const float4*)&Wqc_b[i * 768 + e];
        a = make_float4(b0.x + b1.x, b0.y + b1.y, b0.z + b1.z, b0.w + b1.w);
        #pragma unroll
        for (int s = 24; s < 72; s++) {
            float4 p = *(const float4*)&ws[OFF_ARENA2 + s * 73728 + rr];
            a.x += p.x; a.y += p.y; a.z += p.z; a.w += p.w;
        }
    }
    a.x = fmaxf(a.x, 0.f); a.y = fmaxf(a.y, 0.f); a.z = fmaxf(a.z, 0.f); a.w = fmaxf(a.w, 0.f);
    *(float4*)&ws[(kind ? OFF_G : OFF_E) + rr] = a;
}

// L6: LayerNorm(E)*LayerNorm(G) -> fused. 96 blocks (i,b).
__global__ __launch_bounds__(256) void k_ln2(const float* lnE_g, const float* lnE_b,
        const float* lnG_g, const float* lnG_b, float* ws) {
    int blk = blockIdx.x;
    int i = blk / B, b = blk % B;
    const float* E = ws + OFF_E + (i * B + b) * D;
    const float* G = ws + OFF_G + (i * B + b) * D;
    int t = threadIdx.x;
    float e0 = E[t], e1 = E[t + 256], e2 = E[t + 512];
    float g0 = G[t], g1 = G[t + 256], g2 = G[t + 512];
    __shared__ float r1[256], r2[256], r3[256], r4[256];
    r1[t] = e0 + e1 + e2;
    r2[t] = e0 * e0 + e1 * e1 + e2 * e2;
    r3[t] = g0 + g1 + g2;
    r4[t] = g0 * g0 + g1 * g1 + g2 * g2;
    __syncthreads();
    for (int st = 128; st > 0; st >>= 1) {
        if (t < st) { r1[t] += r1[t + st]; r2[t] += r2[t + st]; r3[t] += r3[t + st]; r4[t] += r4[t + st]; }
        __syncthreads();
    }
    float mE = r1[0] * (1.0f / D), vE = r2[0] * (1.0f / D) - mE * mE;
    float mG = r3[0] * (1.0f / D), vG = r4[0] * (1.0f / D) - mG * mG;
    float sE = rsqrtf(vE + LN_EPS), sG = rsqrtf(vG + LN_EPS);
    float* o = ws + OFF_FUSED + b * MD + i * D;
    const float* eg = lnE_g + i * D; const float* ebv = lnE_b + i * D;
    const float* gg = lnG_g + i * D; const float* gbv = lnG_b + i * D;
    o[t]       = ((e0 - mE) * sE * eg[t]       + ebv[t])       * ((g0 - mG) * sG * gg[t]       + gbv[t]);
    o[t + 256] = ((e1 - mE) * sE * eg[t + 256] + ebv[t + 256]) * ((g1 - mG) * sG * gg[t + 256] + gbv[t + 256]);
    o[t + 512] = ((e2 - mE) * sE * eg[t + 512] + ebv[t + 512]) * ((g2 - mG) * sG * gg[t + 512] + gbv[t + 512]);
}

// L7: out GEMM partials -> arena (no atomics). 288 blocks (bg 4, kc 72 (32 k)) x 256.
__global__ __launch_bounds__(256) void k_out2(const float* out_w, float* ws) {
    int blk = blockIdx.x;
    int bg = blk / 72, kc = blk % 72;
    int kbase = kc * 32;
    __shared__ __align__(16) float xs[32][8];
    for (int idx = threadIdx.x; idx < 256; idx += 256) {
        int d = idx & 31, bb = idx >> 5;
        xs[d][bb] = ws[OFF_FUSED + (bg * 8 + bb) * MD + kbase + d];
    }
    __syncthreads();
    int e4 = threadIdx.x * 4;
    const float* Wm = out_w + kbase * H + e4;
    float4 acc[8];
    #pragma unroll
    for (int bb = 0; bb < 8; bb++) acc[bb] = make_float4(0.f, 0.f, 0.f, 0.f);
    for (int k = 0; k < 32; k++) {
        float4 w = *(const float4*)(Wm + k * H);
        float4 x0 = *(const float4*)&xs[k][0];
        float4 x1 = *(const float4*)&xs[k][4];
        fma4(acc[0], x0.x, w); fma4(acc[1], x0.y, w);
        fma4(acc[2], x0.z, w); fma4(acc[3], x0.w, w);
        fma4(acc[4], x1.x, w); fma4(acc[5], x1.y, w);
        fma4(acc[6], x1.z, w); fma4(acc[7], x1.w, w);
    }
    #pragma unroll
    for (int bb = 0; bb < 8; bb++)
        *(float4*)&ws[OFF_ARENA + kc * 32768 + (bg * 8 + bb) * 1024 + e4] = acc[bb];
}

// L7b: sum out partials (72 kc) + bias; block 0 also reduces KL partials. 32 blocks (b) x 256.
__global__ __launch_bounds__(256) void k_fin(const float* out_b, float* ws, float* out) {
    int b = blockIdx.x;
    int h4 = threadIdx.x * 4;
    float4 a = *(const float4*)&out_b[h4];
    #pragma unroll
    for (int kc = 0; kc < 72; kc++) {
        float4 p = *(const float4*)&ws[OFF_ARENA + kc * 32768 + b * 1024 + h4];
        a.x += p.x; a.y += p.y; a.z += p.z; a.w += p.w;
    }
    *(float4*)&out[b * H + h4] = a;
    if (b == 0) {
        int t = threadIdx.x;
        __shared__ float kls[256];
        float s = 0.f;
        #pragma unroll
        for (int u = 0; u < 6; u++) s += ws[OFF_KLP + t + u * 256];
        kls[t] = s;
        __syncthreads();
        for (int st = 128; st > 0; st >>= 1) {
            if (t < st) kls[t] += kls[t + st];
            __syncthreads();
        }
        if (t == 0) out[B * H] = -kls[0];
    }
}

extern "C" void kernel_launch(void* const* d_in, const int* in_sizes, int n_in,
                              void* d_out, int out_size, void* d_ws, size_t ws_size,
                              hipStream_t stream) {
    const float* feats = (const float*)d_in[0];
    const float* Wq    = (const float*)d_in[1];
    const float* bq    = (const float*)d_in[2];
    const float* Wk    = (const float*)d_in[3];
    const float* bk    = (const float*)d_in[4];
    const float* Wv    = (const float*)d_in[5];
    const float* bv    = (const float*)d_in[6];
    const float* pgq_w = (const float*)d_in[7];
    const float* pgq_b = (const float*)d_in[8];
    const float* pgk_w = (const float*)d_in[9];
    const float* pgk_b = (const float*)d_in[10];
    const float* mu_w  = (const float*)d_in[11];
    const float* mu_b  = (const float*)d_in[12];
    const float* lv_w  = (const float*)d_in[13];
    const float* lv_b  = (const float*)d_in[14];
    const float* dyn   = (const float*)d_in[15];
    const float* WE_w  = (const float*)d_in[16];
    const float* WE_b  = (const float*)d_in[17];
    const float* Wh_w  = (const float*)d_in[18];
    const float* Wh_b  = (const float*)d_in[19];
    const float* Wqc_w = (const float*)d_in[20];
    const float* Wqc_b = (const float*)d_in[21];
    const float* lnE_g = (const float*)d_in[22];
    const float* lnE_b = (const float*)d_in[23];
    const float* lnG_g = (const float*)d_in[24];
    const float* lnG_b = (const float*)d_in[25];
    const float* out_w = (const float*)d_in[26];
    const float* out_b = (const float*)d_in[27];
    const float* eps   = (const float*)d_in[28];
    float* ws  = (float*)d_ws;
    float* out = (float*)d_out;

    k_prep2<<<807, 256, 0, stream>>>(feats, Wq, Wk, bq, bk, mu_w, mu_b, lv_w, lv_b,
                                     pgq_w, pgq_b, pgk_w, pgk_b, ws);
    k_redQ<<<96, 256, 0, stream>>>(bq, bk, ws);
    k_stats2<<<2112, 256, 0, stream>>>(feats, bq, bk, ws);
    k_redqk<<<144, 256, 0, stream>>>(ws);
    k_attn<<<384, 1024, 0, stream>>>(feats, eps, dyn, ws);
    k_agg2<<<576, 192, 0, stream>>>(Wv, ws);
    k_redA<<<72, 256, 0, stream>>>(bv, ws);
    k_eg2<<<864, 192, 0, stream>>>(WE_w, Wh_w, Wqc_w, ws);
    k_redEG<<<144, 256, 0, stream>>>(WE_b, Wh_b, Wqc_b, ws);
    k_ln2<<<96, 256, 0, stream>>>(lnE_g, lnE_b, lnG_g, lnG_b, ws);
    k_out2<<<288, 256, 0, stream>>>(out_w, ws);
    k_fin<<<32, 256, 0, stream>>>(out_b, ws, out);
}

// Round 6
// 296.570 us; speedup vs baseline: 1.2323x; 1.0102x over previous
//
#include <hip/hip_runtime.h>

// Problem constants (fixed by the reference)
#define M 3
#define B 32
#define S 256
#define D 768
#define H 1024
#define MD (M * D)          // 2304
#define NP (M * (M - 1))    // 6 ordered (i,j) pairs
#define SCALE 0.03608439182435161f  // 1/sqrt(768)
#define LN_EPS 1e-5f

// Workspace layout (float offsets).
#define OFF_WMU   0         // [M][D]   (WMU then WLV contiguous: staged together)
#define OFF_WLV   2304      // [M][D]
#define OFF_WPGQ  4608      // [M][D]
#define OFF_WPK   6912      // [NP][D]
#define OFF_CMU   11520     // [M]
#define OFF_CLV   11523     // [M]
#define OFF_CPGQ  11526     // [M]
#define OFF_CPK   11529     // [NP]
#define OFF_PQ    11536     // [NP][B] final pq gate (pq_base * g0)
#define OFF_Q     11776     // [M][B][D]
#define OFF_QBK   85504     // [NP][B]
#define OFF_QK    85760     // [NP][B][D] reduced qk (147456)
#define OFF_MLH   233216    // [NP][B][8(h)][2(m,l)] = 3072
#define OFF_KLP   236288    // [256] per-block KL partials
#define OFF_AGG   236544    // [M][B][D]
#define OFF_E     310272    // [M][B][D]
#define OFF_G     384000    // [M][B][D]
#define OFF_FUSED 457728    // [B][MD]
#define OFF_FSUM  531520    // [8(h)][NP][B][D] (h stride 147456) = 1179648
#define OFF_WKT   1711168   // [M][D][D] Wk transposed (1769472)
#define OFF_ARENA 3480640   // Q partials (24 x 73728) -> agg partials (48 x 73728) -> out partials (72 x 32768)
#define OFF_ARENA2 7019584  // qk partials (24 x 147456) -> E/G partials (72 x 73728)

__device__ __forceinline__ float wave_reduce(float v) {
    #pragma unroll
    for (int o = 32; o > 0; o >>= 1) v += __shfl_down(v, o, 64);
    return v;
}

__device__ __forceinline__ float sigmoidf(float x) {
    return 1.0f / (1.0f + __expf(-x));
}

__device__ __forceinline__ float dot4(float4 a, float4 b) {
    return a.x * b.x + a.y * b.y + a.z * b.z + a.w * b.w;
}

__device__ __forceinline__ void fma4(float4& a, float s, float4 w) {
    a.x += s * w.x; a.y += s * w.y; a.z += s * w.z; a.w += s * w.w;
}

// L1: fused prep + Q partials.
// blocks 0..71 vector-dots, 72..86 scalar consts, 87..518 Wk transpose,
// 519..806 Q GEMV partials (feats_s0 @ Wq, split-K 24).
__global__ __launch_bounds__(256) void k_prep2(const float* feats,
        const float* Wq, const float* Wk,
        const float* bq, const float* bk,
        const float* mu_w, const float* mu_b, const float* lv_w, const float* lv_b,
        const float* pgq_w, const float* pgq_b, const float* pgk_w, const float* pgk_b,
        float* ws) {
    int blk = blockIdx.x;
    if (blk < 72) {
        int mat = blk / 12, rg = blk % 12;
        const float* Wm; const float *va, *vb, *vc;
        float *oa, *ob, *oc; int nv;
        if (mat < 3) {
            int i = mat;
            Wm = Wq + i * D * D;
            va = mu_w + i * D; vb = lv_w + i * D; vc = pgq_w + i * D;
            oa = ws + OFF_WMU + i * D; ob = ws + OFF_WLV + i * D; oc = ws + OFF_WPGQ + i * D;
            nv = 3;
        } else {
            int j = mat - 3;
            int i1 = (j == 0) ? 1 : 0, i2 = (j == 2) ? 1 : 2;
            int p1 = 2 * i1 + ((j < i1) ? j : j - 1);
            int p2 = 2 * i2 + ((j < i2) ? j : j - 1);
            Wm = Wk + j * D * D;
            va = pgk_w + i1 * D; vb = pgk_w + i2 * D; vc = va;
            oa = ws + OFF_WPK + p1 * D; ob = ws + OFF_WPK + p2 * D; oc = oa;
            nv = 2;
        }
        int wave = threadIdx.x >> 6, lane = threadIdx.x & 63;
        const float4* va4 = (const float4*)va;
        const float4* vb4 = (const float4*)vb;
        const float4* vc4 = (const float4*)vc;
        float4 A0 = va4[lane], A1 = va4[lane + 64], A2 = va4[lane + 128];
        float4 B0 = vb4[lane], B1 = vb4[lane + 64], B2 = vb4[lane + 128];
        float4 C0 = vc4[lane], C1 = vc4[lane + 64], C2 = vc4[lane + 128];
        int base = rg * 64 + wave * 16;
        for (int r = 0; r < 16; r += 2) {
            const float4* rowP = (const float4*)(Wm + (base + r) * D);
            const float4* rowQ = (const float4*)(Wm + (base + r + 1) * D);
            float4 x0 = rowP[lane], x1 = rowP[lane + 64], x2 = rowP[lane + 128];
            float4 y0 = rowQ[lane], y1 = rowQ[lane + 64], y2 = rowQ[lane + 128];
            float daP = dot4(x0, A0) + dot4(x1, A1) + dot4(x2, A2);
            float dbP = dot4(x0, B0) + dot4(x1, B1) + dot4(x2, B2);
            float dcP = dot4(x0, C0) + dot4(x1, C1) + dot4(x2, C2);
            float daQ = dot4(y0, A0) + dot4(y1, A1) + dot4(y2, A2);
            float dbQ = dot4(y0, B0) + dot4(y1, B1) + dot4(y2, B2);
            float dcQ = dot4(y0, C0) + dot4(y1, C1) + dot4(y2, C2);
            daP = wave_reduce(daP); dbP = wave_reduce(dbP);
            daQ = wave_reduce(daQ); dbQ = wave_reduce(dbQ);
            if (nv == 3) { dcP = wave_reduce(dcP); dcQ = wave_reduce(dcQ); }
            if (lane == 0) {
                oa[base + r] = daP; ob[base + r] = dbP;
                oa[base + r + 1] = daQ; ob[base + r + 1] = dbQ;
                if (nv == 3) { oc[base + r] = dcP; oc[base + r + 1] = dcQ; }
            }
        }
    } else if (blk < 87) {
        int job = blk - 72;
        const float *a, *bvec; float bias; float* out;
        if (job < 3)      { int i = job;     a = bq + i * D; bvec = mu_w + i * D;  bias = mu_b[i];  out = ws + OFF_CMU + i; }
        else if (job < 6) { int i = job - 3; a = bq + i * D; bvec = lv_w + i * D;  bias = lv_b[i];  out = ws + OFF_CLV + i; }
        else if (job < 9) { int i = job - 6; a = bq + i * D; bvec = pgq_w + i * D; bias = pgq_b[i]; out = ws + OFF_CPGQ + i; }
        else {
            int p = job - 9, i = p / 2, c = p % 2, j = c + (c >= i ? 1 : 0);
            a = bk + j * D; bvec = pgk_w + i * D; bias = pgk_b[i]; out = ws + OFF_CPK + p;
        }
        int t = threadIdx.x;
        float part = 0.f;
        if (t < 192) part = dot4(((const float4*)a)[t], ((const float4*)bvec)[t]);
        part = wave_reduce(part);
        __shared__ float r[4];
        if ((t & 63) == 0) r[t >> 6] = part;
        __syncthreads();
        if (t == 0) *out = r[0] + r[1] + r[2] + r[3] + bias;
    } else if (blk < 519) {
        int r = blk - 87;
        int j = r / 144; r = r % 144;
        int d0 = (r / 12) * 64, e0 = (r % 12) * 64;
        __shared__ float tile[64][65];
        const float* src = Wk + j * D * D;
        for (int idx = threadIdx.x; idx < 4096; idx += 256) {
            int rr = idx / 64, cc = idx % 64;
            tile[rr][cc] = src[(d0 + rr) * D + e0 + cc];
        }
        __syncthreads();
        float* dst = ws + OFF_WKT + j * D * D;
        for (int idx = threadIdx.x; idx < 4096; idx += 256) {
            int rr = idx / 64, cc = idx % 64;
            dst[(e0 + rr) * D + d0 + cc] = tile[cc][rr];
        }
    } else {
        // Q partials: blocks (i 3, bg 4 (8 b), kc 24 (32 k))
        int qb = blk - 519;
        int i = qb / 96, r = qb % 96, bg = r / 24, kc = r % 24;
        int kbase = kc * 32;
        __shared__ __align__(16) float xs[32][8];
        for (int idx = threadIdx.x; idx < 256; idx += 256) {
            int d = idx & 31, bb = idx >> 5;
            xs[d][bb] = feats[((size_t)(i * B + bg * 8 + bb) * S) * D + kbase + d];
        }
        __syncthreads();
        if (threadIdx.x < 192) {
            int e4 = threadIdx.x * 4;
            const float* Wm = Wq + i * D * D + kbase * D + e4;
            float4 acc[8];
            #pragma unroll
            for (int bb = 0; bb < 8; bb++) acc[bb] = make_float4(0.f, 0.f, 0.f, 0.f);
            for (int k = 0; k < 32; k++) {
                float4 w = *(const float4*)(Wm + k * D);
                float4 x0 = *(const float4*)&xs[k][0];
                float4 x1 = *(const float4*)&xs[k][4];
                fma4(acc[0], x0.x, w); fma4(acc[1], x0.y, w);
                fma4(acc[2], x0.z, w); fma4(acc[3], x0.w, w);
                fma4(acc[4], x1.x, w); fma4(acc[5], x1.y, w);
                fma4(acc[6], x1.z, w); fma4(acc[7], x1.w, w);
            }
            #pragma unroll
            for (int bb = 0; bb < 8; bb++)
                *(float4*)&ws[OFF_ARENA + kc * 73728 + (i * 32 + bg * 8 + bb) * 768 + e4] = acc[bb];
        }
    }
}

// L1b: reduce Q partials (+bq) -> OFF_Q, qbk = Q.bk, and PQ gate from feats row 0. 96 blocks (i,b).
__global__ __launch_bounds__(256) void k_redQ(const float* feats, const float* bq,
        const float* bk, const float* eps, const float* dyn, float* ws) {
    int blk = blockIdx.x;
    int i = blk / B, b = blk % B;
    int fbase = (i * B + b) * D;
    int t = threadIdx.x;
    int wave = t >> 6, lane = t & 63;
    __shared__ float4 qsh[192];
    __shared__ float redsh[8];
    __shared__ float pqred[12];
    if (t < 192) {
        float4 a = *(const float4*)&bq[i * D + t * 4];
        #pragma unroll
        for (int kc = 0; kc < 24; kc++) {
            float4 v = *(const float4*)&ws[OFF_ARENA + kc * 73728 + fbase + t * 4];
            a.x += v.x; a.y += v.y; a.z += v.z; a.w += v.w;
        }
        *(float4*)&ws[OFF_Q + fbase + t * 4] = a;
        qsh[t] = a;
    }
    __syncthreads();
    int jA = (i == 0) ? 1 : 0, jB = (i == 2) ? 1 : 2;
    float pA_ = 0.f, pB_ = 0.f;
    if (t < 192) {
        float4 q = qsh[t];
        pA_ = dot4(q, *(const float4*)&bk[jA * D + t * 4]);
        pB_ = dot4(q, *(const float4*)&bk[jB * D + t * 4]);
    }
    pA_ = wave_reduce(pA_); pB_ = wave_reduce(pB_);
    if (lane == 0) { redsh[wave] = pA_; redsh[4 + wave] = pB_; }
    // PQ: stats of feats row s=0 for modality i
    float dm = 0.f, dl = 0.f, dp = 0.f;
    if (t < 192) {
        float4 x = *(const float4*)&feats[((size_t)(i * B + b) * S) * D + t * 4];
        dm = dot4(x, *(const float4*)&ws[OFF_WMU + i * D + t * 4]);
        dl = dot4(x, *(const float4*)&ws[OFF_WLV + i * D + t * 4]);
        dp = dot4(x, *(const float4*)&ws[OFF_WPGQ + i * D + t * 4]);
    }
    dm = wave_reduce(dm); dl = wave_reduce(dl); dp = wave_reduce(dp);
    if (lane == 0 && wave < 3) { pqred[wave] = dm; pqred[4 + wave] = dl; pqred[8 + wave] = dp; }
    __syncthreads();
    if (t == 0) {
        ws[OFF_QBK + (2 * i) * B + b]     = redsh[0] + redsh[1] + redsh[2] + redsh[3];
        ws[OFF_QBK + (2 * i + 1) * B + b] = redsh[4] + redsh[5] + redsh[6] + redsh[7];
        float mu0 = pqred[0] + pqred[1] + pqred[2] + ws[OFF_CMU + i];
        float lv0 = pqred[4] + pqred[5] + pqred[6] + ws[OFF_CLV + i];
        float pqb = pqred[8] + pqred[9] + pqred[10] + ws[OFF_CPGQ + i];
        float sd = dyn[0] * __expf(0.5f * lv0);
        float pqs = sigmoidf(pqb);
        #pragma unroll
        for (int c = 0; c < 2; c++) {
            int p = 2 * i + c;
            float e0 = eps[(size_t)(p * B + b) * S];
            ws[OFF_PQ + p * B + b] = pqs * sigmoidf(mu0 + sd * e0);
        }
    }
}

// L2: qk GEMV partials with WkT (reads reduced Q). 576 blocks (j 3, vg 8, kc 24 (32 k)).
__global__ __launch_bounds__(256) void k_qk(float* ws) {
    int blk = blockIdx.x;
    int j = blk / 192, r = blk % 192, vg = r / 24, kc = r % 24;
    int kbase = kc * 32;
    int i1 = (j == 0) ? 1 : 0, i2 = (j == 2) ? 1 : 2;
    __shared__ __align__(16) float xs[32][8];
    for (int idx = threadIdx.x; idx < 256; idx += 256) {
        int d = idx & 31, v = idx >> 5;
        int v64 = vg * 8 + v;
        int i_ = (v64 < 32) ? i1 : i2, b = v64 & 31;
        xs[d][v] = ws[OFF_Q + (i_ * 32 + b) * 768 + kbase + d];
    }
    __syncthreads();
    if (threadIdx.x < 192) {
        int e4 = threadIdx.x * 4;
        const float* Wm = ws + OFF_WKT + j * D * D + kbase * D + e4;
        float4 acc[8];
        #pragma unroll
        for (int bb = 0; bb < 8; bb++) acc[bb] = make_float4(0.f, 0.f, 0.f, 0.f);
        for (int k = 0; k < 32; k++) {
            float4 w = *(const float4*)(Wm + k * D);
            float4 x0 = *(const float4*)&xs[k][0];
            float4 x1 = *(const float4*)&xs[k][4];
            fma4(acc[0], x0.x, w); fma4(acc[1], x0.y, w);
            fma4(acc[2], x0.z, w); fma4(acc[3], x0.w, w);
            fma4(acc[4], x1.x, w); fma4(acc[5], x1.y, w);
            fma4(acc[6], x1.z, w); fma4(acc[7], x1.w, w);
        }
        #pragma unroll
        for (int v = 0; v < 8; v++)
            *(float4*)&ws[OFF_ARENA2 + kc * 147456 + (j * 64 + vg * 8 + v) * 768 + e4] = acc[v];
    }
}

// L2b: coalesced reduce of qk partials (24 slots) -> QK[p][b][d]. 144 blocks x 256.
__global__ __launch_bounds__(256) void k_redqk(float* ws) {
    int idx = blockIdx.x * 256 + threadIdx.x;
    int fidx = idx * 4;
    int row = fidx / 768, d = fidx % 768;
    int j = row / 64, v64 = row % 64;
    int b = v64 & 31, islot = v64 >> 5;
    int i_ = islot ? ((j == 2) ? 1 : 2) : ((j == 0) ? 1 : 0);
    int p = 2 * i_ + ((j < i_) ? j : j - 1);
    float4 a = make_float4(0.f, 0.f, 0.f, 0.f);
    #pragma unroll
    for (int kc = 0; kc < 24; kc++) {
        float4 v = *(const float4*)&ws[OFF_ARENA2 + kc * 147456 + fidx];
        a.x += v.x; a.y += v.y; a.z += v.z; a.w += v.w;
    }
    *(float4*)&ws[OFF_QK + (p * B + b) * D + d] = a;
}

// L3: MEGA-FUSED single feats pass: per (b, 32-row chunk h) across ALL modalities:
// stats (mu/lv/pkpre + KL) + score dots + gates + chunk softmax + weighted feats sum.
// 256 blocks (b 32, h 8) x 1024 threads.
__global__ __launch_bounds__(1024) void k_fused(const float* feats, const float* eps,
                                                const float* dyn, float* ws) {
    int blk = blockIdx.x;
    int b = blk >> 3, h = blk & 7;
    int t = threadIdx.x;
    int w = t >> 6, lane = t & 63;
    __shared__ __align__(16) float swA[4608];   // WMU[3][768] | WLV[3][768]
    __shared__ __align__(16) float swPK[4608];  // WPK[6][768]
    __shared__ __align__(16) float sqk[4608];   // qk[6][768]
    __shared__ float raws[6][32], pkps[6][32], mus[3][32], lvs[3][32], wgt[6][32];
    __shared__ float klv[96];
    __shared__ float pq_s[6], qbk_s[6], cmu_s[3], clv_s[3], cpk_s[6];
    {
        const float4* srcA = (const float4*)(ws + OFF_WMU);
        const float4* srcP = (const float4*)(ws + OFF_WPK);
        float4* dA = (float4*)swA;
        float4* dP = (float4*)swPK;
        float4* dQ = (float4*)sqk;
        for (int idx = t; idx < 1152; idx += 1024) {
            dA[idx] = srcA[idx];
            dP[idx] = srcP[idx];
            int p = idx / 192, d4 = (idx % 192) * 4;
            dQ[idx] = *(const float4*)&ws[OFF_QK + (p * B + b) * D + d4];
        }
        if (t < 6) { pq_s[t] = ws[OFF_PQ + t * B + b]; qbk_s[t] = ws[OFF_QBK + t * B + b]; cpk_s[t] = ws[OFF_CPK + t]; }
        else if (t < 9) { cmu_s[t - 6] = ws[OFF_CMU + t - 6]; clv_s[t - 6] = ws[OFF_CLV + t - 6]; }
    }
    __syncthreads();
    // phase 1: 96 row tasks (m,k): 6 dots each (mu, lv, pk for 2 pairs keyed by m, raw scores for same)
    const float4* swA4 = (const float4*)swA;
    const float4* swPK4 = (const float4*)swPK;
    const float4* sqk4 = (const float4*)sqk;
    for (int tau = w * 6; tau < w * 6 + 6; tau++) {
        int m = tau >> 5, k = tau & 31;
        const float4* row = (const float4*)(feats + ((size_t)((m * B + b) * S) + h * 32 + k) * D);
        float4 x0 = row[lane], x1 = row[lane + 64], x2 = row[lane + 128];
        int i1 = (m == 0) ? 1 : 0, i2 = (m == 2) ? 1 : 2;
        int pj0 = 2 * i1 + ((m < i1) ? m : m - 1);
        int pj1 = 2 * i2 + ((m < i2) ? m : m - 1);
        int oM = m * 192, oL = (3 + m) * 192, o0 = pj0 * 192, o1 = pj1 * 192;
        float dmu = dot4(x0, swA4[oM + lane]) + dot4(x1, swA4[oM + lane + 64]) + dot4(x2, swA4[oM + lane + 128]);
        float dlv = dot4(x0, swA4[oL + lane]) + dot4(x1, swA4[oL + lane + 64]) + dot4(x2, swA4[oL + lane + 128]);
        float dk0 = dot4(x0, swPK4[o0 + lane]) + dot4(x1, swPK4[o0 + lane + 64]) + dot4(x2, swPK4[o0 + lane + 128]);
        float dk1 = dot4(x0, swPK4[o1 + lane]) + dot4(x1, swPK4[o1 + lane + 64]) + dot4(x2, swPK4[o1 + lane + 128]);
        float dr0 = dot4(x0, sqk4[o0 + lane]) + dot4(x1, sqk4[o0 + lane + 64]) + dot4(x2, sqk4[o0 + lane + 128]);
        float dr1 = dot4(x0, sqk4[o1 + lane]) + dot4(x1, sqk4[o1 + lane + 64]) + dot4(x2, sqk4[o1 + lane + 128]);
        dmu = wave_reduce(dmu); dlv = wave_reduce(dlv);
        dk0 = wave_reduce(dk0); dk1 = wave_reduce(dk1);
        dr0 = wave_reduce(dr0); dr1 = wave_reduce(dr1);
        if (lane == 0) {
            mus[m][k] = dmu + cmu_s[m];
            lvs[m][k] = dlv + clv_s[m];
            pkps[pj0][k] = dk0 + cpk_s[pj0];
            pkps[pj1][k] = dk1 + cpk_s[pj1];
            raws[pj0][k] = dr0;
            raws[pj1][k] = dr1;
        }
    }
    __syncthreads();
    float dynv = dyn[0];
    // phase 2: gates + scores + per-chunk softmax (6 pairs in 3 waves), KL terms in waves 3-4
    if (t < 192) {
        int p = t >> 5, k = t & 31;
        int iq = p >> 1;
        float e = eps[(size_t)(p * B + b) * S + h * 32 + k];
        float g = sigmoidf(mus[iq][k] + dynv * __expf(0.5f * lvs[iq][k]) * e);
        float pk = sigmoidf(pkps[p][k]) * g;
        float s = (raws[p][k] + qbk_s[p]) * SCALE * pq_s[p] * pk;
        float mc = s;
        #pragma unroll
        for (int o = 16; o > 0; o >>= 1) mc = fmaxf(mc, __shfl_xor(mc, o, 64));
        float wv_ = __expf(s - mc);
        float l = wv_;
        #pragma unroll
        for (int o = 16; o > 0; o >>= 1) l += __shfl_xor(l, o, 64);
        wgt[p][k] = wv_;
        if (k == 0) {
            float* mh = ws + OFF_MLH + (p * B + b) * 16 + h * 2;
            mh[0] = mc; mh[1] = l;
        }
    } else if (t < 288) {
        int tau = t - 192;
        int m = tau >> 5, k = tau & 31;
        float muv = mus[m][k], lvv = lvs[m][k];
        klv[tau] = 1.0f + lvv - muv * muv - __expf(lvv);
    }
    __syncthreads();
    // phase 4: weighted feats sum per target modality (2 pairs each), unnormalized
    if (t < 768) {
        #pragma unroll
        for (int jm = 0; jm < 3; jm++) {
            int i1 = (jm == 0) ? 1 : 0, i2 = (jm == 2) ? 1 : 2;
            int pj0 = 2 * i1 + ((jm < i1) ? jm : jm - 1);
            int pj1 = 2 * i2 + ((jm < i2) ? jm : jm - 1);
            const float* col = feats + ((size_t)((jm * B + b) * S) + h * 32) * D + t;
            float accA = 0.f, accB = 0.f;
            #pragma unroll 8
            for (int k = 0; k < 32; k++) {
                float fv = col[(size_t)k * D];
                accA += wgt[pj0][k] * fv;
                accB += wgt[pj1][k] * fv;
            }
            ws[OFF_FSUM + h * 147456 + (pj0 * B + b) * D + t] = accA;
            ws[OFF_FSUM + h * 147456 + (pj1 * B + b) * D + t] = accB;
        }
    }
    if (t < 64) {
        float s2 = klv[t] + ((t < 32) ? klv[64 + t] : 0.f);
        s2 = wave_reduce(s2);
        if (t == 0) ws[OFF_KLP + blk] = s2;
    }
}

// L4: agg partials, one Wv stream per block, combining 8 S-chunks via (m,l).
// 576 blocks (i 3, js 2, bg 4, kc 24 (32 k)) x 192.
__global__ __launch_bounds__(192) void k_agg2(const float* Wv, float* ws) {
    int blk = blockIdx.x;
    int i = blk / 192, r = blk % 192, js = r / 96, r2 = r % 96, bg = r2 / 24, kc = r2 % 24;
    int kbase = kc * 32;
    int j0 = (i == 0) ? 1 : 0, j1 = (i == 2) ? 1 : 2;
    int jv = js ? j1 : j0;
    int p = 2 * i + js;
    __shared__ __align__(16) float xs[32][8];
    __shared__ float comb[8][8];
    if (threadIdx.x < 8) {
        int bb = threadIdx.x;
        const float* mh = ws + OFF_MLH + (p * B + bg * 8 + bb) * 16;
        float mm[8], ll[8];
        float mx = -1e30f;
        #pragma unroll
        for (int hh = 0; hh < 8; hh++) { mm[hh] = mh[2 * hh]; ll[hh] = mh[2 * hh + 1]; mx = fmaxf(mx, mm[hh]); }
        float L = 0.f;
        float ee[8];
        #pragma unroll
        for (int hh = 0; hh < 8; hh++) { ee[hh] = __expf(mm[hh] - mx); L += ee[hh] * ll[hh]; }
        #pragma unroll
        for (int hh = 0; hh < 8; hh++) comb[hh][bb] = ee[hh] / L;
    }
    __syncthreads();
    for (int idx = threadIdx.x; idx < 256; idx += 192) {
        int d = idx & 31, bb = idx >> 5;
        int base = OFF_FSUM + (p * B + bg * 8 + bb) * D + kbase + d;
        float v = 0.f;
        #pragma unroll
        for (int hh = 0; hh < 8; hh++) v += comb[hh][bb] * ws[base + hh * 147456];
        xs[d][bb] = v;
    }
    __syncthreads();
    int e4 = threadIdx.x * 4;
    const float* W0 = Wv + jv * D * D + kbase * D + e4;
    float4 acc[8];
    #pragma unroll
    for (int bb = 0; bb < 8; bb++) acc[bb] = make_float4(0.f, 0.f, 0.f, 0.f);
    for (int k = 0; k < 32; k++) {
        float4 w0 = *(const float4*)(W0 + k * D);
        float4 a0 = *(const float4*)&xs[k][0];
        float4 a1 = *(const float4*)&xs[k][4];
        fma4(acc[0], a0.x, w0); fma4(acc[1], a0.y, w0);
        fma4(acc[2], a0.z, w0); fma4(acc[3], a0.w, w0);
        fma4(acc[4], a1.x, w0); fma4(acc[5], a1.y, w0);
        fma4(acc[6], a1.z, w0); fma4(acc[7], a1.w, w0);
    }
    #pragma unroll
    for (int bb = 0; bb < 8; bb++)
        *(float4*)&ws[OFF_ARENA + (js * 24 + kc) * 73728 + (i * 32 + bg * 8 + bb) * 768 + e4] = acc[bb];
}

// L4b: coalesced reduce agg partials (48 slots) + bv biases -> AGG. 72 blocks x 256.
__global__ __launch_bounds__(256) void k_redA(const float* bv, float* ws) {
    int idx = blockIdx.x * 256 + threadIdx.x;
    int fidx = idx * 4;
    int i = fidx / 24576, e = fidx % 768;
    int j0 = (i == 0) ? 1 : 0, j1 = (i == 2) ? 1 : 2;
    float4 b0 = *(const float4*)&bv[j0 * 768 + e];
    float4 b1 = *(const float4*)&bv[j1 * 768 + e];
    float4 a = make_float4(b0.x + b1.x, b0.y + b1.y, b0.z + b1.z, b0.w + b1.w);
    #pragma unroll
    for (int s = 0; s < 48; s++) {
        float4 p = *(const float4*)&ws[OFF_ARENA + s * 73728 + fidx];
        a.x += p.x; a.y += p.y; a.z += p.z; a.w += p.w;
    }
    *(float4*)&ws[OFF_AGG + fidx] = a;
}

// L5: E/G partials, one stream per block. 864 blocks (kind 3, i 3, bg 4, kc 24 (32 k)).
__global__ __launch_bounds__(192) void k_eg2(const float* WE_w, const float* Wh_w,
                                             const float* Wqc_w, float* ws) {
    int blk = blockIdx.x;
    int kind = blk / 288, r = blk % 288;
    int i = r / 96, r2 = r % 96, bg = r2 / 24, kc = r2 % 24;
    int kbase = kc * 32;
    int src = (kind == 2) ? OFF_Q : OFF_AGG;
    __shared__ __align__(16) float xs[32][8];
    for (int idx = threadIdx.x; idx < 256; idx += 192) {
        int d = idx & 31, bb = idx >> 5;
        xs[d][bb] = ws[src + (i * 32 + bg * 8 + bb) * 768 + kbase + d];
    }
    __syncthreads();
    int e4 = threadIdx.x * 4;
    const float* Wm = ((kind == 0) ? WE_w : (kind == 1) ? Wh_w : Wqc_w) + i * D * D + kbase * D + e4;
    float4 acc[8];
    #pragma unroll
    for (int bb = 0; bb < 8; bb++) acc[bb] = make_float4(0.f, 0.f, 0.f, 0.f);
    for (int k = 0; k < 32; k++) {
        float4 w = *(const float4*)(Wm + k * D);
        float4 a0 = *(const float4*)&xs[k][0];
        float4 a1 = *(const float4*)&xs[k][4];
        fma4(acc[0], a0.x, w); fma4(acc[1], a0.y, w);
        fma4(acc[2], a0.z, w); fma4(acc[3], a0.w, w);
        fma4(acc[4], a1.x, w); fma4(acc[5], a1.y, w);
        fma4(acc[6], a1.z, w); fma4(acc[7], a1.w, w);
    }
    #pragma unroll
    for (int bb = 0; bb < 8; bb++)
        *(float4*)&ws[OFF_ARENA2 + (kind * 24 + kc) * 73728 + (i * 32 + bg * 8 + bb) * 768 + e4] = acc[bb];
}

// L5b: coalesced reduce E/G partials + bias + relu. 144 blocks x 256.
__global__ __launch_bounds__(256) void k_redEG(const float* WE_b, const float* Wh_b,
                                               const float* Wqc_b, float* ws) {
    int idx = blockIdx.x * 256 + threadIdx.x;
    int fidx = idx * 4;
    int kind = fidx / 73728;        // 0 = E, 1 = G
    int rr = fidx % 73728;
    int i = rr / 24576, e = rr % 768;
    float4 a;
    if (kind == 0) {
        a = *(const float4*)&WE_b[i * 768 + e];
        #pragma unroll
        for (int s = 0; s < 24; s++) {
            float4 p = *(const float4*)&ws[OFF_ARENA2 + s * 73728 + rr];
            a.x += p.x; a.y += p.y; a.z += p.z; a.w += p.w;
        }
    } else {
        float4 b0 = *(const float4*)&Wh_b[i * 768 + e];
        float4 b1 = *(const float4*)&Wqc_b[i * 768 + e];
        a = make_float4(b0.x + b1.x, b0.y + b1.y, b0.z + b1.z, b0.w + b1.w);
        #pragma unroll
        for (int s = 24; s < 72; s++) {
            float4 p = *(const float4*)&ws[OFF_ARENA2 + s * 73728 + rr];
            a.x += p.x; a.y += p.y; a.z += p.z; a.w += p.w;
        }
    }
    a.x = fmaxf(a.x, 0.f); a.y = fmaxf(a.y, 0.f); a.z = fmaxf(a.z, 0.f); a.w = fmaxf(a.w, 0.f);
    *(float4*)&ws[(kind ? OFF_G : OFF_E) + rr] = a;
}

// L6: LayerNorm(E)*LayerNorm(G) -> fused. 96 blocks (i,b).
__global__ __launch_bounds__(256) void k_ln2(const float* lnE_g, const float* lnE_b,
        const float* lnG_g, const float* lnG_b, float* ws) {
    int blk = blockIdx.x;
    int i = blk / B, b = blk % B;
    const float* E = ws + OFF_E + (i * B + b) * D;
    const float* G = ws + OFF_G + (i * B + b) * D;
    int t = threadIdx.x;
    float e0 = E[t], e1 = E[t + 256], e2 = E[t + 512];
    float g0 = G[t], g1 = G[t + 256], g2 = G[t + 512];
    __shared__ float r1[256], r2[256], r3[256], r4[256];
    r1[t] = e0 + e1 + e2;
    r2[t] = e0 * e0 + e1 * e1 + e2 * e2;
    r3[t] = g0 + g1 + g2;
    r4[t] = g0 * g0 + g1 * g1 + g2 * g2;
    __syncthreads();
    for (int st = 128; st > 0; st >>= 1) {
        if (t < st) { r1[t] += r1[t + st]; r2[t] += r2[t + st]; r3[t] += r3[t + st]; r4[t] += r4[t + st]; }
        __syncthreads();
    }
    float mE = r1[0] * (1.0f / D), vE = r2[0] * (1.0f / D) - mE * mE;
    float mG = r3[0] * (1.0f / D), vG = r4[0] * (1.0f / D) - mG * mG;
    float sE = rsqrtf(vE + LN_EPS), sG = rsqrtf(vG + LN_EPS);
    float* o = ws + OFF_FUSED + b * MD + i * D;
    const float* eg = lnE_g + i * D; const float* ebv = lnE_b + i * D;
    const float* gg = lnG_g + i * D; const float* gbv = lnG_b + i * D;
    o[t]       = ((e0 - mE) * sE * eg[t]       + ebv[t])       * ((g0 - mG) * sG * gg[t]       + gbv[t]);
    o[t + 256] = ((e1 - mE) * sE * eg[t + 256] + ebv[t + 256]) * ((g1 - mG) * sG * gg[t + 256] + gbv[t + 256]);
    o[t + 512] = ((e2 - mE) * sE * eg[t + 512] + ebv[t + 512]) * ((g2 - mG) * sG * gg[t + 512] + gbv[t + 512]);
}

// L7: out GEMM partials -> arena (no atomics). 288 blocks (bg 4, kc 72 (32 k)) x 256.
__global__ __launch_bounds__(256) void k_out2(const float* out_w, float* ws) {
    int blk = blockIdx.x;
    int bg = blk / 72, kc = blk % 72;
    int kbase = kc * 32;
    __shared__ __align__(16) float xs[32][8];
    for (int idx = threadIdx.x; idx < 256; idx += 256) {
        int d = idx & 31, bb = idx >> 5;
        xs[d][bb] = ws[OFF_FUSED + (bg * 8 + bb) * MD + kbase + d];
    }
    __syncthreads();
    int e4 = threadIdx.x * 4;
    const float* Wm = out_w + kbase * H + e4;
    float4 acc[8];
    #pragma unroll
    for (int bb = 0; bb < 8; bb++) acc[bb] = make_float4(0.f, 0.f, 0.f, 0.f);
    for (int k = 0; k < 32; k++) {
        float4 w = *(const float4*)(Wm + k * H);
        float4 x0 = *(const float4*)&xs[k][0];
        float4 x1 = *(const float4*)&xs[k][4];
        fma4(acc[0], x0.x, w); fma4(acc[1], x0.y, w);
        fma4(acc[2], x0.z, w); fma4(acc[3], x0.w, w);
        fma4(acc[4], x1.x, w); fma4(acc[5], x1.y, w);
        fma4(acc[6], x1.z, w); fma4(acc[7], x1.w, w);
    }
    #pragma unroll
    for (int bb = 0; bb < 8; bb++)
        *(float4*)&ws[OFF_ARENA + kc * 32768 + (bg * 8 + bb) * 1024 + e4] = acc[bb];
}

// L7b: sum out partials (72 kc) + bias; block 0 reduces KL partials (256). 32 blocks (b) x 256.
__global__ __launch_bounds__(256) void k_fin(const float* out_b, float* ws, float* out) {
    int b = blockIdx.x;
    int h4 = threadIdx.x * 4;
    float4 a = *(const float4*)&out_b[h4];
    #pragma unroll
    for (int kc = 0; kc < 72; kc++) {
        float4 p = *(const float4*)&ws[OFF_ARENA + kc * 32768 + b * 1024 + h4];
        a.x += p.x; a.y += p.y; a.z += p.z; a.w += p.w;
    }
    *(float4*)&out[b * H + h4] = a;
    if (b == 0) {
        int t = threadIdx.x;
        __shared__ float kls[256];
        kls[t] = ws[OFF_KLP + t];
        __syncthreads();
        for (int st = 128; st > 0; st >>= 1) {
            if (t < st) kls[t] += kls[t + st];
            __syncthreads();
        }
        if (t == 0) out[B * H] = -kls[0];
    }
}

extern "C" void kernel_launch(void* const* d_in, const int* in_sizes, int n_in,
                              void* d_out, int out_size, void* d_ws, size_t ws_size,
                              hipStream_t stream) {
    const float* feats = (const float*)d_in[0];
    const float* Wq    = (const float*)d_in[1];
    const float* bq    = (const float*)d_in[2];
    const float* Wk    = (const float*)d_in[3];
    const float* bk    = (const float*)d_in[4];
    const float* Wv    = (const float*)d_in[5];
    const float* bv    = (const float*)d_in[6];
    const float* pgq_w = (const float*)d_in[7];
    const float* pgq_b = (const float*)d_in[8];
    const float* pgk_w = (const float*)d_in[9];
    const float* pgk_b = (const float*)d_in[10];
    const float* mu_w  = (const float*)d_in[11];
    const float* mu_b  = (const float*)d_in[12];
    const float* lv_w  = (const float*)d_in[13];
    const float* lv_b  = (const float*)d_in[14];
    const float* dyn   = (const float*)d_in[15];
    const float* WE_w  = (const float*)d_in[16];
    const float* WE_b  = (const float*)d_in[17];
    const float* Wh_w  = (const float*)d_in[18];
    const float* Wh_b  = (const float*)d_in[19];
    const float* Wqc_w = (const float*)d_in[20];
    const float* Wqc_b = (const float*)d_in[21];
    const float* lnE_g = (const float*)d_in[22];
    const float* lnE_b = (const float*)d_in[23];
    const float* lnG_g = (const float*)d_in[24];
    const float* lnG_b = (const float*)d_in[25];
    const float* out_w = (const float*)d_in[26];
    const float* out_b = (const float*)d_in[27];
    const float* eps   = (const float*)d_in[28];
    float* ws  = (float*)d_ws;
    float* out = (float*)d_out;

    k_prep2<<<807, 256, 0, stream>>>(feats, Wq, Wk, bq, bk, mu_w, mu_b, lv_w, lv_b,
                                     pgq_w, pgq_b, pgk_w, pgk_b, ws);
    k_redQ<<<96, 256, 0, stream>>>(feats, bq, bk, eps, dyn, ws);
    k_qk<<<576, 256, 0, stream>>>(ws);
    k_redqk<<<144, 256, 0, stream>>>(ws);
    k_fused<<<256, 1024, 0, stream>>>(feats, eps, dyn, ws);
    k_agg2<<<576, 192, 0, stream>>>(Wv, ws);
    k_redA<<<72, 256, 0, stream>>>(bv, ws);
    k_eg2<<<864, 192, 0, stream>>>(WE_w, Wh_w, Wqc_w, ws);
    k_redEG<<<144, 256, 0, stream>>>(WE_b, Wh_b, Wqc_b, ws);
    k_ln2<<<96, 256, 0, stream>>>(lnE_g, lnE_b, lnG_g, lnG_b, ws);
    k_out2<<<288, 256, 0, stream>>>(out_w, ws);
    k_fin<<<32, 256, 0, stream>>>(out_b, ws, out);
}

// Round 7
// 289.324 us; speedup vs baseline: 1.2631x; 1.0250x over previous
//
#include <hip/hip_runtime.h>

// Problem constants (fixed by the reference)
#define M 3
#define B 32
#define S 256
#define D 768
#define H 1024
#define MD (M * D)          // 2304
#define NP (M * (M - 1))    // 6 ordered (i,j) pairs
#define SCALE 0.03608439182435161f  // 1/sqrt(768)
#define LN_EPS 1e-5f

// Workspace layout (float offsets).
#define OFF_WMU   0         // [M][D]   (WMU then WLV contiguous: staged together)
#define OFF_WLV   2304      // [M][D]
#define OFF_WPGQ  4608      // [M][D]
#define OFF_WPK   6912      // [NP][D]
#define OFF_CMU   11520     // [M]
#define OFF_CLV   11523     // [M]
#define OFF_CPGQ  11526     // [M]
#define OFF_CPK   11529     // [NP]
#define OFF_PQ    11536     // [NP][B] final pq gate (pq_base * g0)
#define OFF_Q     11776     // [M][B][D]
#define OFF_QBK   85504     // [NP][B]
#define OFF_QK    85760     // [NP][B][D] reduced qk (147456)
#define OFF_MLH   233216    // [NP][B][8(h)][2(m,l)] = 3072
#define OFF_KLP   236288    // [256] per-block KL partials
#define OFF_FUSED 457728    // [B][MD]
#define OFF_FSUM  531520    // [8(h)][NP][B][D] (h stride 147456) = 1179648
#define OFF_WKT   1711168   // [M][D][D] Wk transposed (1769472)
#define OFF_ARENA 3480640   // Q partials (24 x 73728) -> agg partials (48 x 73728) -> out partials (72 x 32768)
#define OFF_ARENA2 7019584  // qk partials (24 x 147456) -> E/G partials (72 x 73728)
#define OFF_AGG   236544    // [M][B][D]

__device__ __forceinline__ float wave_reduce(float v) {
    #pragma unroll
    for (int o = 32; o > 0; o >>= 1) v += __shfl_down(v, o, 64);
    return v;
}

__device__ __forceinline__ float sigmoidf(float x) {
    return 1.0f / (1.0f + __expf(-x));
}

__device__ __forceinline__ float dot4(float4 a, float4 b) {
    return a.x * b.x + a.y * b.y + a.z * b.z + a.w * b.w;
}

__device__ __forceinline__ void fma4(float4& a, float s, float4 w) {
    a.x += s * w.x; a.y += s * w.y; a.z += s * w.z; a.w += s * w.w;
}

// L1: fused prep + Q partials.
// blocks 0..71 vector-dots, 72..86 scalar consts, 87..518 Wk transpose,
// 519..806 Q GEMV partials (feats_s0 @ Wq, split-K 24).
__global__ __launch_bounds__(256) void k_prep2(const float* feats,
        const float* Wq, const float* Wk,
        const float* bq, const float* bk,
        const float* mu_w, const float* mu_b, const float* lv_w, const float* lv_b,
        const float* pgq_w, const float* pgq_b, const float* pgk_w, const float* pgk_b,
        float* ws) {
    int blk = blockIdx.x;
    if (blk < 72) {
        int mat = blk / 12, rg = blk % 12;
        const float* Wm; const float *va, *vb, *vc;
        float *oa, *ob, *oc; int nv;
        if (mat < 3) {
            int i = mat;
            Wm = Wq + i * D * D;
            va = mu_w + i * D; vb = lv_w + i * D; vc = pgq_w + i * D;
            oa = ws + OFF_WMU + i * D; ob = ws + OFF_WLV + i * D; oc = ws + OFF_WPGQ + i * D;
            nv = 3;
        } else {
            int j = mat - 3;
            int i1 = (j == 0) ? 1 : 0, i2 = (j == 2) ? 1 : 2;
            int p1 = 2 * i1 + ((j < i1) ? j : j - 1);
            int p2 = 2 * i2 + ((j < i2) ? j : j - 1);
            Wm = Wk + j * D * D;
            va = pgk_w + i1 * D; vb = pgk_w + i2 * D; vc = va;
            oa = ws + OFF_WPK + p1 * D; ob = ws + OFF_WPK + p2 * D; oc = oa;
            nv = 2;
        }
        int wave = threadIdx.x >> 6, lane = threadIdx.x & 63;
        const float4* va4 = (const float4*)va;
        const float4* vb4 = (const float4*)vb;
        const float4* vc4 = (const float4*)vc;
        float4 A0 = va4[lane], A1 = va4[lane + 64], A2 = va4[lane + 128];
        float4 B0 = vb4[lane], B1 = vb4[lane + 64], B2 = vb4[lane + 128];
        float4 C0 = vc4[lane], C1 = vc4[lane + 64], C2 = vc4[lane + 128];
        int base = rg * 64 + wave * 16;
        for (int r = 0; r < 16; r += 2) {
            const float4* rowP = (const float4*)(Wm + (base + r) * D);
            const float4* rowQ = (const float4*)(Wm + (base + r + 1) * D);
            float4 x0 = rowP[lane], x1 = rowP[lane + 64], x2 = rowP[lane + 128];
            float4 y0 = rowQ[lane], y1 = rowQ[lane + 64], y2 = rowQ[lane + 128];
            float daP = dot4(x0, A0) + dot4(x1, A1) + dot4(x2, A2);
            float dbP = dot4(x0, B0) + dot4(x1, B1) + dot4(x2, B2);
            float dcP = dot4(x0, C0) + dot4(x1, C1) + dot4(x2, C2);
            float daQ = dot4(y0, A0) + dot4(y1, A1) + dot4(y2, A2);
            float dbQ = dot4(y0, B0) + dot4(y1, B1) + dot4(y2, B2);
            float dcQ = dot4(y0, C0) + dot4(y1, C1) + dot4(y2, C2);
            daP = wave_reduce(daP); dbP = wave_reduce(dbP);
            daQ = wave_reduce(daQ); dbQ = wave_reduce(dbQ);
            if (nv == 3) { dcP = wave_reduce(dcP); dcQ = wave_reduce(dcQ); }
            if (lane == 0) {
                oa[base + r] = daP; ob[base + r] = dbP;
                oa[base + r + 1] = daQ; ob[base + r + 1] = dbQ;
                if (nv == 3) { oc[base + r] = dcP; oc[base + r + 1] = dcQ; }
            }
        }
    } else if (blk < 87) {
        int job = blk - 72;
        const float *a, *bvec; float bias; float* out;
        if (job < 3)      { int i = job;     a = bq + i * D; bvec = mu_w + i * D;  bias = mu_b[i];  out = ws + OFF_CMU + i; }
        else if (job < 6) { int i = job - 3; a = bq + i * D; bvec = lv_w + i * D;  bias = lv_b[i];  out = ws + OFF_CLV + i; }
        else if (job < 9) { int i = job - 6; a = bq + i * D; bvec = pgq_w + i * D; bias = pgq_b[i]; out = ws + OFF_CPGQ + i; }
        else {
            int p = job - 9, i = p / 2, c = p % 2, j = c + (c >= i ? 1 : 0);
            a = bk + j * D; bvec = pgk_w + i * D; bias = pgk_b[i]; out = ws + OFF_CPK + p;
        }
        int t = threadIdx.x;
        float part = 0.f;
        if (t < 192) part = dot4(((const float4*)a)[t], ((const float4*)bvec)[t]);
        part = wave_reduce(part);
        __shared__ float r[4];
        if ((t & 63) == 0) r[t >> 6] = part;
        __syncthreads();
        if (t == 0) *out = r[0] + r[1] + r[2] + r[3] + bias;
    } else if (blk < 519) {
        int r = blk - 87;
        int j = r / 144; r = r % 144;
        int d0 = (r / 12) * 64, e0 = (r % 12) * 64;
        __shared__ float tile[64][65];
        const float* src = Wk + j * D * D;
        for (int idx = threadIdx.x; idx < 4096; idx += 256) {
            int rr = idx / 64, cc = idx % 64;
            tile[rr][cc] = src[(d0 + rr) * D + e0 + cc];
        }
        __syncthreads();
        float* dst = ws + OFF_WKT + j * D * D;
        for (int idx = threadIdx.x; idx < 4096; idx += 256) {
            int rr = idx / 64, cc = idx % 64;
            dst[(e0 + rr) * D + d0 + cc] = tile[cc][rr];
        }
    } else {
        // Q partials: blocks (i 3, bg 4 (8 b), kc 24 (32 k))
        int qb = blk - 519;
        int i = qb / 96, r = qb % 96, bg = r / 24, kc = r % 24;
        int kbase = kc * 32;
        __shared__ __align__(16) float xs[32][8];
        for (int idx = threadIdx.x; idx < 256; idx += 256) {
            int d = idx & 31, bb = idx >> 5;
            xs[d][bb] = feats[((size_t)(i * B + bg * 8 + bb) * S) * D + kbase + d];
        }
        __syncthreads();
        if (threadIdx.x < 192) {
            int e4 = threadIdx.x * 4;
            const float* Wm = Wq + i * D * D + kbase * D + e4;
            float4 acc[8];
            #pragma unroll
            for (int bb = 0; bb < 8; bb++) acc[bb] = make_float4(0.f, 0.f, 0.f, 0.f);
            for (int k = 0; k < 32; k++) {
                float4 w = *(const float4*)(Wm + k * D);
                float4 x0 = *(const float4*)&xs[k][0];
                float4 x1 = *(const float4*)&xs[k][4];
                fma4(acc[0], x0.x, w); fma4(acc[1], x0.y, w);
                fma4(acc[2], x0.z, w); fma4(acc[3], x0.w, w);
                fma4(acc[4], x1.x, w); fma4(acc[5], x1.y, w);
                fma4(acc[6], x1.z, w); fma4(acc[7], x1.w, w);
            }
            #pragma unroll
            for (int bb = 0; bb < 8; bb++)
                *(float4*)&ws[OFF_ARENA + kc * 73728 + (i * 32 + bg * 8 + bb) * 768 + e4] = acc[bb];
        }
    }
}

// L1b: reduce Q partials (+bq) -> OFF_Q, qbk = Q.bk, and PQ gate from feats row 0. 96 blocks (i,b).
__global__ __launch_bounds__(256) void k_redQ(const float* feats, const float* bq,
        const float* bk, const float* eps, const float* dyn, float* ws) {
    int blk = blockIdx.x;
    int i = blk / B, b = blk % B;
    int fbase = (i * B + b) * D;
    int t = threadIdx.x;
    int wave = t >> 6, lane = t & 63;
    __shared__ float4 qsh[192];
    __shared__ float redsh[8];
    __shared__ float pqred[12];
    if (t < 192) {
        float4 a = *(const float4*)&bq[i * D + t * 4];
        #pragma unroll
        for (int kc = 0; kc < 24; kc++) {
            float4 v = *(const float4*)&ws[OFF_ARENA + kc * 73728 + fbase + t * 4];
            a.x += v.x; a.y += v.y; a.z += v.z; a.w += v.w;
        }
        *(float4*)&ws[OFF_Q + fbase + t * 4] = a;
        qsh[t] = a;
    }
    __syncthreads();
    int jA = (i == 0) ? 1 : 0, jB = (i == 2) ? 1 : 2;
    float pA_ = 0.f, pB_ = 0.f;
    if (t < 192) {
        float4 q = qsh[t];
        pA_ = dot4(q, *(const float4*)&bk[jA * D + t * 4]);
        pB_ = dot4(q, *(const float4*)&bk[jB * D + t * 4]);
    }
    pA_ = wave_reduce(pA_); pB_ = wave_reduce(pB_);
    if (lane == 0) { redsh[wave] = pA_; redsh[4 + wave] = pB_; }
    // PQ: stats of feats row s=0 for modality i
    float dm = 0.f, dl = 0.f, dp = 0.f;
    if (t < 192) {
        float4 x = *(const float4*)&feats[((size_t)(i * B + b) * S) * D + t * 4];
        dm = dot4(x, *(const float4*)&ws[OFF_WMU + i * D + t * 4]);
        dl = dot4(x, *(const float4*)&ws[OFF_WLV + i * D + t * 4]);
        dp = dot4(x, *(const float4*)&ws[OFF_WPGQ + i * D + t * 4]);
    }
    dm = wave_reduce(dm); dl = wave_reduce(dl); dp = wave_reduce(dp);
    if (lane == 0 && wave < 3) { pqred[wave] = dm; pqred[4 + wave] = dl; pqred[8 + wave] = dp; }
    __syncthreads();
    if (t == 0) {
        ws[OFF_QBK + (2 * i) * B + b]     = redsh[0] + redsh[1] + redsh[2] + redsh[3];
        ws[OFF_QBK + (2 * i + 1) * B + b] = redsh[4] + redsh[5] + redsh[6] + redsh[7];
        float mu0 = pqred[0] + pqred[1] + pqred[2] + ws[OFF_CMU + i];
        float lv0 = pqred[4] + pqred[5] + pqred[6] + ws[OFF_CLV + i];
        float pqb = pqred[8] + pqred[9] + pqred[10] + ws[OFF_CPGQ + i];
        float sd = dyn[0] * __expf(0.5f * lv0);
        float pqs = sigmoidf(pqb);
        #pragma unroll
        for (int c = 0; c < 2; c++) {
            int p = 2 * i + c;
            float e0 = eps[(size_t)(p * B + b) * S];
            ws[OFF_PQ + p * B + b] = pqs * sigmoidf(mu0 + sd * e0);
        }
    }
}

// L2: qk GEMV partials with WkT (reads reduced Q). 576 blocks (j 3, vg 8, kc 24 (32 k)).
// min-occupancy 4 waves/EU to cap VGPR at 128 (was latency-bound at ~2 waves/SIMD).
__global__ __launch_bounds__(256, 4) void k_qk(float* ws) {
    int blk = blockIdx.x;
    int j = blk / 192, r = blk % 192, vg = r / 24, kc = r % 24;
    int kbase = kc * 32;
    int i1 = (j == 0) ? 1 : 0, i2 = (j == 2) ? 1 : 2;
    __shared__ __align__(16) float xs[32][8];
    for (int idx = threadIdx.x; idx < 256; idx += 256) {
        int d = idx & 31, v = idx >> 5;
        int v64 = vg * 8 + v;
        int i_ = (v64 < 32) ? i1 : i2, b = v64 & 31;
        xs[d][v] = ws[OFF_Q + (i_ * 32 + b) * 768 + kbase + d];
    }
    __syncthreads();
    if (threadIdx.x < 192) {
        int e4 = threadIdx.x * 4;
        const float* Wm = ws + OFF_WKT + j * D * D + kbase * D + e4;
        float4 acc[8];
        #pragma unroll
        for (int bb = 0; bb < 8; bb++) acc[bb] = make_float4(0.f, 0.f, 0.f, 0.f);
        for (int k = 0; k < 32; k++) {
            float4 w = *(const float4*)(Wm + k * D);
            float4 x0 = *(const float4*)&xs[k][0];
            float4 x1 = *(const float4*)&xs[k][4];
            fma4(acc[0], x0.x, w); fma4(acc[1], x0.y, w);
            fma4(acc[2], x0.z, w); fma4(acc[3], x0.w, w);
            fma4(acc[4], x1.x, w); fma4(acc[5], x1.y, w);
            fma4(acc[6], x1.z, w); fma4(acc[7], x1.w, w);
        }
        #pragma unroll
        for (int v = 0; v < 8; v++)
            *(float4*)&ws[OFF_ARENA2 + kc * 147456 + (j * 64 + vg * 8 + v) * 768 + e4] = acc[v];
    }
}

// L2b: coalesced reduce of qk partials (24 slots) -> QK[p][b][d]. 144 blocks x 256.
__global__ __launch_bounds__(256) void k_redqk(float* ws) {
    int idx = blockIdx.x * 256 + threadIdx.x;
    int fidx = idx * 4;
    int row = fidx / 768, d = fidx % 768;
    int j = row / 64, v64 = row % 64;
    int b = v64 & 31, islot = v64 >> 5;
    int i_ = islot ? ((j == 2) ? 1 : 2) : ((j == 0) ? 1 : 0);
    int p = 2 * i_ + ((j < i_) ? j : j - 1);
    float4 a = make_float4(0.f, 0.f, 0.f, 0.f);
    #pragma unroll
    for (int kc = 0; kc < 24; kc++) {
        float4 v = *(const float4*)&ws[OFF_ARENA2 + kc * 147456 + fidx];
        a.x += v.x; a.y += v.y; a.z += v.z; a.w += v.w;
    }
    *(float4*)&ws[OFF_QK + (p * B + b) * D + d] = a;
}

// L3: MEGA-FUSED single feats pass: per (b, 32-row chunk h) across ALL modalities:
// stats (mu/lv/pkpre + KL) + score dots + gates + chunk softmax + weighted feats sum.
// 256 blocks (b 32, h 8) x 1024 threads.
__global__ __launch_bounds__(1024) void k_fused(const float* feats, const float* eps,
                                                const float* dyn, float* ws) {
    int blk = blockIdx.x;
    int b = blk >> 3, h = blk & 7;
    int t = threadIdx.x;
    int w = t >> 6, lane = t & 63;
    __shared__ __align__(16) float swA[4608];   // WMU[3][768] | WLV[3][768]
    __shared__ __align__(16) float swPK[4608];  // WPK[6][768]
    __shared__ __align__(16) float sqk[4608];   // qk[6][768]
    __shared__ float raws[6][32], pkps[6][32], mus[3][32], lvs[3][32], wgt[6][32];
    __shared__ float klv[96];
    __shared__ float pq_s[6], qbk_s[6], cmu_s[3], clv_s[3], cpk_s[6];
    {
        const float4* srcA = (const float4*)(ws + OFF_WMU);
        const float4* srcP = (const float4*)(ws + OFF_WPK);
        float4* dA = (float4*)swA;
        float4* dP = (float4*)swPK;
        float4* dQ = (float4*)sqk;
        for (int idx = t; idx < 1152; idx += 1024) {
            dA[idx] = srcA[idx];
            dP[idx] = srcP[idx];
            int p = idx / 192, d4 = (idx % 192) * 4;
            dQ[idx] = *(const float4*)&ws[OFF_QK + (p * B + b) * D + d4];
        }
        if (t < 6) { pq_s[t] = ws[OFF_PQ + t * B + b]; qbk_s[t] = ws[OFF_QBK + t * B + b]; cpk_s[t] = ws[OFF_CPK + t]; }
        else if (t < 9) { cmu_s[t - 6] = ws[OFF_CMU + t - 6]; clv_s[t - 6] = ws[OFF_CLV + t - 6]; }
    }
    __syncthreads();
    // phase 1: 96 row tasks (m,k): 6 dots each
    const float4* swA4 = (const float4*)swA;
    const float4* swPK4 = (const float4*)swPK;
    const float4* sqk4 = (const float4*)sqk;
    for (int tau = w * 6; tau < w * 6 + 6; tau++) {
        int m = tau >> 5, k = tau & 31;
        const float4* row = (const float4*)(feats + ((size_t)((m * B + b) * S) + h * 32 + k) * D);
        float4 x0 = row[lane], x1 = row[lane + 64], x2 = row[lane + 128];
        int i1 = (m == 0) ? 1 : 0, i2 = (m == 2) ? 1 : 2;
        int pj0 = 2 * i1 + ((m < i1) ? m : m - 1);
        int pj1 = 2 * i2 + ((m < i2) ? m : m - 1);
        int oM = m * 192, oL = (3 + m) * 192, o0 = pj0 * 192, o1 = pj1 * 192;
        float dmu = dot4(x0, swA4[oM + lane]) + dot4(x1, swA4[oM + lane + 64]) + dot4(x2, swA4[oM + lane + 128]);
        float dlv = dot4(x0, swA4[oL + lane]) + dot4(x1, swA4[oL + lane + 64]) + dot4(x2, swA4[oL + lane + 128]);
        float dk0 = dot4(x0, swPK4[o0 + lane]) + dot4(x1, swPK4[o0 + lane + 64]) + dot4(x2, swPK4[o0 + lane + 128]);
        float dk1 = dot4(x0, swPK4[o1 + lane]) + dot4(x1, swPK4[o1 + lane + 64]) + dot4(x2, swPK4[o1 + lane + 128]);
        float dr0 = dot4(x0, sqk4[o0 + lane]) + dot4(x1, sqk4[o0 + lane + 64]) + dot4(x2, sqk4[o0 + lane + 128]);
        float dr1 = dot4(x0, sqk4[o1 + lane]) + dot4(x1, sqk4[o1 + lane + 64]) + dot4(x2, sqk4[o1 + lane + 128]);
        dmu = wave_reduce(dmu); dlv = wave_reduce(dlv);
        dk0 = wave_reduce(dk0); dk1 = wave_reduce(dk1);
        dr0 = wave_reduce(dr0); dr1 = wave_reduce(dr1);
        if (lane == 0) {
            mus[m][k] = dmu + cmu_s[m];
            lvs[m][k] = dlv + clv_s[m];
            pkps[pj0][k] = dk0 + cpk_s[pj0];
            pkps[pj1][k] = dk1 + cpk_s[pj1];
            raws[pj0][k] = dr0;
            raws[pj1][k] = dr1;
        }
    }
    __syncthreads();
    float dynv = dyn[0];
    // phase 2: gates + scores + per-chunk softmax; KL terms
    if (t < 192) {
        int p = t >> 5, k = t & 31;
        int iq = p >> 1;
        float e = eps[(size_t)(p * B + b) * S + h * 32 + k];
        float g = sigmoidf(mus[iq][k] + dynv * __expf(0.5f * lvs[iq][k]) * e);
        float pk = sigmoidf(pkps[p][k]) * g;
        float s = (raws[p][k] + qbk_s[p]) * SCALE * pq_s[p] * pk;
        float mc = s;
        #pragma unroll
        for (int o = 16; o > 0; o >>= 1) mc = fmaxf(mc, __shfl_xor(mc, o, 64));
        float wv_ = __expf(s - mc);
        float l = wv_;
        #pragma unroll
        for (int o = 16; o > 0; o >>= 1) l += __shfl_xor(l, o, 64);
        wgt[p][k] = wv_;
        if (k == 0) {
            float* mh = ws + OFF_MLH + (p * B + b) * 16 + h * 2;
            mh[0] = mc; mh[1] = l;
        }
    } else if (t < 288) {
        int tau = t - 192;
        int m = tau >> 5, k = tau & 31;
        float muv = mus[m][k], lvv = lvs[m][k];
        klv[tau] = 1.0f + lvv - muv * muv - __expf(lvv);
    }
    __syncthreads();
    // phase 4: weighted feats sum per target modality (2 pairs each), unnormalized
    if (t < 768) {
        #pragma unroll
        for (int jm = 0; jm < 3; jm++) {
            int i1 = (jm == 0) ? 1 : 0, i2 = (jm == 2) ? 1 : 2;
            int pj0 = 2 * i1 + ((jm < i1) ? jm : jm - 1);
            int pj1 = 2 * i2 + ((jm < i2) ? jm : jm - 1);
            const float* col = feats + ((size_t)((jm * B + b) * S) + h * 32) * D + t;
            float accA = 0.f, accB = 0.f;
            #pragma unroll 8
            for (int k = 0; k < 32; k++) {
                float fv = col[(size_t)k * D];
                accA += wgt[pj0][k] * fv;
                accB += wgt[pj1][k] * fv;
            }
            ws[OFF_FSUM + h * 147456 + (pj0 * B + b) * D + t] = accA;
            ws[OFF_FSUM + h * 147456 + (pj1 * B + b) * D + t] = accB;
        }
    }
    if (t < 64) {
        float s2 = klv[t] + ((t < 32) ? klv[64 + t] : 0.f);
        s2 = wave_reduce(s2);
        if (t == 0) ws[OFF_KLP + blk] = s2;
    }
}

// L4: agg partials, one Wv stream per block, combining 8 S-chunks via (m,l).
// 576 blocks (i 3, js 2, bg 4, kc 24 (32 k)) x 192. min-occupancy hint.
__global__ __launch_bounds__(192, 4) void k_agg2(const float* Wv, float* ws) {
    int blk = blockIdx.x;
    int i = blk / 192, r = blk % 192, js = r / 96, r2 = r % 96, bg = r2 / 24, kc = r2 % 24;
    int kbase = kc * 32;
    int j0 = (i == 0) ? 1 : 0, j1 = (i == 2) ? 1 : 2;
    int jv = js ? j1 : j0;
    int p = 2 * i + js;
    __shared__ __align__(16) float xs[32][8];
    __shared__ float comb[8][8];
    if (threadIdx.x < 8) {
        int bb = threadIdx.x;
        const float* mh = ws + OFF_MLH + (p * B + bg * 8 + bb) * 16;
        float mm[8], ll[8];
        float mx = -1e30f;
        #pragma unroll
        for (int hh = 0; hh < 8; hh++) { mm[hh] = mh[2 * hh]; ll[hh] = mh[2 * hh + 1]; mx = fmaxf(mx, mm[hh]); }
        float L = 0.f;
        float ee[8];
        #pragma unroll
        for (int hh = 0; hh < 8; hh++) { ee[hh] = __expf(mm[hh] - mx); L += ee[hh] * ll[hh]; }
        #pragma unroll
        for (int hh = 0; hh < 8; hh++) comb[hh][bb] = ee[hh] / L;
    }
    __syncthreads();
    for (int idx = threadIdx.x; idx < 256; idx += 192) {
        int d = idx & 31, bb = idx >> 5;
        int base = OFF_FSUM + (p * B + bg * 8 + bb) * D + kbase + d;
        float v = 0.f;
        #pragma unroll
        for (int hh = 0; hh < 8; hh++) v += comb[hh][bb] * ws[base + hh * 147456];
        xs[d][bb] = v;
    }
    __syncthreads();
    int e4 = threadIdx.x * 4;
    const float* W0 = Wv + jv * D * D + kbase * D + e4;
    float4 acc[8];
    #pragma unroll
    for (int bb = 0; bb < 8; bb++) acc[bb] = make_float4(0.f, 0.f, 0.f, 0.f);
    for (int k = 0; k < 32; k++) {
        float4 w0 = *(const float4*)(W0 + k * D);
        float4 a0 = *(const float4*)&xs[k][0];
        float4 a1 = *(const float4*)&xs[k][4];
        fma4(acc[0], a0.x, w0); fma4(acc[1], a0.y, w0);
        fma4(acc[2], a0.z, w0); fma4(acc[3], a0.w, w0);
        fma4(acc[4], a1.x, w0); fma4(acc[5], a1.y, w0);
        fma4(acc[6], a1.z, w0); fma4(acc[7], a1.w, w0);
    }
    #pragma unroll
    for (int bb = 0; bb < 8; bb++)
        *(float4*)&ws[OFF_ARENA + (js * 24 + kc) * 73728 + (i * 32 + bg * 8 + bb) * 768 + e4] = acc[bb];
}

// L4b: coalesced reduce agg partials (48 slots) + bv biases -> AGG. 72 blocks x 256.
__global__ __launch_bounds__(256) void k_redA(const float* bv, float* ws) {
    int idx = blockIdx.x * 256 + threadIdx.x;
    int fidx = idx * 4;
    int i = fidx / 24576, e = fidx % 768;
    int j0 = (i == 0) ? 1 : 0, j1 = (i == 2) ? 1 : 2;
    float4 b0 = *(const float4*)&bv[j0 * 768 + e];
    float4 b1 = *(const float4*)&bv[j1 * 768 + e];
    float4 a = make_float4(b0.x + b1.x, b0.y + b1.y, b0.z + b1.z, b0.w + b1.w);
    #pragma unroll
    for (int s = 0; s < 48; s++) {
        float4 p = *(const float4*)&ws[OFF_ARENA + s * 73728 + fidx];
        a.x += p.x; a.y += p.y; a.z += p.z; a.w += p.w;
    }
    *(float4*)&ws[OFF_AGG + fidx] = a;
}

// L5: E/G partials, one stream per block. 864 blocks (kind 3, i 3, bg 4, kc 24 (32 k)).
// min-occupancy hint.
__global__ __launch_bounds__(192, 4) void k_eg2(const float* WE_w, const float* Wh_w,
                                                const float* Wqc_w, float* ws) {
    int blk = blockIdx.x;
    int kind = blk / 288, r = blk % 288;
    int i = r / 96, r2 = r % 96, bg = r2 / 24, kc = r2 % 24;
    int kbase = kc * 32;
    int src = (kind == 2) ? OFF_Q : OFF_AGG;
    __shared__ __align__(16) float xs[32][8];
    for (int idx = threadIdx.x; idx < 256; idx += 192) {
        int d = idx & 31, bb = idx >> 5;
        xs[d][bb] = ws[src + (i * 32 + bg * 8 + bb) * 768 + kbase + d];
    }
    __syncthreads();
    int e4 = threadIdx.x * 4;
    const float* Wm = ((kind == 0) ? WE_w : (kind == 1) ? Wh_w : Wqc_w) + i * D * D + kbase * D + e4;
    float4 acc[8];
    #pragma unroll
    for (int bb = 0; bb < 8; bb++) acc[bb] = make_float4(0.f, 0.f, 0.f, 0.f);
    for (int k = 0; k < 32; k++) {
        float4 w = *(const float4*)(Wm + k * D);
        float4 a0 = *(const float4*)&xs[k][0];
        float4 a1 = *(const float4*)&xs[k][4];
        fma4(acc[0], a0.x, w); fma4(acc[1], a0.y, w);
        fma4(acc[2], a0.z, w); fma4(acc[3], a0.w, w);
        fma4(acc[4], a1.x, w); fma4(acc[5], a1.y, w);
        fma4(acc[6], a1.z, w); fma4(acc[7], a1.w, w);
    }
    #pragma unroll
    for (int bb = 0; bb < 8; bb++)
        *(float4*)&ws[OFF_ARENA2 + (kind * 24 + kc) * 73728 + (i * 32 + bg * 8 + bb) * 768 + e4] = acc[bb];
}

// L5b+L6 merged: reduce E/G partials (+bias+relu), then LayerNorm(E)*LayerNorm(G)
// -> FUSED, all in one block per (i,b). 96 blocks x 256.
__global__ __launch_bounds__(256) void k_redEGLN(const float* WE_b, const float* Wh_b,
        const float* Wqc_b,
        const float* lnE_g, const float* lnE_b,
        const float* lnG_g, const float* lnG_b, float* ws) {
    int blk = blockIdx.x;
    int i = blk / B, b = blk % B;
    int row = (i * B + b) * D;
    int t = threadIdx.x;
    float4 e = make_float4(0.f, 0.f, 0.f, 0.f);
    float4 g = make_float4(0.f, 0.f, 0.f, 0.f);
    if (t < 192) {
        e = *(const float4*)&WE_b[i * D + t * 4];
        float4 b0 = *(const float4*)&Wh_b[i * D + t * 4];
        float4 b1 = *(const float4*)&Wqc_b[i * D + t * 4];
        g = make_float4(b0.x + b1.x, b0.y + b1.y, b0.z + b1.z, b0.w + b1.w);
        #pragma unroll
        for (int s = 0; s < 24; s++) {
            float4 p = *(const float4*)&ws[OFF_ARENA2 + s * 73728 + row + t * 4];
            e.x += p.x; e.y += p.y; e.z += p.z; e.w += p.w;
        }
        #pragma unroll
        for (int s = 24; s < 72; s++) {
            float4 p = *(const float4*)&ws[OFF_ARENA2 + s * 73728 + row + t * 4];
            g.x += p.x; g.y += p.y; g.z += p.z; g.w += p.w;
        }
        e.x = fmaxf(e.x, 0.f); e.y = fmaxf(e.y, 0.f); e.z = fmaxf(e.z, 0.f); e.w = fmaxf(e.w, 0.f);
        g.x = fmaxf(g.x, 0.f); g.y = fmaxf(g.y, 0.f); g.z = fmaxf(g.z, 0.f); g.w = fmaxf(g.w, 0.f);
    }
    __shared__ float r1[256], r2[256], r3[256], r4[256];
    r1[t] = e.x + e.y + e.z + e.w;
    r2[t] = e.x * e.x + e.y * e.y + e.z * e.z + e.w * e.w;
    r3[t] = g.x + g.y + g.z + g.w;
    r4[t] = g.x * g.x + g.y * g.y + g.z * g.z + g.w * g.w;
    __syncthreads();
    for (int st = 128; st > 0; st >>= 1) {
        if (t < st) { r1[t] += r1[t + st]; r2[t] += r2[t + st]; r3[t] += r3[t + st]; r4[t] += r4[t + st]; }
        __syncthreads();
    }
    float mE = r1[0] * (1.0f / D), vE = r2[0] * (1.0f / D) - mE * mE;
    float mG = r3[0] * (1.0f / D), vG = r4[0] * (1.0f / D) - mG * mG;
    float sE = rsqrtf(vE + LN_EPS), sG = rsqrtf(vG + LN_EPS);
    if (t < 192) {
        float4 eg  = *(const float4*)&lnE_g[i * D + t * 4];
        float4 ebv = *(const float4*)&lnE_b[i * D + t * 4];
        float4 gg  = *(const float4*)&lnG_g[i * D + t * 4];
        float4 gbv = *(const float4*)&lnG_b[i * D + t * 4];
        float4 o;
        o.x = ((e.x - mE) * sE * eg.x + ebv.x) * ((g.x - mG) * sG * gg.x + gbv.x);
        o.y = ((e.y - mE) * sE * eg.y + ebv.y) * ((g.y - mG) * sG * gg.y + gbv.y);
        o.z = ((e.z - mE) * sE * eg.z + ebv.z) * ((g.z - mG) * sG * gg.z + gbv.z);
        o.w = ((e.w - mE) * sE * eg.w + ebv.w) * ((g.w - mG) * sG * gg.w + gbv.w);
        *(float4*)&ws[OFF_FUSED + b * MD + i * D + t * 4] = o;
    }
}

// L7: out GEMM partials -> arena (no atomics). 288 blocks (bg 4, kc 72 (32 k)) x 256.
// min-occupancy 4 waves/EU (was 208 VGPR -> 2 waves/SIMD cap).
__global__ __launch_bounds__(256, 4) void k_out2(const float* out_w, float* ws) {
    int blk = blockIdx.x;
    int bg = blk / 72, kc = blk % 72;
    int kbase = kc * 32;
    __shared__ __align__(16) float xs[32][8];
    for (int idx = threadIdx.x; idx < 256; idx += 256) {
        int d = idx & 31, bb = idx >> 5;
        xs[d][bb] = ws[OFF_FUSED + (bg * 8 + bb) * MD + kbase + d];
    }
    __syncthreads();
    int e4 = threadIdx.x * 4;
    const float* Wm = out_w + kbase * H + e4;
    float4 acc[8];
    #pragma unroll
    for (int bb = 0; bb < 8; bb++) acc[bb] = make_float4(0.f, 0.f, 0.f, 0.f);
    for (int k = 0; k < 32; k++) {
        float4 w = *(const float4*)(Wm + k * H);
        float4 x0 = *(const float4*)&xs[k][0];
        float4 x1 = *(const float4*)&xs[k][4];
        fma4(acc[0], x0.x, w); fma4(acc[1], x0.y, w);
        fma4(acc[2], x0.z, w); fma4(acc[3], x0.w, w);
        fma4(acc[4], x1.x, w); fma4(acc[5], x1.y, w);
        fma4(acc[6], x1.z, w); fma4(acc[7], x1.w, w);
    }
    #pragma unroll
    for (int bb = 0; bb < 8; bb++)
        *(float4*)&ws[OFF_ARENA + kc * 32768 + (bg * 8 + bb) * 1024 + e4] = acc[bb];
}

// L7b: sum out partials (72 kc) + bias; block 0 reduces KL partials (256). 32 blocks (b) x 256.
__global__ __launch_bounds__(256) void k_fin(const float* out_b, float* ws, float* out) {
    int b = blockIdx.x;
    int h4 = threadIdx.x * 4;
    float4 a = *(const float4*)&out_b[h4];
    #pragma unroll
    for (int kc = 0; kc < 72; kc++) {
        float4 p = *(const float4*)&ws[OFF_ARENA + kc * 32768 + b * 1024 + h4];
        a.x += p.x; a.y += p.y; a.z += p.z; a.w += p.w;
    }
    *(float4*)&out[b * H + h4] = a;
    if (b == 0) {
        int t = threadIdx.x;
        __shared__ float kls[256];
        kls[t] = ws[OFF_KLP + t];
        __syncthreads();
        for (int st = 128; st > 0; st >>= 1) {
            if (t < st) kls[t] += kls[t + st];
            __syncthreads();
        }
        if (t == 0) out[B * H] = -kls[0];
    }
}

extern "C" void kernel_launch(void* const* d_in, const int* in_sizes, int n_in,
                              void* d_out, int out_size, void* d_ws, size_t ws_size,
                              hipStream_t stream) {
    const float* feats = (const float*)d_in[0];
    const float* Wq    = (const float*)d_in[1];
    const float* bq    = (const float*)d_in[2];
    const float* Wk    = (const float*)d_in[3];
    const float* bk    = (const float*)d_in[4];
    const float* Wv    = (const float*)d_in[5];
    const float* bv    = (const float*)d_in[6];
    const float* pgq_w = (const float*)d_in[7];
    const float* pgq_b = (const float*)d_in[8];
    const float* pgk_w = (const float*)d_in[9];
    const float* pgk_b = (const float*)d_in[10];
    const float* mu_w  = (const float*)d_in[11];
    const float* mu_b  = (const float*)d_in[12];
    const float* lv_w  = (const float*)d_in[13];
    const float* lv_b  = (const float*)d_in[14];
    const float* dyn   = (const float*)d_in[15];
    const float* WE_w  = (const float*)d_in[16];
    const float* WE_b  = (const float*)d_in[17];
    const float* Wh_w  = (const float*)d_in[18];
    const float* Wh_b  = (const float*)d_in[19];
    const float* Wqc_w = (const float*)d_in[20];
    const float* Wqc_b = (const float*)d_in[21];
    const float* lnE_g = (const float*)d_in[22];
    const float* lnE_b = (const float*)d_in[23];
    const float* lnG_g = (const float*)d_in[24];
    const float* lnG_b = (const float*)d_in[25];
    const float* out_w = (const float*)d_in[26];
    const float* out_b = (const float*)d_in[27];
    const float* eps   = (const float*)d_in[28];
    float* ws  = (float*)d_ws;
    float* out = (float*)d_out;

    k_prep2<<<807, 256, 0, stream>>>(feats, Wq, Wk, bq, bk, mu_w, mu_b, lv_w, lv_b,
                                     pgq_w, pgq_b, pgk_w, pgk_b, ws);
    k_redQ<<<96, 256, 0, stream>>>(feats, bq, bk, eps, dyn, ws);
    k_qk<<<576, 256, 0, stream>>>(ws);
    k_redqk<<<144, 256, 0, stream>>>(ws);
    k_fused<<<256, 1024, 0, stream>>>(feats, eps, dyn, ws);
    k_agg2<<<576, 192, 0, stream>>>(Wv, ws);
    k_redA<<<72, 256, 0, stream>>>(bv, ws);
    k_eg2<<<864, 192, 0, stream>>>(WE_w, Wh_w, Wqc_w, ws);
    k_redEGLN<<<96, 256, 0, stream>>>(WE_b, Wh_b, Wqc_b, lnE_g, lnE_b, lnG_g, lnG_b, ws);
    k_out2<<<288, 256, 0, stream>>>(out_w, ws);
    k_fin<<<32, 256, 0, stream>>>(out_b, ws, out);
}